// Round 1
// baseline (2325.827 us; speedup 1.0000x reference)
//
#include <hip/hip_runtime.h>

// ---------------------------------------------------------------------------
// Res_up block:
//   knn (shared) -> interp(x) -> skip MPL on fine graph
//                -> MPL on coarse -> interp -> MPL on fine
//   -> residual + train-mode BatchNorm (over nodes) + SELU
// Sizes (fixed by the problem): Nc=4096, Nf=16384, Ec=65536, Ef=262144,
// Cin=128, Ch=64, Cout=128.
// ---------------------------------------------------------------------------

#define SELU_SCALE 1.0507009873554805f
#define SELU_ALPHA 1.6732632423543772f

static constexpr int NC = 4096, NF = 16384, EC = 65536, EF = 262144;
static constexpr int CIN = 128, CH = 64, CO = 128;

__device__ __forceinline__ float selu_f(float x) {
    return x > 0.0f ? SELU_SCALE * x
                    : SELU_SCALE * SELU_ALPHA * (__expf(x) - 1.0f);
}

// ---------------------------------------------------------------------------
// K1: brute-force kNN (k=3) of pos_f against pos_c; stores indices and
// pre-normalized inverse-square-distance weights.
// ---------------------------------------------------------------------------
__global__ __launch_bounds__(256) void knn_kernel(
    const float* __restrict__ pos_c, const float* __restrict__ pos_f,
    int* __restrict__ knn_idx, float* __restrict__ knn_w) {
    __shared__ float2 spos[NC];
    for (int i = threadIdx.x; i < NC; i += blockDim.x)
        spos[i] = ((const float2*)pos_c)[i];
    __syncthreads();

    int t = blockIdx.x * blockDim.x + threadIdx.x;
    float2 p = ((const float2*)pos_f)[t];

    float d0 = 1e30f, d1 = 1e30f, d2 = 1e30f;
    int i0 = 0, i1 = 0, i2 = 0;
    for (int j = 0; j < NC; ++j) {
        float dx = p.x - spos[j].x;
        float dy = p.y - spos[j].y;
        float d = dx * dx + dy * dy;
        if (d < d2) {
            if (d < d1) {
                d2 = d1; i2 = i1;
                if (d < d0) { d1 = d0; i1 = i0; d0 = d; i0 = j; }
                else        { d1 = d;  i1 = j; }
            } else { d2 = d; i2 = j; }
        }
    }
    float w0 = 1.0f / fmaxf(d0, 1e-16f);
    float w1 = 1.0f / fmaxf(d1, 1e-16f);
    float w2 = 1.0f / fmaxf(d2, 1e-16f);
    float s = 1.0f / (w0 + w1 + w2);
    knn_idx[t * 3 + 0] = i0; knn_idx[t * 3 + 1] = i1; knn_idx[t * 3 + 2] = i2;
    knn_w[t * 3 + 0] = w0 * s; knn_w[t * 3 + 1] = w1 * s; knn_w[t * 3 + 2] = w2 * s;
}

// ---------------------------------------------------------------------------
// K2: apply knn interpolation: out[t] = sum_k w[t][k] * x[idx[t][k]]
// one thread per (t, 4-channel group)
// ---------------------------------------------------------------------------
template <int C>
__global__ __launch_bounds__(256) void interp_kernel(
    const float* __restrict__ x, const int* __restrict__ knn_idx,
    const float* __restrict__ knn_w, float* __restrict__ out) {
    int tid = blockIdx.x * blockDim.x + threadIdx.x;
    int t = tid / (C / 4);
    int c4 = tid % (C / 4);
    int i0 = knn_idx[t * 3 + 0], i1 = knn_idx[t * 3 + 1], i2 = knn_idx[t * 3 + 2];
    float w0 = knn_w[t * 3 + 0], w1 = knn_w[t * 3 + 1], w2 = knn_w[t * 3 + 2];
    float4 a = ((const float4*)(x + (size_t)i0 * C))[c4];
    float4 b = ((const float4*)(x + (size_t)i1 * C))[c4];
    float4 c = ((const float4*)(x + (size_t)i2 * C))[c4];
    float4 r;
    r.x = w0 * a.x + w1 * b.x + w2 * c.x;
    r.y = w0 * a.y + w1 * b.y + w2 * c.y;
    r.z = w0 * a.z + w1 * b.z + w2 * c.z;
    r.w = w0 * a.w + w1 * b.w + w2 * c.w;
    ((float4*)(out + (size_t)t * C))[c4] = r;
}

// ---------------------------------------------------------------------------
// K3: fused MLP GEMM.
//   EDGE=true : rows = edges; A[e] = concat(X1[src[e]], X2[dst[e]]) (C1==C2),
//               epilogue scatter: atomicAdd(out[dst[e]], selu(acc+bias))
//   EDGE=false: rows = nodes; A[n] = concat(X1[n] (C1), X2[n] (C2)),
//               epilogue store: out[n] = selu(acc+bias)
// Tiled fp32 GEMM: BM=64 rows, BK=32, full COUT width, 256 threads,
// thread computes 4 rows x TN cols.
// ---------------------------------------------------------------------------
template <int C1, int C2, int COUTT, bool EDGE>
__global__ __launch_bounds__(256) void mlp_kernel(
    const float* __restrict__ X1, const float* __restrict__ X2,
    const int* __restrict__ ei, const float* __restrict__ W,
    const float* __restrict__ bias, float* __restrict__ out, int M) {
    constexpr int K = C1 + C2;
    constexpr int BM = 64, BK = 32;
    constexpr int TN = COUTT / 16;
    constexpr int NCH = K / BK;

    __shared__ float As[BK][BM + 8];   // transposed A tile, padded
    __shared__ float Bs[BK][COUTT];
    __shared__ int r1s[BM], r2s[BM];

    const int tid = threadIdx.x;
    const int e0 = blockIdx.x * BM;

    if (tid < BM) {
        int e = e0 + tid;
        if constexpr (EDGE) {
            r1s[tid] = ei[e];        // src
            r2s[tid] = ei[M + e];    // dst
        } else {
            r1s[tid] = e;
            r2s[tid] = e;
        }
    }
    __syncthreads();

    float acc[4][TN];
#pragma unroll
    for (int i = 0; i < 4; ++i)
#pragma unroll
        for (int j = 0; j < TN; ++j) acc[i][j] = 0.0f;

    const int lr = tid & 63;    // staging row
    const int kq = tid >> 6;    // staging k-quad (8 floats each)
    const int tx = tid & 15;    // compute col group
    const int ty = tid >> 4;    // compute row group

    for (int ch = 0; ch < NCH; ++ch) {
        const int k0 = ch * BK;
        // --- stage A (gathered) ---
        {
            const float* base;
            if (k0 < C1) base = X1 + (size_t)r1s[lr] * C1 + k0;
            else         base = X2 + (size_t)r2s[lr] * C2 + (k0 - C1);
            const float4 v0 = *(const float4*)(base + kq * 8);
            const float4 v1 = *(const float4*)(base + kq * 8 + 4);
            const int kb = kq * 8;
            As[kb + 0][lr] = v0.x; As[kb + 1][lr] = v0.y;
            As[kb + 2][lr] = v0.z; As[kb + 3][lr] = v0.w;
            As[kb + 4][lr] = v1.x; As[kb + 5][lr] = v1.y;
            As[kb + 6][lr] = v1.z; As[kb + 7][lr] = v1.w;
        }
        // --- stage B (contiguous chunk of W) ---
        {
            const float4* wsrc = (const float4*)(W + (size_t)k0 * COUTT);
            float4* bdst = (float4*)&Bs[0][0];
#pragma unroll
            for (int j = 0; j < (BK * COUTT) / (4 * 256); ++j)
                bdst[tid + j * 256] = wsrc[tid + j * 256];
        }
        __syncthreads();
        // --- compute ---
#pragma unroll
        for (int kk = 0; kk < BK; ++kk) {
            float a[4];
            *(float4*)a = *(const float4*)&As[kk][ty * 4];
            float b[TN];
#pragma unroll
            for (int j = 0; j < TN; j += 4)
                *(float4*)&b[j] = *(const float4*)&Bs[kk][tx * TN + j];
#pragma unroll
            for (int i = 0; i < 4; ++i)
#pragma unroll
                for (int j = 0; j < TN; ++j)
                    acc[i][j] += a[i] * b[j];
        }
        __syncthreads();
    }

    // --- epilogue ---
#pragma unroll
    for (int i = 0; i < 4; ++i) {
        const int row = ty * 4 + i;
#pragma unroll
        for (int j = 0; j < TN; ++j) {
            const int col = tx * TN + j;
            float v = selu_f(acc[i][j] + bias[col]);
            if constexpr (EDGE) {
                atomicAdd(&out[(size_t)r2s[row] * COUTT + col], v);
            } else {
                out[(size_t)(e0 + row) * COUTT + col] = v;
            }
        }
    }
}

// ---------------------------------------------------------------------------
// K4: residual add + per-channel sum/sumsq (BN stats). Writes pre-BN value
// into d_out; accumulates stats[0..127]=sum, stats[128..255]=sumsq.
// Grid-stride with stride a multiple of 128 -> each thread owns one channel.
// ---------------------------------------------------------------------------
__global__ __launch_bounds__(256) void stats_kernel(
    const float* __restrict__ h2, const float* __restrict__ xs,
    float* __restrict__ pre, float* __restrict__ stats, int total) {
    const int stride = gridDim.x * blockDim.x;
    const int i0 = blockIdx.x * blockDim.x + threadIdx.x;
    float s = 0.0f, sq = 0.0f;
    for (int i = i0; i < total; i += stride) {
        float v = h2[i] + xs[i];
        pre[i] = v;
        s += v;
        sq += v * v;
    }
    __shared__ float ls[256], lq[256];
    ls[threadIdx.x] = s; lq[threadIdx.x] = sq;
    __syncthreads();
    if (threadIdx.x < 128) {
        float a = ls[threadIdx.x] + ls[threadIdx.x + 128];
        float b = lq[threadIdx.x] + lq[threadIdx.x + 128];
        int c = i0 & 127;
        atomicAdd(&stats[c], a);
        atomicAdd(&stats[128 + c], b);
    }
}

// ---------------------------------------------------------------------------
// K5: BN normalize + SELU, in place on d_out.
// ---------------------------------------------------------------------------
__global__ __launch_bounds__(256) void bn_kernel(
    float* __restrict__ out, const float* __restrict__ stats,
    const float* __restrict__ gamma, const float* __restrict__ beta, int Nn) {
    const int i = blockIdx.x * blockDim.x + threadIdx.x;
    const int c = i & 127;
    const float invn = 1.0f / (float)Nn;
    float mu = stats[c] * invn;
    float var = stats[128 + c] * invn - mu * mu;
    float r = rsqrtf(var + 1e-5f);
    float v = (out[i] - mu) * r * gamma[c] + beta[c];
    out[i] = selu_f(v);
}

// ---------------------------------------------------------------------------
extern "C" void kernel_launch(void* const* d_in, const int* in_sizes, int n_in,
                              void* d_out, int out_size, void* d_ws, size_t ws_size,
                              hipStream_t stream) {
    const float* x     = (const float*)d_in[0];
    const float* pos_c = (const float*)d_in[1];
    const float* pos_f = (const float*)d_in[2];
    const int*   ei_c  = (const int*)d_in[3];
    const int*   ei_f  = (const int*)d_in[4];
    const float* We1 = (const float*)d_in[5];
    const float* be1 = (const float*)d_in[6];
    const float* Wn1 = (const float*)d_in[7];
    const float* bn1 = (const float*)d_in[8];
    const float* We2 = (const float*)d_in[9];
    const float* be2 = (const float*)d_in[10];
    const float* Wn2 = (const float*)d_in[11];
    const float* bn2 = (const float*)d_in[12];
    const float* WeS = (const float*)d_in[13];
    const float* beS = (const float*)d_in[14];
    const float* WnS = (const float*)d_in[15];
    const float* bnS = (const float*)d_in[16];
    const float* gamma = (const float*)d_in[17];
    const float* beta  = (const float*)d_in[18];

    // workspace layout
    char* w = (char*)d_ws;
    size_t o = 0;
    int*   knn_idx = (int*)(w + o);   o += (size_t)NF * 3 * sizeof(int);
    float* knn_w   = (float*)(w + o); o += (size_t)NF * 3 * sizeof(float);
    float* x_up    = (float*)(w + o); o += (size_t)NF * CIN * sizeof(float);
    float* aggD    = (float*)(w + o); o += (size_t)NF * CO * sizeof(float);
    float* x_skip  = (float*)(w + o); o += (size_t)NF * CO * sizeof(float);
    float* h1      = (float*)(w + o); o += (size_t)NC * CH * sizeof(float);
    float* agg1    = (float*)(w + o); o += (size_t)NC * CH * sizeof(float);
    float* h_up    = (float*)(w + o); o += (size_t)NF * CH * sizeof(float);
    float* stats   = (float*)(w + o); o += 256 * sizeof(float);
    float* h2 = x_up;  // x_up dead after skip-node MLP; reuse for h2
    float* outp = (float*)d_out;

    hipMemsetAsync(agg1, 0, (size_t)NC * CH * sizeof(float), stream);
    hipMemsetAsync(aggD, 0, (size_t)NF * CO * sizeof(float), stream);
    hipMemsetAsync(stats, 0, 256 * sizeof(float), stream);

    // kNN (shared by both interpolations)
    knn_kernel<<<NF / 256, 256, 0, stream>>>(pos_c, pos_f, knn_idx, knn_w);

    // skip branch
    interp_kernel<128><<<NF * (128 / 4) / 256, 256, 0, stream>>>(x, knn_idx, knn_w, x_up);
    mlp_kernel<128, 128, 128, true><<<EF / 64, 256, 0, stream>>>(
        x_up, x_up, ei_f, WeS, beS, aggD, EF);
    mlp_kernel<128, 128, 128, false><<<NF / 64, 256, 0, stream>>>(
        x_up, aggD, nullptr, WnS, bnS, x_skip, NF);

    // main branch: coarse MPL
    mlp_kernel<128, 128, 64, true><<<EC / 64, 256, 0, stream>>>(
        x, x, ei_c, We1, be1, agg1, EC);
    mlp_kernel<128, 64, 64, false><<<NC / 64, 256, 0, stream>>>(
        x, agg1, nullptr, Wn1, bn1, h1, NC);

    // upsample h1
    interp_kernel<64><<<NF * (64 / 4) / 256, 256, 0, stream>>>(h1, knn_idx, knn_w, h_up);

    // fine MPL
    hipMemsetAsync(aggD, 0, (size_t)NF * CO * sizeof(float), stream);
    mlp_kernel<64, 64, 128, true><<<EF / 64, 256, 0, stream>>>(
        h_up, h_up, ei_f, We2, be2, aggD, EF);
    mlp_kernel<64, 128, 128, false><<<NF / 64, 256, 0, stream>>>(
        h_up, aggD, nullptr, Wn2, bn2, h2, NF);

    // residual + BN + SELU
    stats_kernel<<<256, 256, 0, stream>>>(h2, x_skip, outp, stats, NF * CO);
    bn_kernel<<<NF * CO / 256, 256, 0, stream>>>(outp, stats, gamma, beta, NF);
}

// Round 2
// 617.397 us; speedup vs baseline: 3.7672x; 3.7672x over previous
//
#include <hip/hip_runtime.h>

// ---------------------------------------------------------------------------
// Res_up block, round 2: edge MLP decomposed as selu(P[src]+Q[dst]+be) with
// P=X@We_top, Q=X@We_bot (node GEMMs), edges counting-sorted by dst, and
// aggregation as a wave-per-node gather-reduce (no atomics).
// Sizes fixed: Nc=4096, Nf=16384, Ec=65536, Ef=262144, Cin=128, Ch=64, Co=128.
// ---------------------------------------------------------------------------

#define SELU_SCALE 1.0507009873554805f
#define SELU_ALPHA 1.6732632423543772f

static constexpr int NC = 4096, NF = 16384, EC = 65536, EF = 262144;
static constexpr int CIN = 128, CH = 64, CO = 128;

__device__ __forceinline__ float selu_f(float x) {
    return x > 0.0f ? SELU_SCALE * x
                    : SELU_SCALE * SELU_ALPHA * (__expf(x) - 1.0f);
}

// ---------------------------------------------------------------------------
// K1: brute-force kNN (k=3) of pos_f against pos_c; pre-normalized weights.
// ---------------------------------------------------------------------------
__global__ __launch_bounds__(256) void knn_kernel(
    const float* __restrict__ pos_c, const float* __restrict__ pos_f,
    int* __restrict__ knn_idx, float* __restrict__ knn_w) {
    __shared__ float2 spos[NC];
    for (int i = threadIdx.x; i < NC; i += blockDim.x)
        spos[i] = ((const float2*)pos_c)[i];
    __syncthreads();

    int t = blockIdx.x * blockDim.x + threadIdx.x;
    float2 p = ((const float2*)pos_f)[t];

    float d0 = 1e30f, d1 = 1e30f, d2 = 1e30f;
    int i0 = 0, i1 = 0, i2 = 0;
    for (int j = 0; j < NC; ++j) {
        float dx = p.x - spos[j].x;
        float dy = p.y - spos[j].y;
        float d = dx * dx + dy * dy;
        if (d < d2) {
            if (d < d1) {
                d2 = d1; i2 = i1;
                if (d < d0) { d1 = d0; i1 = i0; d0 = d; i0 = j; }
                else        { d1 = d;  i1 = j; }
            } else { d2 = d; i2 = j; }
        }
    }
    float w0 = 1.0f / fmaxf(d0, 1e-16f);
    float w1 = 1.0f / fmaxf(d1, 1e-16f);
    float w2 = 1.0f / fmaxf(d2, 1e-16f);
    float s = 1.0f / (w0 + w1 + w2);
    knn_idx[t * 3 + 0] = i0; knn_idx[t * 3 + 1] = i1; knn_idx[t * 3 + 2] = i2;
    knn_w[t * 3 + 0] = w0 * s; knn_w[t * 3 + 1] = w1 * s; knn_w[t * 3 + 2] = w2 * s;
}

// ---------------------------------------------------------------------------
// K2: apply knn interpolation. one thread per (t, 4-channel group)
// ---------------------------------------------------------------------------
template <int C>
__global__ __launch_bounds__(256) void interp_kernel(
    const float* __restrict__ x, const int* __restrict__ knn_idx,
    const float* __restrict__ knn_w, float* __restrict__ out) {
    int tid = blockIdx.x * blockDim.x + threadIdx.x;
    int t = tid / (C / 4);
    int c4 = tid % (C / 4);
    int i0 = knn_idx[t * 3 + 0], i1 = knn_idx[t * 3 + 1], i2 = knn_idx[t * 3 + 2];
    float w0 = knn_w[t * 3 + 0], w1 = knn_w[t * 3 + 1], w2 = knn_w[t * 3 + 2];
    float4 a = ((const float4*)(x + (size_t)i0 * C))[c4];
    float4 b = ((const float4*)(x + (size_t)i1 * C))[c4];
    float4 c = ((const float4*)(x + (size_t)i2 * C))[c4];
    float4 r;
    r.x = w0 * a.x + w1 * b.x + w2 * c.x;
    r.y = w0 * a.y + w1 * b.y + w2 * c.y;
    r.z = w0 * a.z + w1 * b.z + w2 * c.z;
    r.w = w0 * a.w + w1 * b.w + w2 * c.w;
    ((float4*)(out + (size_t)t * C))[c4] = r;
}

// ---------------------------------------------------------------------------
// Edge counting-sort by dst: histogram -> single-block scan -> scatter.
// ---------------------------------------------------------------------------
__global__ __launch_bounds__(256) void hist_kernel(
    const int* __restrict__ ei, int* __restrict__ cnt, int M) {
    int e = blockIdx.x * blockDim.x + threadIdx.x;
    if (e < M) atomicAdd(&cnt[ei[M + e]], 1);
}

template <int NN>
__global__ __launch_bounds__(1024) void scan_kernel(
    const int* __restrict__ cnt, int* __restrict__ base, int* __restrict__ curs) {
    constexpr int IT = NN / 1024;
    __shared__ int part[1024];
    const int t = threadIdx.x;
    int loc[IT];
    int s = 0;
#pragma unroll
    for (int i = 0; i < IT; ++i) { loc[i] = cnt[t * IT + i]; s += loc[i]; }
    part[t] = s;
    __syncthreads();
    for (int off = 1; off < 1024; off <<= 1) {
        int v = part[t];
        int u = (t >= off) ? part[t - off] : 0;
        __syncthreads();
        part[t] = v + u;
        __syncthreads();
    }
    int ex = (t == 0) ? 0 : part[t - 1];
#pragma unroll
    for (int i = 0; i < IT; ++i) {
        base[t * IT + i] = ex;
        curs[t * IT + i] = ex;
        ex += loc[i];
    }
    if (t == 1023) base[NN] = ex;
}

__global__ __launch_bounds__(256) void scatter_kernel(
    const int* __restrict__ ei, int* __restrict__ curs,
    int* __restrict__ sorted_src, int M) {
    int e = blockIdx.x * blockDim.x + threadIdx.x;
    if (e < M) {
        int dst = ei[M + e];
        int pos = atomicAdd(&curs[dst], 1);
        sorted_src[pos] = ei[e];
    }
}

// ---------------------------------------------------------------------------
// K3: PQ GEMM.  PQ[n][0:COUT] = X[n] @ We[0:K,:],  PQ[n][COUT:2C] = X[n] @ We[K:2K,:]
// (bias NOT added here; added once per node in agg).
// BM=64 rows, BK=32, 256 threads, thread computes 4 rows x TN cols.
// ---------------------------------------------------------------------------
template <int K, int COUT>
__global__ __launch_bounds__(256) void pq_kernel(
    const float* __restrict__ X, const float* __restrict__ We,
    float* __restrict__ PQ) {
    constexpr int N2 = 2 * COUT;
    constexpr int BM = 64, BK = 32;
    constexpr int TN = N2 / 16;
    constexpr int NCH = K / BK;

    __shared__ float As[BK][BM + 8];
    __shared__ float Bs[BK][N2];

    const int tid = threadIdx.x;
    const int e0 = blockIdx.x * BM;

    float acc[4][TN];
#pragma unroll
    for (int i = 0; i < 4; ++i)
#pragma unroll
        for (int j = 0; j < TN; ++j) acc[i][j] = 0.0f;

    const int lr = tid & 63;
    const int kq = tid >> 6;
    const int tx = tid & 15;
    const int ty = tid >> 4;

    for (int ch = 0; ch < NCH; ++ch) {
        const int k0 = ch * BK;
        // stage A (rows contiguous)
        {
            const float* base = X + (size_t)(e0 + lr) * K + k0;
            const float4 v0 = *(const float4*)(base + kq * 8);
            const float4 v1 = *(const float4*)(base + kq * 8 + 4);
            const int kb = kq * 8;
            As[kb + 0][lr] = v0.x; As[kb + 1][lr] = v0.y;
            As[kb + 2][lr] = v0.z; As[kb + 3][lr] = v0.w;
            As[kb + 4][lr] = v1.x; As[kb + 5][lr] = v1.y;
            As[kb + 6][lr] = v1.z; As[kb + 7][lr] = v1.w;
        }
        // stage B: Bs[kk][j] = (j<COUT) ? We[k0+kk][j] : We[K+k0+kk][j-COUT]
        {
            constexpr int F4 = BK * N2 / 4;
#pragma unroll
            for (int q = tid; q < F4; q += 256) {
                const int kk = q / (N2 / 4);
                const int j = (q % (N2 / 4)) * 4;
                const float* src = (j < COUT)
                    ? (We + (size_t)(k0 + kk) * COUT + j)
                    : (We + (size_t)(K + k0 + kk) * COUT + (j - COUT));
                *(float4*)&Bs[kk][j] = *(const float4*)src;
            }
        }
        __syncthreads();
#pragma unroll
        for (int kk = 0; kk < BK; ++kk) {
            float a[4];
            *(float4*)a = *(const float4*)&As[kk][ty * 4];
            float b[TN];
#pragma unroll
            for (int j = 0; j < TN; j += 4)
                *(float4*)&b[j] = *(const float4*)&Bs[kk][tx * TN + j];
#pragma unroll
            for (int i = 0; i < 4; ++i)
#pragma unroll
                for (int j = 0; j < TN; ++j)
                    acc[i][j] += a[i] * b[j];
        }
        __syncthreads();
    }
#pragma unroll
    for (int i = 0; i < 4; ++i)
#pragma unroll
        for (int j = 0; j < TN; ++j)
            PQ[(size_t)(e0 + ty * 4 + i) * N2 + tx * TN + j] = acc[i][j];
}

// ---------------------------------------------------------------------------
// K4: aggregation, one wave per dst node:
//   agg[n] = sum_{e in bucket(n)} selu(P[src_e] + Q[n] + be)
// ---------------------------------------------------------------------------
template <int COUT>
__global__ __launch_bounds__(256) void agg_kernel(
    const float* __restrict__ PQ, const int* __restrict__ base,
    const int* __restrict__ sorted_src, const float* __restrict__ be,
    float* __restrict__ agg, int NN) {
    const int gid = blockIdx.x * blockDim.x + threadIdx.x;
    const int n = gid >> 6;
    const int lane = gid & 63;
    if (n >= NN) return;
    const int b0 = base[n], b1 = base[n + 1];

    if constexpr (COUT == 128) {
        float2 qv = *(const float2*)(PQ + (size_t)n * 256 + 128 + lane * 2);
        float2 bv = *(const float2*)(be + lane * 2);
        const float qx = qv.x + bv.x, qy = qv.y + bv.y;
        float ax = 0.0f, ay = 0.0f;
        for (int e = b0; e < b1; ++e) {
            const int src = sorted_src[e];
            float2 p = *(const float2*)(PQ + (size_t)src * 256 + lane * 2);
            ax += selu_f(p.x + qx);
            ay += selu_f(p.y + qy);
        }
        float2 r; r.x = ax; r.y = ay;
        *(float2*)(agg + (size_t)n * 128 + lane * 2) = r;
    } else {
        const float q = PQ[(size_t)n * (2 * COUT) + COUT + lane] + be[lane];
        float a = 0.0f;
        for (int e = b0; e < b1; ++e) {
            const int src = sorted_src[e];
            a += selu_f(PQ[(size_t)src * (2 * COUT) + lane] + q);
        }
        agg[(size_t)n * COUT + lane] = a;
    }
}

// ---------------------------------------------------------------------------
// K5: node MLP GEMM: out[n] = selu(concat(X1[n] (C1), X2[n] (C2)) @ W + b)
// ---------------------------------------------------------------------------
template <int C1, int C2, int COUTT>
__global__ __launch_bounds__(256) void node_mlp_kernel(
    const float* __restrict__ X1, const float* __restrict__ X2,
    const float* __restrict__ W, const float* __restrict__ bias,
    float* __restrict__ out) {
    constexpr int K = C1 + C2;
    constexpr int BM = 64, BK = 32;
    constexpr int TN = COUTT / 16;
    constexpr int NCH = K / BK;

    __shared__ float As[BK][BM + 8];
    __shared__ float Bs[BK][COUTT];

    const int tid = threadIdx.x;
    const int e0 = blockIdx.x * BM;

    float acc[4][TN];
#pragma unroll
    for (int i = 0; i < 4; ++i)
#pragma unroll
        for (int j = 0; j < TN; ++j) acc[i][j] = 0.0f;

    const int lr = tid & 63;
    const int kq = tid >> 6;
    const int tx = tid & 15;
    const int ty = tid >> 4;

    for (int ch = 0; ch < NCH; ++ch) {
        const int k0 = ch * BK;
        {
            const float* base;
            if (k0 < C1) base = X1 + (size_t)(e0 + lr) * C1 + k0;
            else         base = X2 + (size_t)(e0 + lr) * C2 + (k0 - C1);
            const float4 v0 = *(const float4*)(base + kq * 8);
            const float4 v1 = *(const float4*)(base + kq * 8 + 4);
            const int kb = kq * 8;
            As[kb + 0][lr] = v0.x; As[kb + 1][lr] = v0.y;
            As[kb + 2][lr] = v0.z; As[kb + 3][lr] = v0.w;
            As[kb + 4][lr] = v1.x; As[kb + 5][lr] = v1.y;
            As[kb + 6][lr] = v1.z; As[kb + 7][lr] = v1.w;
        }
        {
            const float4* wsrc = (const float4*)(W + (size_t)k0 * COUTT);
            float4* bdst = (float4*)&Bs[0][0];
#pragma unroll
            for (int j = 0; j < (BK * COUTT) / (4 * 256); ++j)
                bdst[tid + j * 256] = wsrc[tid + j * 256];
        }
        __syncthreads();
#pragma unroll
        for (int kk = 0; kk < BK; ++kk) {
            float a[4];
            *(float4*)a = *(const float4*)&As[kk][ty * 4];
            float b[TN];
#pragma unroll
            for (int j = 0; j < TN; j += 4)
                *(float4*)&b[j] = *(const float4*)&Bs[kk][tx * TN + j];
#pragma unroll
            for (int i = 0; i < 4; ++i)
#pragma unroll
                for (int j = 0; j < TN; ++j)
                    acc[i][j] += a[i] * b[j];
        }
        __syncthreads();
    }
#pragma unroll
    for (int i = 0; i < 4; ++i)
#pragma unroll
        for (int j = 0; j < TN; ++j) {
            const int col = tx * TN + j;
            out[(size_t)(e0 + ty * 4 + i) * COUTT + col] =
                selu_f(acc[i][j] + bias[col]);
        }
}

// ---------------------------------------------------------------------------
// K6: residual add + per-channel sum/sumsq (BN stats); pre-BN value -> d_out.
// ---------------------------------------------------------------------------
__global__ __launch_bounds__(256) void stats_kernel(
    const float* __restrict__ h2, float* __restrict__ pre,
    float* __restrict__ stats, int total) {
    const int stride = gridDim.x * blockDim.x;
    const int i0 = blockIdx.x * blockDim.x + threadIdx.x;
    float s = 0.0f, sq = 0.0f;
    for (int i = i0; i < total; i += stride) {
        float v = h2[i] + pre[i];   // pre currently holds x_skip
        pre[i] = v;
        s += v;
        sq += v * v;
    }
    __shared__ float ls[256], lq[256];
    ls[threadIdx.x] = s; lq[threadIdx.x] = sq;
    __syncthreads();
    if (threadIdx.x < 128) {
        float a = ls[threadIdx.x] + ls[threadIdx.x + 128];
        float b = lq[threadIdx.x] + lq[threadIdx.x + 128];
        int c = i0 & 127;
        atomicAdd(&stats[c], a);
        atomicAdd(&stats[128 + c], b);
    }
}

// ---------------------------------------------------------------------------
// K7: BN normalize + SELU, in place on d_out.
// ---------------------------------------------------------------------------
__global__ __launch_bounds__(256) void bn_kernel(
    float* __restrict__ out, const float* __restrict__ stats,
    const float* __restrict__ gamma, const float* __restrict__ beta, int Nn) {
    const int i = blockIdx.x * blockDim.x + threadIdx.x;
    const int c = i & 127;
    const float invn = 1.0f / (float)Nn;
    float mu = stats[c] * invn;
    float var = stats[128 + c] * invn - mu * mu;
    float r = rsqrtf(var + 1e-5f);
    float v = (out[i] - mu) * r * gamma[c] + beta[c];
    out[i] = selu_f(v);
}

// ---------------------------------------------------------------------------
extern "C" void kernel_launch(void* const* d_in, const int* in_sizes, int n_in,
                              void* d_out, int out_size, void* d_ws, size_t ws_size,
                              hipStream_t stream) {
    const float* x     = (const float*)d_in[0];
    const float* pos_c = (const float*)d_in[1];
    const float* pos_f = (const float*)d_in[2];
    const int*   ei_c  = (const int*)d_in[3];
    const int*   ei_f  = (const int*)d_in[4];
    const float* We1 = (const float*)d_in[5];
    const float* be1 = (const float*)d_in[6];
    const float* Wn1 = (const float*)d_in[7];
    const float* bn1 = (const float*)d_in[8];
    const float* We2 = (const float*)d_in[9];
    const float* be2 = (const float*)d_in[10];
    const float* Wn2 = (const float*)d_in[11];
    const float* bn2 = (const float*)d_in[12];
    const float* WeS = (const float*)d_in[13];
    const float* beS = (const float*)d_in[14];
    const float* WnS = (const float*)d_in[15];
    const float* bnS = (const float*)d_in[16];
    const float* gamma = (const float*)d_in[17];
    const float* beta  = (const float*)d_in[18];

    // workspace layout
    char* w = (char*)d_ws;
    size_t o = 0;
    auto alloc = [&](size_t bytes) { void* p = w + o; o += (bytes + 255) & ~(size_t)255; return p; };
    int*   knn_idx = (int*)alloc((size_t)NF * 3 * sizeof(int));
    float* knn_w   = (float*)alloc((size_t)NF * 3 * sizeof(float));
    float* x_up    = (float*)alloc((size_t)NF * CIN * sizeof(float));   // later reused as h2
    float* PQ      = (float*)alloc((size_t)NF * 2 * CO * sizeof(float)); // shared by all 3 edge MLPs
    float* aggF    = (float*)alloc((size_t)NF * CO * sizeof(float));     // shared skip/mpl2
    float* h1      = (float*)alloc((size_t)NC * CH * sizeof(float));
    float* agg1    = (float*)alloc((size_t)NC * CH * sizeof(float));
    float* h_up    = (float*)alloc((size_t)NF * CH * sizeof(float));
    int*   cntF    = (int*)alloc((size_t)NF * sizeof(int));
    int*   baseF   = (int*)alloc((size_t)(NF + 1) * sizeof(int));
    int*   cursF   = (int*)alloc((size_t)NF * sizeof(int));
    int*   srtF    = (int*)alloc((size_t)EF * sizeof(int));
    int*   cntC    = (int*)alloc((size_t)NC * sizeof(int));
    int*   baseC   = (int*)alloc((size_t)(NC + 1) * sizeof(int));
    int*   cursC   = (int*)alloc((size_t)NC * sizeof(int));
    int*   srtC    = (int*)alloc((size_t)EC * sizeof(int));
    float* stats   = (float*)alloc(256 * sizeof(float));
    float* h2 = x_up;            // x_up dead after skip node MLP
    float* outp = (float*)d_out; // holds x_skip, then pre-BN, then final

    hipMemsetAsync(cntF, 0, (size_t)NF * sizeof(int), stream);
    hipMemsetAsync(cntC, 0, (size_t)NC * sizeof(int), stream);
    hipMemsetAsync(stats, 0, 256 * sizeof(float), stream);

    // kNN (shared by both interpolations)
    knn_kernel<<<NF / 256, 256, 0, stream>>>(pos_c, pos_f, knn_idx, knn_w);
    interp_kernel<128><<<NF * (128 / 4) / 256, 256, 0, stream>>>(x, knn_idx, knn_w, x_up);

    // sort fine + coarse edge lists by dst
    hist_kernel<<<EF / 256, 256, 0, stream>>>(ei_f, cntF, EF);
    scan_kernel<NF><<<1, 1024, 0, stream>>>(cntF, baseF, cursF);
    scatter_kernel<<<EF / 256, 256, 0, stream>>>(ei_f, cursF, srtF, EF);
    hist_kernel<<<EC / 256, 256, 0, stream>>>(ei_c, cntC, EC);
    scan_kernel<NC><<<1, 1024, 0, stream>>>(cntC, baseC, cursC);
    scatter_kernel<<<EC / 256, 256, 0, stream>>>(ei_c, cursC, srtC, EC);

    // --- skip branch (fine graph, Cin->Cout) ---
    pq_kernel<128, 128><<<NF / 64, 256, 0, stream>>>(x_up, WeS, PQ);
    agg_kernel<128><<<NF / 4, 256, 0, stream>>>(PQ, baseF, srtF, beS, aggF, NF);
    node_mlp_kernel<128, 128, 128><<<NF / 64, 256, 0, stream>>>(
        x_up, aggF, WnS, bnS, outp);                    // outp = x_skip

    // --- coarse MPL (Cin->Ch) ---
    pq_kernel<128, 64><<<NC / 64, 256, 0, stream>>>(x, We1, PQ);
    agg_kernel<64><<<NC / 4, 256, 0, stream>>>(PQ, baseC, srtC, be1, agg1, NC);
    node_mlp_kernel<128, 64, 64><<<NC / 64, 256, 0, stream>>>(x, agg1, Wn1, bn1, h1);

    // upsample h1 -> h_up
    interp_kernel<64><<<NF * (64 / 4) / 256, 256, 0, stream>>>(h1, knn_idx, knn_w, h_up);

    // --- fine MPL (Ch->Cout) ---
    pq_kernel<64, 128><<<NF / 64, 256, 0, stream>>>(h_up, We2, PQ);
    agg_kernel<128><<<NF / 4, 256, 0, stream>>>(PQ, baseF, srtF, be2, aggF, NF);
    node_mlp_kernel<64, 128, 128><<<NF / 64, 256, 0, stream>>>(h_up, aggF, Wn2, bn2, h2);

    // residual + BN + SELU (x_skip already in d_out)
    stats_kernel<<<256, 256, 0, stream>>>(h2, outp, stats, NF * CO);
    bn_kernel<<<NF * CO / 256, 256, 0, stream>>>(outp, stats, gamma, beta, NF);
}

// Round 3
// 376.097 us; speedup vs baseline: 6.1841x; 1.6416x over previous
//
#include <hip/hip_runtime.h>

// ---------------------------------------------------------------------------
// Res_up block, round 3: kNN re-parallelized to one wave per fine point
// (64-lane strided scan + shfl_xor butterfly top-3 merge). Rest unchanged
// from round 2 (edge MLP as selu(P[src]+Q[dst]+be), counting-sorted gather
// aggregation, fp32 tiled GEMMs).
// Sizes fixed: Nc=4096, Nf=16384, Ec=65536, Ef=262144, Cin=128, Ch=64, Co=128.
// ---------------------------------------------------------------------------

#define SELU_SCALE 1.0507009873554805f
#define SELU_ALPHA 1.6732632423543772f

static constexpr int NC = 4096, NF = 16384, EC = 65536, EF = 262144;
static constexpr int CIN = 128, CH = 64, CO = 128;

__device__ __forceinline__ float selu_f(float x) {
    return x > 0.0f ? SELU_SCALE * x
                    : SELU_SCALE * SELU_ALPHA * (__expf(x) - 1.0f);
}

// ---------------------------------------------------------------------------
// K1: kNN (k=3), one wave per fine point. Lane l scans coarse points
// j = l + 64k; per-lane top-3 kept sorted by (d, idx); butterfly merge.
// ---------------------------------------------------------------------------
__device__ __forceinline__ bool knn_less(float da, int ia, float db, int ib) {
    return da < db || (da == db && ia < ib);
}

__global__ __launch_bounds__(256) void knn_kernel(
    const float* __restrict__ pos_c, const float* __restrict__ pos_f,
    int* __restrict__ knn_idx, float* __restrict__ knn_w) {
    __shared__ float2 spos[NC];
    for (int i = threadIdx.x; i < NC; i += 256)
        spos[i] = ((const float2*)pos_c)[i];
    __syncthreads();

    const int wid = threadIdx.x >> 6;
    const int lane = threadIdx.x & 63;
    const int t = blockIdx.x * 4 + wid;
    const float2 p = ((const float2*)pos_f)[t];

    float d0 = 1e30f, d1 = 1e30f, d2 = 1e30f;
    int i0 = 0x7fffffff, i1 = 0x7fffffff, i2 = 0x7fffffff;
#pragma unroll 4
    for (int k = 0; k < NC / 64; ++k) {
        const int j = lane + k * 64;
        const float dx = p.x - spos[j].x;
        const float dy = p.y - spos[j].y;
        const float d = dx * dx + dy * dy;
        if (d < d2) {                       // strict < : keeps lower j in-lane
            if (d < d1) {
                d2 = d1; i2 = i1;
                if (d < d0) { d1 = d0; i1 = i0; d0 = d; i0 = j; }
                else        { d1 = d;  i1 = j; }
            } else { d2 = d; i2 = j; }
        }
    }

    // butterfly merge of per-lane top-3 (lexicographic (d, idx))
#pragma unroll
    for (int m = 1; m < 64; m <<= 1) {
        float e0 = __shfl_xor(d0, m), e1 = __shfl_xor(d1, m), e2 = __shfl_xor(d2, m);
        int   f0 = __shfl_xor(i0, m), f1 = __shfl_xor(i1, m), f2 = __shfl_xor(i2, m);
        float ed[3] = {e0, e1, e2};
        int   fi[3] = {f0, f1, f2};
#pragma unroll
        for (int q = 0; q < 3; ++q) {
            const float d = ed[q]; const int j = fi[q];
            if (knn_less(d, j, d2, i2)) {
                if (knn_less(d, j, d1, i1)) {
                    d2 = d1; i2 = i1;
                    if (knn_less(d, j, d0, i0)) { d1 = d0; i1 = i0; d0 = d; i0 = j; }
                    else                        { d1 = d;  i1 = j; }
                } else { d2 = d; i2 = j; }
            }
        }
    }

    if (lane == 0) {
        const float w0 = 1.0f / fmaxf(d0, 1e-16f);
        const float w1 = 1.0f / fmaxf(d1, 1e-16f);
        const float w2 = 1.0f / fmaxf(d2, 1e-16f);
        const float s = 1.0f / (w0 + w1 + w2);
        knn_idx[t * 3 + 0] = i0; knn_idx[t * 3 + 1] = i1; knn_idx[t * 3 + 2] = i2;
        knn_w[t * 3 + 0] = w0 * s; knn_w[t * 3 + 1] = w1 * s; knn_w[t * 3 + 2] = w2 * s;
    }
}

// ---------------------------------------------------------------------------
// K2: apply knn interpolation. one thread per (t, 4-channel group)
// ---------------------------------------------------------------------------
template <int C>
__global__ __launch_bounds__(256) void interp_kernel(
    const float* __restrict__ x, const int* __restrict__ knn_idx,
    const float* __restrict__ knn_w, float* __restrict__ out) {
    int tid = blockIdx.x * blockDim.x + threadIdx.x;
    int t = tid / (C / 4);
    int c4 = tid % (C / 4);
    int i0 = knn_idx[t * 3 + 0], i1 = knn_idx[t * 3 + 1], i2 = knn_idx[t * 3 + 2];
    float w0 = knn_w[t * 3 + 0], w1 = knn_w[t * 3 + 1], w2 = knn_w[t * 3 + 2];
    float4 a = ((const float4*)(x + (size_t)i0 * C))[c4];
    float4 b = ((const float4*)(x + (size_t)i1 * C))[c4];
    float4 c = ((const float4*)(x + (size_t)i2 * C))[c4];
    float4 r;
    r.x = w0 * a.x + w1 * b.x + w2 * c.x;
    r.y = w0 * a.y + w1 * b.y + w2 * c.y;
    r.z = w0 * a.z + w1 * b.z + w2 * c.z;
    r.w = w0 * a.w + w1 * b.w + w2 * c.w;
    ((float4*)(out + (size_t)t * C))[c4] = r;
}

// ---------------------------------------------------------------------------
// Edge counting-sort by dst: histogram -> single-block scan -> scatter.
// ---------------------------------------------------------------------------
__global__ __launch_bounds__(256) void hist_kernel(
    const int* __restrict__ ei, int* __restrict__ cnt, int M) {
    int e = blockIdx.x * blockDim.x + threadIdx.x;
    if (e < M) atomicAdd(&cnt[ei[M + e]], 1);
}

template <int NN>
__global__ __launch_bounds__(1024) void scan_kernel(
    const int* __restrict__ cnt, int* __restrict__ base, int* __restrict__ curs) {
    constexpr int IT = NN / 1024;
    __shared__ int part[1024];
    const int t = threadIdx.x;
    int loc[IT];
    int s = 0;
#pragma unroll
    for (int i = 0; i < IT; ++i) { loc[i] = cnt[t * IT + i]; s += loc[i]; }
    part[t] = s;
    __syncthreads();
    for (int off = 1; off < 1024; off <<= 1) {
        int v = part[t];
        int u = (t >= off) ? part[t - off] : 0;
        __syncthreads();
        part[t] = v + u;
        __syncthreads();
    }
    int ex = (t == 0) ? 0 : part[t - 1];
#pragma unroll
    for (int i = 0; i < IT; ++i) {
        base[t * IT + i] = ex;
        curs[t * IT + i] = ex;
        ex += loc[i];
    }
    if (t == 1023) base[NN] = ex;
}

__global__ __launch_bounds__(256) void scatter_kernel(
    const int* __restrict__ ei, int* __restrict__ curs,
    int* __restrict__ sorted_src, int M) {
    int e = blockIdx.x * blockDim.x + threadIdx.x;
    if (e < M) {
        int dst = ei[M + e];
        int pos = atomicAdd(&curs[dst], 1);
        sorted_src[pos] = ei[e];
    }
}

// ---------------------------------------------------------------------------
// K3: PQ GEMM.  PQ[n][0:COUT] = X[n] @ We[0:K,:],  PQ[n][COUT:2C] = X[n] @ We[K:2K,:]
// ---------------------------------------------------------------------------
template <int K, int COUT>
__global__ __launch_bounds__(256) void pq_kernel(
    const float* __restrict__ X, const float* __restrict__ We,
    float* __restrict__ PQ) {
    constexpr int N2 = 2 * COUT;
    constexpr int BM = 64, BK = 32;
    constexpr int TN = N2 / 16;
    constexpr int NCH = K / BK;

    __shared__ float As[BK][BM + 8];
    __shared__ float Bs[BK][N2];

    const int tid = threadIdx.x;
    const int e0 = blockIdx.x * BM;

    float acc[4][TN];
#pragma unroll
    for (int i = 0; i < 4; ++i)
#pragma unroll
        for (int j = 0; j < TN; ++j) acc[i][j] = 0.0f;

    const int lr = tid & 63;
    const int kq = tid >> 6;
    const int tx = tid & 15;
    const int ty = tid >> 4;

    for (int ch = 0; ch < NCH; ++ch) {
        const int k0 = ch * BK;
        {
            const float* base = X + (size_t)(e0 + lr) * K + k0;
            const float4 v0 = *(const float4*)(base + kq * 8);
            const float4 v1 = *(const float4*)(base + kq * 8 + 4);
            const int kb = kq * 8;
            As[kb + 0][lr] = v0.x; As[kb + 1][lr] = v0.y;
            As[kb + 2][lr] = v0.z; As[kb + 3][lr] = v0.w;
            As[kb + 4][lr] = v1.x; As[kb + 5][lr] = v1.y;
            As[kb + 6][lr] = v1.z; As[kb + 7][lr] = v1.w;
        }
        {
            constexpr int F4 = BK * N2 / 4;
#pragma unroll
            for (int q = tid; q < F4; q += 256) {
                const int kk = q / (N2 / 4);
                const int j = (q % (N2 / 4)) * 4;
                const float* src = (j < COUT)
                    ? (We + (size_t)(k0 + kk) * COUT + j)
                    : (We + (size_t)(K + k0 + kk) * COUT + (j - COUT));
                *(float4*)&Bs[kk][j] = *(const float4*)src;
            }
        }
        __syncthreads();
#pragma unroll
        for (int kk = 0; kk < BK; ++kk) {
            float a[4];
            *(float4*)a = *(const float4*)&As[kk][ty * 4];
            float b[TN];
#pragma unroll
            for (int j = 0; j < TN; j += 4)
                *(float4*)&b[j] = *(const float4*)&Bs[kk][tx * TN + j];
#pragma unroll
            for (int i = 0; i < 4; ++i)
#pragma unroll
                for (int j = 0; j < TN; ++j)
                    acc[i][j] += a[i] * b[j];
        }
        __syncthreads();
    }
#pragma unroll
    for (int i = 0; i < 4; ++i)
#pragma unroll
        for (int j = 0; j < TN; ++j)
            PQ[(size_t)(e0 + ty * 4 + i) * N2 + tx * TN + j] = acc[i][j];
}

// ---------------------------------------------------------------------------
// K4: aggregation, one wave per dst node:
//   agg[n] = sum_{e in bucket(n)} selu(P[src_e] + Q[n] + be)
// ---------------------------------------------------------------------------
template <int COUT>
__global__ __launch_bounds__(256) void agg_kernel(
    const float* __restrict__ PQ, const int* __restrict__ base,
    const int* __restrict__ sorted_src, const float* __restrict__ be,
    float* __restrict__ agg, int NN) {
    const int gid = blockIdx.x * blockDim.x + threadIdx.x;
    const int n = gid >> 6;
    const int lane = gid & 63;
    if (n >= NN) return;
    const int b0 = base[n], b1 = base[n + 1];

    if constexpr (COUT == 128) {
        float2 qv = *(const float2*)(PQ + (size_t)n * 256 + 128 + lane * 2);
        float2 bv = *(const float2*)(be + lane * 2);
        const float qx = qv.x + bv.x, qy = qv.y + bv.y;
        float ax = 0.0f, ay = 0.0f;
        for (int e = b0; e < b1; ++e) {
            const int src = sorted_src[e];
            float2 p = *(const float2*)(PQ + (size_t)src * 256 + lane * 2);
            ax += selu_f(p.x + qx);
            ay += selu_f(p.y + qy);
        }
        float2 r; r.x = ax; r.y = ay;
        *(float2*)(agg + (size_t)n * 128 + lane * 2) = r;
    } else {
        const float q = PQ[(size_t)n * (2 * COUT) + COUT + lane] + be[lane];
        float a = 0.0f;
        for (int e = b0; e < b1; ++e) {
            const int src = sorted_src[e];
            a += selu_f(PQ[(size_t)src * (2 * COUT) + lane] + q);
        }
        agg[(size_t)n * COUT + lane] = a;
    }
}

// ---------------------------------------------------------------------------
// K5: node MLP GEMM: out[n] = selu(concat(X1[n] (C1), X2[n] (C2)) @ W + b)
// ---------------------------------------------------------------------------
template <int C1, int C2, int COUTT>
__global__ __launch_bounds__(256) void node_mlp_kernel(
    const float* __restrict__ X1, const float* __restrict__ X2,
    const float* __restrict__ W, const float* __restrict__ bias,
    float* __restrict__ out) {
    constexpr int K = C1 + C2;
    constexpr int BM = 64, BK = 32;
    constexpr int TN = COUTT / 16;
    constexpr int NCH = K / BK;

    __shared__ float As[BK][BM + 8];
    __shared__ float Bs[BK][COUTT];

    const int tid = threadIdx.x;
    const int e0 = blockIdx.x * BM;

    float acc[4][TN];
#pragma unroll
    for (int i = 0; i < 4; ++i)
#pragma unroll
        for (int j = 0; j < TN; ++j) acc[i][j] = 0.0f;

    const int lr = tid & 63;
    const int kq = tid >> 6;
    const int tx = tid & 15;
    const int ty = tid >> 4;

    for (int ch = 0; ch < NCH; ++ch) {
        const int k0 = ch * BK;
        {
            const float* base;
            if (k0 < C1) base = X1 + (size_t)(e0 + lr) * C1 + k0;
            else         base = X2 + (size_t)(e0 + lr) * C2 + (k0 - C1);
            const float4 v0 = *(const float4*)(base + kq * 8);
            const float4 v1 = *(const float4*)(base + kq * 8 + 4);
            const int kb = kq * 8;
            As[kb + 0][lr] = v0.x; As[kb + 1][lr] = v0.y;
            As[kb + 2][lr] = v0.z; As[kb + 3][lr] = v0.w;
            As[kb + 4][lr] = v1.x; As[kb + 5][lr] = v1.y;
            As[kb + 6][lr] = v1.z; As[kb + 7][lr] = v1.w;
        }
        {
            const float4* wsrc = (const float4*)(W + (size_t)k0 * COUTT);
            float4* bdst = (float4*)&Bs[0][0];
#pragma unroll
            for (int j = 0; j < (BK * COUTT) / (4 * 256); ++j)
                bdst[tid + j * 256] = wsrc[tid + j * 256];
        }
        __syncthreads();
#pragma unroll
        for (int kk = 0; kk < BK; ++kk) {
            float a[4];
            *(float4*)a = *(const float4*)&As[kk][ty * 4];
            float b[TN];
#pragma unroll
            for (int j = 0; j < TN; j += 4)
                *(float4*)&b[j] = *(const float4*)&Bs[kk][tx * TN + j];
#pragma unroll
            for (int i = 0; i < 4; ++i)
#pragma unroll
                for (int j = 0; j < TN; ++j)
                    acc[i][j] += a[i] * b[j];
        }
        __syncthreads();
    }
#pragma unroll
    for (int i = 0; i < 4; ++i)
#pragma unroll
        for (int j = 0; j < TN; ++j) {
            const int col = tx * TN + j;
            out[(size_t)(e0 + ty * 4 + i) * COUTT + col] =
                selu_f(acc[i][j] + bias[col]);
        }
}

// ---------------------------------------------------------------------------
// K6: residual add + per-channel sum/sumsq (BN stats); pre-BN value -> d_out.
// ---------------------------------------------------------------------------
__global__ __launch_bounds__(256) void stats_kernel(
    const float* __restrict__ h2, float* __restrict__ pre,
    float* __restrict__ stats, int total) {
    const int stride = gridDim.x * blockDim.x;
    const int i0 = blockIdx.x * blockDim.x + threadIdx.x;
    float s = 0.0f, sq = 0.0f;
    for (int i = i0; i < total; i += stride) {
        float v = h2[i] + pre[i];   // pre currently holds x_skip
        pre[i] = v;
        s += v;
        sq += v * v;
    }
    __shared__ float ls[256], lq[256];
    ls[threadIdx.x] = s; lq[threadIdx.x] = sq;
    __syncthreads();
    if (threadIdx.x < 128) {
        float a = ls[threadIdx.x] + ls[threadIdx.x + 128];
        float b = lq[threadIdx.x] + lq[threadIdx.x + 128];
        int c = i0 & 127;
        atomicAdd(&stats[c], a);
        atomicAdd(&stats[128 + c], b);
    }
}

// ---------------------------------------------------------------------------
// K7: BN normalize + SELU, in place on d_out.
// ---------------------------------------------------------------------------
__global__ __launch_bounds__(256) void bn_kernel(
    float* __restrict__ out, const float* __restrict__ stats,
    const float* __restrict__ gamma, const float* __restrict__ beta, int Nn) {
    const int i = blockIdx.x * blockDim.x + threadIdx.x;
    const int c = i & 127;
    const float invn = 1.0f / (float)Nn;
    float mu = stats[c] * invn;
    float var = stats[128 + c] * invn - mu * mu;
    float r = rsqrtf(var + 1e-5f);
    float v = (out[i] - mu) * r * gamma[c] + beta[c];
    out[i] = selu_f(v);
}

// ---------------------------------------------------------------------------
extern "C" void kernel_launch(void* const* d_in, const int* in_sizes, int n_in,
                              void* d_out, int out_size, void* d_ws, size_t ws_size,
                              hipStream_t stream) {
    const float* x     = (const float*)d_in[0];
    const float* pos_c = (const float*)d_in[1];
    const float* pos_f = (const float*)d_in[2];
    const int*   ei_c  = (const int*)d_in[3];
    const int*   ei_f  = (const int*)d_in[4];
    const float* We1 = (const float*)d_in[5];
    const float* be1 = (const float*)d_in[6];
    const float* Wn1 = (const float*)d_in[7];
    const float* bn1 = (const float*)d_in[8];
    const float* We2 = (const float*)d_in[9];
    const float* be2 = (const float*)d_in[10];
    const float* Wn2 = (const float*)d_in[11];
    const float* bn2 = (const float*)d_in[12];
    const float* WeS = (const float*)d_in[13];
    const float* beS = (const float*)d_in[14];
    const float* WnS = (const float*)d_in[15];
    const float* bnS = (const float*)d_in[16];
    const float* gamma = (const float*)d_in[17];
    const float* beta  = (const float*)d_in[18];

    // workspace layout
    char* w = (char*)d_ws;
    size_t o = 0;
    auto alloc = [&](size_t bytes) { void* p = w + o; o += (bytes + 255) & ~(size_t)255; return p; };
    int*   knn_idx = (int*)alloc((size_t)NF * 3 * sizeof(int));
    float* knn_w   = (float*)alloc((size_t)NF * 3 * sizeof(float));
    float* x_up    = (float*)alloc((size_t)NF * CIN * sizeof(float));   // later reused as h2
    float* PQ      = (float*)alloc((size_t)NF * 2 * CO * sizeof(float)); // shared by all 3 edge MLPs
    float* aggF    = (float*)alloc((size_t)NF * CO * sizeof(float));     // shared skip/mpl2
    float* h1      = (float*)alloc((size_t)NC * CH * sizeof(float));
    float* agg1    = (float*)alloc((size_t)NC * CH * sizeof(float));
    float* h_up    = (float*)alloc((size_t)NF * CH * sizeof(float));
    int*   cntF    = (int*)alloc((size_t)NF * sizeof(int));
    int*   baseF   = (int*)alloc((size_t)(NF + 1) * sizeof(int));
    int*   cursF   = (int*)alloc((size_t)NF * sizeof(int));
    int*   srtF    = (int*)alloc((size_t)EF * sizeof(int));
    int*   cntC    = (int*)alloc((size_t)NC * sizeof(int));
    int*   baseC   = (int*)alloc((size_t)(NC + 1) * sizeof(int));
    int*   cursC   = (int*)alloc((size_t)NC * sizeof(int));
    int*   srtC    = (int*)alloc((size_t)EC * sizeof(int));
    float* stats   = (float*)alloc(256 * sizeof(float));
    float* h2 = x_up;            // x_up dead after skip node MLP
    float* outp = (float*)d_out; // holds x_skip, then pre-BN, then final

    hipMemsetAsync(cntF, 0, (size_t)NF * sizeof(int), stream);
    hipMemsetAsync(cntC, 0, (size_t)NC * sizeof(int), stream);
    hipMemsetAsync(stats, 0, 256 * sizeof(float), stream);

    // kNN (shared by both interpolations): one wave per fine point
    knn_kernel<<<NF / 4, 256, 0, stream>>>(pos_c, pos_f, knn_idx, knn_w);
    interp_kernel<128><<<NF * (128 / 4) / 256, 256, 0, stream>>>(x, knn_idx, knn_w, x_up);

    // sort fine + coarse edge lists by dst
    hist_kernel<<<EF / 256, 256, 0, stream>>>(ei_f, cntF, EF);
    scan_kernel<NF><<<1, 1024, 0, stream>>>(cntF, baseF, cursF);
    scatter_kernel<<<EF / 256, 256, 0, stream>>>(ei_f, cursF, srtF, EF);
    hist_kernel<<<EC / 256, 256, 0, stream>>>(ei_c, cntC, EC);
    scan_kernel<NC><<<1, 1024, 0, stream>>>(cntC, baseC, cursC);
    scatter_kernel<<<EC / 256, 256, 0, stream>>>(ei_c, cursC, srtC, EC);

    // --- skip branch (fine graph, Cin->Cout) ---
    pq_kernel<128, 128><<<NF / 64, 256, 0, stream>>>(x_up, WeS, PQ);
    agg_kernel<128><<<NF / 4, 256, 0, stream>>>(PQ, baseF, srtF, beS, aggF, NF);
    node_mlp_kernel<128, 128, 128><<<NF / 64, 256, 0, stream>>>(
        x_up, aggF, WnS, bnS, outp);                    // outp = x_skip

    // --- coarse MPL (Cin->Ch) ---
    pq_kernel<128, 64><<<NC / 64, 256, 0, stream>>>(x, We1, PQ);
    agg_kernel<64><<<NC / 4, 256, 0, stream>>>(PQ, baseC, srtC, be1, agg1, NC);
    node_mlp_kernel<128, 64, 64><<<NC / 64, 256, 0, stream>>>(x, agg1, Wn1, bn1, h1);

    // upsample h1 -> h_up
    interp_kernel<64><<<NF * (64 / 4) / 256, 256, 0, stream>>>(h1, knn_idx, knn_w, h_up);

    // --- fine MPL (Ch->Cout) ---
    pq_kernel<64, 128><<<NF / 64, 256, 0, stream>>>(h_up, We2, PQ);
    agg_kernel<128><<<NF / 4, 256, 0, stream>>>(PQ, baseF, srtF, be2, aggF, NF);
    node_mlp_kernel<64, 128, 128><<<NF / 64, 256, 0, stream>>>(h_up, aggF, Wn2, bn2, h2);

    // residual + BN + SELU (x_skip already in d_out)
    stats_kernel<<<256, 256, 0, stream>>>(h2, outp, stats, NF * CO);
    bn_kernel<<<NF * CO / 256, 256, 0, stream>>>(outp, stats, gamma, beta, NF);
}

// Round 4
// 279.947 us; speedup vs baseline: 8.3081x; 1.3435x over previous
//
#include <hip/hip_runtime.h>

// ---------------------------------------------------------------------------
// Res_up block, round 4: all 6 GEMMs moved to bf16 MFMA (16x16x32), weights
// pre-converted to fragment-major bf16, producers (interp/agg/convert) write
// bf16 A-matrices. GEMM kernel is LDS-free: A-frags in regs, B-frags
// streamed from L2. knn/sort/agg/stats/bn unchanged from round 3.
// Sizes fixed: Nc=4096, Nf=16384, Ec=65536, Ef=262144, Cin=128, Ch=64, Co=128.
// ---------------------------------------------------------------------------

#define SELU_SCALE 1.0507009873554805f
#define SELU_ALPHA 1.6732632423543772f

static constexpr int NC = 4096, NF = 16384, EC = 65536, EF = 262144;
static constexpr int CIN = 128, CH = 64, CO = 128;

typedef __attribute__((ext_vector_type(8))) short short8v;
typedef __attribute__((ext_vector_type(4))) float f32x4;
typedef unsigned short ushort_t;

__device__ __forceinline__ float selu_f(float x) {
    return x > 0.0f ? SELU_SCALE * x
                    : SELU_SCALE * SELU_ALPHA * (__expf(x) - 1.0f);
}

// fp32 -> bf16 round-to-nearest-even (finite inputs)
__device__ __forceinline__ ushort_t f2bf(float f) {
    unsigned u = __float_as_uint(f);
    u += 0x7FFFu + ((u >> 16) & 1u);
    return (ushort_t)(u >> 16);
}

// ---------------------------------------------------------------------------
// K1: kNN (k=3), one wave per fine point (unchanged from round 3).
// ---------------------------------------------------------------------------
__device__ __forceinline__ bool knn_less(float da, int ia, float db, int ib) {
    return da < db || (da == db && ia < ib);
}

__global__ __launch_bounds__(256) void knn_kernel(
    const float* __restrict__ pos_c, const float* __restrict__ pos_f,
    int* __restrict__ knn_idx, float* __restrict__ knn_w) {
    __shared__ float2 spos[NC];
    for (int i = threadIdx.x; i < NC; i += 256)
        spos[i] = ((const float2*)pos_c)[i];
    __syncthreads();

    const int wid = threadIdx.x >> 6;
    const int lane = threadIdx.x & 63;
    const int t = blockIdx.x * 4 + wid;
    const float2 p = ((const float2*)pos_f)[t];

    float d0 = 1e30f, d1 = 1e30f, d2 = 1e30f;
    int i0 = 0x7fffffff, i1 = 0x7fffffff, i2 = 0x7fffffff;
#pragma unroll 4
    for (int k = 0; k < NC / 64; ++k) {
        const int j = lane + k * 64;
        const float dx = p.x - spos[j].x;
        const float dy = p.y - spos[j].y;
        const float d = dx * dx + dy * dy;
        if (d < d2) {
            if (d < d1) {
                d2 = d1; i2 = i1;
                if (d < d0) { d1 = d0; i1 = i0; d0 = d; i0 = j; }
                else        { d1 = d;  i1 = j; }
            } else { d2 = d; i2 = j; }
        }
    }
#pragma unroll
    for (int m = 1; m < 64; m <<= 1) {
        float e0 = __shfl_xor(d0, m), e1 = __shfl_xor(d1, m), e2 = __shfl_xor(d2, m);
        int   f0 = __shfl_xor(i0, m), f1 = __shfl_xor(i1, m), f2 = __shfl_xor(i2, m);
        float ed[3] = {e0, e1, e2};
        int   fi[3] = {f0, f1, f2};
#pragma unroll
        for (int q = 0; q < 3; ++q) {
            const float d = ed[q]; const int j = fi[q];
            if (knn_less(d, j, d2, i2)) {
                if (knn_less(d, j, d1, i1)) {
                    d2 = d1; i2 = i1;
                    if (knn_less(d, j, d0, i0)) { d1 = d0; i1 = i0; d0 = d; i0 = j; }
                    else                        { d1 = d;  i1 = j; }
                } else { d2 = d; i2 = j; }
            }
        }
    }
    if (lane == 0) {
        const float w0 = 1.0f / fmaxf(d0, 1e-16f);
        const float w1 = 1.0f / fmaxf(d1, 1e-16f);
        const float w2 = 1.0f / fmaxf(d2, 1e-16f);
        const float s = 1.0f / (w0 + w1 + w2);
        knn_idx[t * 3 + 0] = i0; knn_idx[t * 3 + 1] = i1; knn_idx[t * 3 + 2] = i2;
        knn_w[t * 3 + 0] = w0 * s; knn_w[t * 3 + 1] = w1 * s; knn_w[t * 3 + 2] = w2 * s;
    }
}

// ---------------------------------------------------------------------------
// K2: knn interpolation, fp32 in -> bf16 out. one thread per (t, 4 channels)
// ---------------------------------------------------------------------------
template <int C>
__global__ __launch_bounds__(256) void interp_kernel(
    const float* __restrict__ x, const int* __restrict__ knn_idx,
    const float* __restrict__ knn_w, ushort_t* __restrict__ out) {
    int tid = blockIdx.x * blockDim.x + threadIdx.x;
    int t = tid / (C / 4);
    int c4 = tid % (C / 4);
    int i0 = knn_idx[t * 3 + 0], i1 = knn_idx[t * 3 + 1], i2 = knn_idx[t * 3 + 2];
    float w0 = knn_w[t * 3 + 0], w1 = knn_w[t * 3 + 1], w2 = knn_w[t * 3 + 2];
    float4 a = ((const float4*)(x + (size_t)i0 * C))[c4];
    float4 b = ((const float4*)(x + (size_t)i1 * C))[c4];
    float4 c = ((const float4*)(x + (size_t)i2 * C))[c4];
    ushort4 r;
    r.x = f2bf(w0 * a.x + w1 * b.x + w2 * c.x);
    r.y = f2bf(w0 * a.y + w1 * b.y + w2 * c.y);
    r.z = f2bf(w0 * a.z + w1 * b.z + w2 * c.z);
    r.w = f2bf(w0 * a.w + w1 * b.w + w2 * c.w);
    *(ushort4*)(out + (size_t)t * C + c4 * 4) = r;
}

// ---------------------------------------------------------------------------
// Edge counting-sort by dst (unchanged).
// ---------------------------------------------------------------------------
__global__ __launch_bounds__(256) void hist_kernel(
    const int* __restrict__ ei, int* __restrict__ cnt, int M) {
    int e = blockIdx.x * blockDim.x + threadIdx.x;
    if (e < M) atomicAdd(&cnt[ei[M + e]], 1);
}

template <int NN>
__global__ __launch_bounds__(1024) void scan_kernel(
    const int* __restrict__ cnt, int* __restrict__ base, int* __restrict__ curs) {
    constexpr int IT = NN / 1024;
    __shared__ int part[1024];
    const int t = threadIdx.x;
    int loc[IT];
    int s = 0;
#pragma unroll
    for (int i = 0; i < IT; ++i) { loc[i] = cnt[t * IT + i]; s += loc[i]; }
    part[t] = s;
    __syncthreads();
    for (int off = 1; off < 1024; off <<= 1) {
        int v = part[t];
        int u = (t >= off) ? part[t - off] : 0;
        __syncthreads();
        part[t] = v + u;
        __syncthreads();
    }
    int ex = (t == 0) ? 0 : part[t - 1];
#pragma unroll
    for (int i = 0; i < IT; ++i) {
        base[t * IT + i] = ex;
        curs[t * IT + i] = ex;
        ex += loc[i];
    }
    if (t == 1023) base[NN] = ex;
}

__global__ __launch_bounds__(256) void scatter_kernel(
    const int* __restrict__ ei, int* __restrict__ curs,
    int* __restrict__ sorted_src, int M) {
    int e = blockIdx.x * blockDim.x + threadIdx.x;
    if (e < M) {
        int dst = ei[M + e];
        int pos = atomicAdd(&curs[dst], 1);
        sorted_src[pos] = ei[e];
    }
}

// ---------------------------------------------------------------------------
// Convert kernel: x -> bf16, and all 6 weight matrices -> fragment-major bf16.
// Fragment-major layout: Wf[f*512 + lane*8 + e] = W[k][col], where
//   KC=K/32, ntile=f/KC, kc=f%KC, k=kc*32+(lane>>4)*8+e, col=ntile*16+(lane&15)
// For pq-style weights (We[2K][COUT]), effective W[k][j] = (j<COUT)
//   ? We[k][j] : We[K+k][j-COUT]  (i.e. P|Q column concat).
// ---------------------------------------------------------------------------
template <int K, int N, int COUT>
__device__ __forceinline__ void wfrag_write(
    const float* __restrict__ src, ushort_t* __restrict__ dst, int idx) {
    constexpr int KC = K / 32;
    const int f = idx >> 9;
    const int r = idx & 511;
    const int lane = r >> 3;
    const int e = r & 7;
    const int ntile = f / KC;
    const int kc = f - ntile * KC;
    const int k = kc * 32 + ((lane >> 4) << 3) + e;
    const int col = ntile * 16 + (lane & 15);
    float v;
    if constexpr (COUT == N) {
        v = src[(size_t)k * N + col];
    } else {
        v = (col < COUT) ? src[(size_t)k * COUT + col]
                         : src[(size_t)(K + k) * COUT + (col - COUT)];
    }
    dst[idx] = f2bf(v);
}

__global__ __launch_bounds__(256) void convert_kernel(
    const float* __restrict__ x, ushort_t* __restrict__ xb,
    const float* __restrict__ WeS, ushort_t* __restrict__ WfS_pq,
    const float* __restrict__ We1, ushort_t* __restrict__ Wf1_pq,
    const float* __restrict__ We2, ushort_t* __restrict__ Wf2_pq,
    const float* __restrict__ WnS, ushort_t* __restrict__ WfS_n,
    const float* __restrict__ Wn1, ushort_t* __restrict__ Wf1_n,
    const float* __restrict__ Wn2, ushort_t* __restrict__ Wf2_n) {
    constexpr int L0 = NC * CIN;          // 524288 xb
    constexpr int L1 = 128 * 256;         // WfS_pq
    constexpr int L2 = 128 * 128;         // Wf1_pq
    constexpr int L3 = 64 * 256;          // Wf2_pq
    constexpr int L4 = 256 * 128;         // WfS_n
    constexpr int L5 = 192 * 64;          // Wf1_n
    constexpr int L6 = 192 * 128;         // Wf2_n
    int i = blockIdx.x * 256 + threadIdx.x;
    if (i < L0) { xb[i] = f2bf(x[i]); return; }
    i -= L0;
    if (i < L1) { wfrag_write<128, 256, 128>(WeS, WfS_pq, i); return; }
    i -= L1;
    if (i < L2) { wfrag_write<128, 128, 64>(We1, Wf1_pq, i); return; }
    i -= L2;
    if (i < L3) { wfrag_write<64, 256, 128>(We2, Wf2_pq, i); return; }
    i -= L3;
    if (i < L4) { wfrag_write<256, 128, 128>(WnS, WfS_n, i); return; }
    i -= L4;
    if (i < L5) { wfrag_write<192, 64, 64>(Wn1, Wf1_n, i); return; }
    i -= L5;
    if (i < L6) { wfrag_write<192, 128, 128>(Wn2, Wf2_n, i); return; }
}

// ---------------------------------------------------------------------------
// K3: MFMA GEMM  C[M][N] = act(concat(A1(K1) | A2(K2)) @ W + bias)
// A row-major bf16; W fragment-major bf16; C fp32.
// Wave: 16 rows x WN cols. Block: 4 waves = 64 rows. Grid: (M/64, N/WN).
// A-frags loaded once to regs (reused over n-tiles); B-frags streamed (L2).
// ---------------------------------------------------------------------------
template <int K1, int K2, int N, bool ACT>
__global__ __launch_bounds__(256) void mfma_mlp(
    const ushort_t* __restrict__ A1, const ushort_t* __restrict__ A2,
    const ushort_t* __restrict__ Wf, const float* __restrict__ bias,
    float* __restrict__ C) {
    constexpr int K = K1 + K2;
    constexpr int KC = K / 32;
    constexpr int WN = 64;
    constexpr int NTW = WN / 16;

    const int tid = threadIdx.x;
    const int wid = tid >> 6;
    const int lane = tid & 63;
    const int row_base = blockIdx.x * 64 + wid * 16;
    const int row_a = row_base + (lane & 15);
    const int klane = ((lane >> 4) << 3);      // 0,8,16,24

    short8v a[KC];
#pragma unroll
    for (int f = 0; f < KC; ++f) {
        const int k0 = f * 32 + klane;
        const ushort_t* p;
        if constexpr (K2 == 0) {
            p = A1 + (size_t)row_a * K1 + k0;
        } else {
            p = (k0 < K1) ? (A1 + (size_t)row_a * K1 + k0)
                          : (A2 + (size_t)row_a * K2 + (k0 - K1));
        }
        a[f] = *(const short8v*)p;
    }

    const int nt0 = blockIdx.y * NTW;
#pragma unroll
    for (int nt = 0; nt < NTW; ++nt) {
        const int ntg = nt0 + nt;
        f32x4 acc = {0.0f, 0.0f, 0.0f, 0.0f};
#pragma unroll
        for (int f = 0; f < KC; ++f) {
            const short8v b =
                *(const short8v*)(Wf + (size_t)(ntg * KC + f) * 512 + lane * 8);
            acc = __builtin_amdgcn_mfma_f32_16x16x32_bf16(a[f], b, acc, 0, 0, 0);
        }
        const int col = ntg * 16 + (lane & 15);
        float bb = 0.0f;
        if constexpr (ACT) bb = bias[col];
#pragma unroll
        for (int r = 0; r < 4; ++r) {
            const int rowd = row_base + ((lane >> 4) << 2) + r;
            float v = acc[r] + bb;
            if constexpr (ACT) v = selu_f(v);
            C[(size_t)rowd * N + col] = v;
        }
    }
}

// ---------------------------------------------------------------------------
// K4: aggregation, one wave per dst node; PQ fp32 in, bf16 out.
//   agg[n] = sum_{e in bucket(n)} selu(P[src_e] + Q[n] + be)
// ---------------------------------------------------------------------------
template <int COUT>
__global__ __launch_bounds__(256) void agg_kernel(
    const float* __restrict__ PQ, const int* __restrict__ base,
    const int* __restrict__ sorted_src, const float* __restrict__ be,
    ushort_t* __restrict__ agg, int NN) {
    const int gid = blockIdx.x * blockDim.x + threadIdx.x;
    const int n = gid >> 6;
    const int lane = gid & 63;
    if (n >= NN) return;
    const int b0 = base[n], b1 = base[n + 1];

    if constexpr (COUT == 128) {
        float2 qv = *(const float2*)(PQ + (size_t)n * 256 + 128 + lane * 2);
        float2 bv = *(const float2*)(be + lane * 2);
        const float qx = qv.x + bv.x, qy = qv.y + bv.y;
        float ax = 0.0f, ay = 0.0f;
        for (int e = b0; e < b1; ++e) {
            const int src = sorted_src[e];
            float2 p = *(const float2*)(PQ + (size_t)src * 256 + lane * 2);
            ax += selu_f(p.x + qx);
            ay += selu_f(p.y + qy);
        }
        ushort2 r; r.x = f2bf(ax); r.y = f2bf(ay);
        *(ushort2*)(agg + (size_t)n * 128 + lane * 2) = r;
    } else {
        const float q = PQ[(size_t)n * (2 * COUT) + COUT + lane] + be[lane];
        float a = 0.0f;
        for (int e = b0; e < b1; ++e) {
            const int src = sorted_src[e];
            a += selu_f(PQ[(size_t)src * (2 * COUT) + lane] + q);
        }
        agg[(size_t)n * COUT + lane] = f2bf(a);
    }
}

// ---------------------------------------------------------------------------
// K6: residual add + per-channel sum/sumsq (BN stats); pre-BN -> d_out.
// ---------------------------------------------------------------------------
__global__ __launch_bounds__(256) void stats_kernel(
    const float* __restrict__ h2, float* __restrict__ pre,
    float* __restrict__ stats, int total) {
    const int stride = gridDim.x * blockDim.x;
    const int i0 = blockIdx.x * blockDim.x + threadIdx.x;
    float s = 0.0f, sq = 0.0f;
    for (int i = i0; i < total; i += stride) {
        float v = h2[i] + pre[i];   // pre currently holds x_skip
        pre[i] = v;
        s += v;
        sq += v * v;
    }
    __shared__ float ls[256], lq[256];
    ls[threadIdx.x] = s; lq[threadIdx.x] = sq;
    __syncthreads();
    if (threadIdx.x < 128) {
        float a = ls[threadIdx.x] + ls[threadIdx.x + 128];
        float b = lq[threadIdx.x] + lq[threadIdx.x + 128];
        int c = i0 & 127;
        atomicAdd(&stats[c], a);
        atomicAdd(&stats[128 + c], b);
    }
}

// ---------------------------------------------------------------------------
// K7: BN normalize + SELU, in place on d_out.
// ---------------------------------------------------------------------------
__global__ __launch_bounds__(256) void bn_kernel(
    float* __restrict__ out, const float* __restrict__ stats,
    const float* __restrict__ gamma, const float* __restrict__ beta, int Nn) {
    const int i = blockIdx.x * blockDim.x + threadIdx.x;
    const int c = i & 127;
    const float invn = 1.0f / (float)Nn;
    float mu = stats[c] * invn;
    float var = stats[128 + c] * invn - mu * mu;
    float r = rsqrtf(var + 1e-5f);
    float v = (out[i] - mu) * r * gamma[c] + beta[c];
    out[i] = selu_f(v);
}

// ---------------------------------------------------------------------------
extern "C" void kernel_launch(void* const* d_in, const int* in_sizes, int n_in,
                              void* d_out, int out_size, void* d_ws, size_t ws_size,
                              hipStream_t stream) {
    const float* x     = (const float*)d_in[0];
    const float* pos_c = (const float*)d_in[1];
    const float* pos_f = (const float*)d_in[2];
    const int*   ei_c  = (const int*)d_in[3];
    const int*   ei_f  = (const int*)d_in[4];
    const float* We1 = (const float*)d_in[5];
    const float* be1 = (const float*)d_in[6];
    const float* Wn1 = (const float*)d_in[7];
    const float* bn1 = (const float*)d_in[8];
    const float* We2 = (const float*)d_in[9];
    const float* be2 = (const float*)d_in[10];
    const float* Wn2 = (const float*)d_in[11];
    const float* bn2 = (const float*)d_in[12];
    const float* WeS = (const float*)d_in[13];
    const float* beS = (const float*)d_in[14];
    const float* WnS = (const float*)d_in[15];
    const float* bnS = (const float*)d_in[16];
    const float* gamma = (const float*)d_in[17];
    const float* beta  = (const float*)d_in[18];

    // workspace layout
    char* w = (char*)d_ws;
    size_t o = 0;
    auto alloc = [&](size_t bytes) { void* p = w + o; o += (bytes + 255) & ~(size_t)255; return p; };
    int*      knn_idx = (int*)alloc((size_t)NF * 3 * sizeof(int));
    float*    knn_w   = (float*)alloc((size_t)NF * 3 * sizeof(float));
    ushort_t* x_upb   = (ushort_t*)alloc((size_t)NF * CIN * 2);
    float*    PQ      = (float*)alloc((size_t)NF * 2 * CO * sizeof(float));
    ushort_t* aggFb   = (ushort_t*)alloc((size_t)NF * CO * 2);
    float*    h1      = (float*)alloc((size_t)NC * CH * sizeof(float));
    ushort_t* agg1b   = (ushort_t*)alloc((size_t)NC * CH * 2);
    ushort_t* h_upb   = (ushort_t*)alloc((size_t)NF * CH * 2);
    float*    h2      = (float*)alloc((size_t)NF * CO * sizeof(float));
    ushort_t* xb      = (ushort_t*)alloc((size_t)NC * CIN * 2);
    ushort_t* WfS_pq  = (ushort_t*)alloc(128 * 256 * 2);
    ushort_t* Wf1_pq  = (ushort_t*)alloc(128 * 128 * 2);
    ushort_t* Wf2_pq  = (ushort_t*)alloc(64 * 256 * 2);
    ushort_t* WfS_n   = (ushort_t*)alloc(256 * 128 * 2);
    ushort_t* Wf1_n   = (ushort_t*)alloc(192 * 64 * 2);
    ushort_t* Wf2_n   = (ushort_t*)alloc(192 * 128 * 2);
    int*   cntF    = (int*)alloc((size_t)NF * sizeof(int));
    int*   baseF   = (int*)alloc((size_t)(NF + 1) * sizeof(int));
    int*   cursF   = (int*)alloc((size_t)NF * sizeof(int));
    int*   srtF    = (int*)alloc((size_t)EF * sizeof(int));
    int*   cntC    = (int*)alloc((size_t)NC * sizeof(int));
    int*   baseC   = (int*)alloc((size_t)(NC + 1) * sizeof(int));
    int*   cursC   = (int*)alloc((size_t)NC * sizeof(int));
    int*   srtC    = (int*)alloc((size_t)EC * sizeof(int));
    float* stats   = (float*)alloc(256 * sizeof(float));
    float* outp = (float*)d_out;  // x_skip, then pre-BN, then final

    hipMemsetAsync(cntF, 0, (size_t)NF * sizeof(int), stream);
    hipMemsetAsync(cntC, 0, (size_t)NC * sizeof(int), stream);
    hipMemsetAsync(stats, 0, 256 * sizeof(float), stream);

    // conversions (x -> bf16, weights -> fragment-major bf16)
    {
        constexpr int TOTAL = NC * CIN + 128 * 256 + 128 * 128 + 64 * 256
                            + 256 * 128 + 192 * 64 + 192 * 128;
        convert_kernel<<<(TOTAL + 255) / 256, 256, 0, stream>>>(
            x, xb, WeS, WfS_pq, We1, Wf1_pq, We2, Wf2_pq,
            WnS, WfS_n, Wn1, Wf1_n, Wn2, Wf2_n);
    }

    // kNN (shared by both interpolations)
    knn_kernel<<<NF / 4, 256, 0, stream>>>(pos_c, pos_f, knn_idx, knn_w);
    interp_kernel<128><<<NF * (128 / 4) / 256, 256, 0, stream>>>(x, knn_idx, knn_w, x_upb);

    // sort fine + coarse edge lists by dst
    hist_kernel<<<EF / 256, 256, 0, stream>>>(ei_f, cntF, EF);
    scan_kernel<NF><<<1, 1024, 0, stream>>>(cntF, baseF, cursF);
    scatter_kernel<<<EF / 256, 256, 0, stream>>>(ei_f, cursF, srtF, EF);
    hist_kernel<<<EC / 256, 256, 0, stream>>>(ei_c, cntC, EC);
    scan_kernel<NC><<<1, 1024, 0, stream>>>(cntC, baseC, cursC);
    scatter_kernel<<<EC / 256, 256, 0, stream>>>(ei_c, cursC, srtC, EC);

    // --- skip branch (fine graph, Cin->Cout) ---
    mfma_mlp<128, 0, 256, false><<<dim3(NF / 64, 4), 256, 0, stream>>>(
        x_upb, nullptr, WfS_pq, nullptr, PQ);
    agg_kernel<128><<<NF / 4, 256, 0, stream>>>(PQ, baseF, srtF, beS, aggFb, NF);
    mfma_mlp<128, 128, 128, true><<<dim3(NF / 64, 2), 256, 0, stream>>>(
        x_upb, aggFb, WfS_n, bnS, outp);                 // outp = x_skip

    // --- coarse MPL (Cin->Ch) ---
    mfma_mlp<128, 0, 128, false><<<dim3(NC / 64, 2), 256, 0, stream>>>(
        xb, nullptr, Wf1_pq, nullptr, PQ);
    agg_kernel<64><<<NC / 4, 256, 0, stream>>>(PQ, baseC, srtC, be1, agg1b, NC);
    mfma_mlp<128, 64, 64, true><<<dim3(NC / 64, 1), 256, 0, stream>>>(
        xb, agg1b, Wf1_n, bn1, h1);

    // upsample h1 -> h_upb
    interp_kernel<64><<<NF * (64 / 4) / 256, 256, 0, stream>>>(h1, knn_idx, knn_w, h_upb);

    // --- fine MPL (Ch->Cout) ---
    mfma_mlp<64, 0, 256, false><<<dim3(NF / 64, 4), 256, 0, stream>>>(
        h_upb, nullptr, Wf2_pq, nullptr, PQ);
    agg_kernel<128><<<NF / 4, 256, 0, stream>>>(PQ, baseF, srtF, be2, aggFb, NF);
    mfma_mlp<64, 128, 128, true><<<dim3(NF / 64, 2), 256, 0, stream>>>(
        h_upb, aggFb, Wf2_n, bn2, h2);

    // residual + BN + SELU (x_skip already in d_out)
    stats_kernel<<<256, 256, 0, stream>>>(h2, outp, stats, NF * CO);
    bn_kernel<<<NF * CO / 256, 256, 0, stream>>>(outp, stats, gamma, beta, NF);
}

// Round 5
// 257.886 us; speedup vs baseline: 9.0188x; 1.0855x over previous
//
#include <hip/hip_runtime.h>

// ---------------------------------------------------------------------------
// Res_up block, round 5:
//  - exact kNN via 32x32 spatial grid + expanding-ring search (~40 candidates
//    instead of 4096)
//  - merged hist/scan/scatter for {fine edges, coarse edges, coarse points}
//  - cnt/stats zeroing folded into convert kernel (no memsets)
//  - residual + BN-stats fused into final MFMA epilogue
// Sizes fixed: Nc=4096, Nf=16384, Ec=65536, Ef=262144, Cin=128, Ch=64, Co=128.
// ---------------------------------------------------------------------------

#define SELU_SCALE 1.0507009873554805f
#define SELU_ALPHA 1.6732632423543772f

static constexpr int NC = 4096, NF = 16384, EC = 65536, EF = 262144;
static constexpr int CIN = 128, CH = 64, CO = 128;
static constexpr int G = 32, NCELL = G * G;   // kNN grid

typedef __attribute__((ext_vector_type(8))) short short8v;
typedef __attribute__((ext_vector_type(4))) float f32x4;
typedef unsigned short ushort_t;
typedef unsigned long long u64;

__device__ __forceinline__ float selu_f(float x) {
    return x > 0.0f ? SELU_SCALE * x
                    : SELU_SCALE * SELU_ALPHA * (__expf(x) - 1.0f);
}

__device__ __forceinline__ ushort_t f2bf(float f) {
    unsigned u = __float_as_uint(f);
    u += 0x7FFFu + ((u >> 16) & 1u);
    return (ushort_t)(u >> 16);
}

__device__ __forceinline__ int cell_of(float2 p) {
    int cx = (int)(p.x * (float)G); cx = cx > G - 1 ? G - 1 : cx;
    int cy = (int)(p.y * (float)G); cy = cy > G - 1 ? G - 1 : cy;
    return cy * G + cx;
}

// ---------------------------------------------------------------------------
// Convert: x -> bf16, weights -> fragment-major bf16, zero cnt/curs-src/stats.
// Fragment-major: Wf[f*512 + lane*8 + e] = W[k][col];
//   KC=K/32, ntile=f/KC, kc=f%KC, k=kc*32+(lane>>4)*8+e, col=ntile*16+(lane&15)
// pq-style (We[2K][COUT]): W[k][j] = j<COUT ? We[k][j] : We[K+k][j-COUT]
// ---------------------------------------------------------------------------
template <int K, int N, int COUT>
__device__ __forceinline__ void wfrag_write(
    const float* __restrict__ src, ushort_t* __restrict__ dst, int idx) {
    constexpr int KC = K / 32;
    const int f = idx >> 9;
    const int r = idx & 511;
    const int lane = r >> 3;
    const int e = r & 7;
    const int ntile = f / KC;
    const int kc = f - ntile * KC;
    const int k = kc * 32 + ((lane >> 4) << 3) + e;
    const int col = ntile * 16 + (lane & 15);
    float v;
    if constexpr (COUT == N) {
        v = src[(size_t)k * N + col];
    } else {
        v = (col < COUT) ? src[(size_t)k * COUT + col]
                         : src[(size_t)(K + k) * COUT + (col - COUT)];
    }
    dst[idx] = f2bf(v);
}

__global__ __launch_bounds__(256) void convert_kernel(
    const float* __restrict__ x, ushort_t* __restrict__ xb,
    const float* __restrict__ WeS, ushort_t* __restrict__ WfS_pq,
    const float* __restrict__ We1, ushort_t* __restrict__ Wf1_pq,
    const float* __restrict__ We2, ushort_t* __restrict__ Wf2_pq,
    const float* __restrict__ WnS, ushort_t* __restrict__ WfS_n,
    const float* __restrict__ Wn1, ushort_t* __restrict__ Wf1_n,
    const float* __restrict__ Wn2, ushort_t* __restrict__ Wf2_n,
    int* __restrict__ cntF, int* __restrict__ cntC, int* __restrict__ cntG,
    float* __restrict__ stats) {
    constexpr int L0 = NC * CIN;
    constexpr int L1 = 128 * 256;
    constexpr int L2 = 128 * 128;
    constexpr int L3 = 64 * 256;
    constexpr int L4 = 256 * 128;
    constexpr int L5 = 192 * 64;
    constexpr int L6 = 192 * 128;
    int i = blockIdx.x * 256 + threadIdx.x;
    if (i < L0) { xb[i] = f2bf(x[i]); return; }
    i -= L0;
    if (i < L1) { wfrag_write<128, 256, 128>(WeS, WfS_pq, i); return; }
    i -= L1;
    if (i < L2) { wfrag_write<128, 128, 64>(We1, Wf1_pq, i); return; }
    i -= L2;
    if (i < L3) { wfrag_write<64, 256, 128>(We2, Wf2_pq, i); return; }
    i -= L3;
    if (i < L4) { wfrag_write<256, 128, 128>(WnS, WfS_n, i); return; }
    i -= L4;
    if (i < L5) { wfrag_write<192, 64, 64>(Wn1, Wf1_n, i); return; }
    i -= L5;
    if (i < L6) { wfrag_write<192, 128, 128>(Wn2, Wf2_n, i); return; }
    i -= L6;
    if (i < NF) { cntF[i] = 0; return; }
    i -= NF;
    if (i < NC) { cntC[i] = 0; return; }
    i -= NC;
    if (i < NCELL) { cntG[i] = 0; return; }
    i -= NCELL;
    if (i < 256) { stats[i] = 0.0f; return; }
}

// ---------------------------------------------------------------------------
// Merged histogram: fine edges by dst, coarse edges by dst, coarse pts by cell
// ---------------------------------------------------------------------------
__global__ __launch_bounds__(256) void hist3_kernel(
    const int* __restrict__ ei_f, const int* __restrict__ ei_c,
    const float* __restrict__ pos_c,
    int* __restrict__ cntF, int* __restrict__ cntC, int* __restrict__ cntG) {
    int i = blockIdx.x * 256 + threadIdx.x;
    if (i < EF) { atomicAdd(&cntF[ei_f[EF + i]], 1); return; }
    i -= EF;
    if (i < EC) { atomicAdd(&cntC[ei_c[EC + i]], 1); return; }
    i -= EC;
    if (i < NC) {
        float2 p = ((const float2*)pos_c)[i];
        atomicAdd(&cntG[cell_of(p)], 1);
    }
}

// ---------------------------------------------------------------------------
// Merged scan: block 0 -> cntF (16384), block 1 -> cntC (4096), block 2 -> cntG
// ---------------------------------------------------------------------------
__global__ __launch_bounds__(1024) void scan3_kernel(
    int* __restrict__ cntF, int* __restrict__ baseF, int* __restrict__ cursF,
    int* __restrict__ cntC, int* __restrict__ baseC, int* __restrict__ cursC,
    int* __restrict__ cntG, int* __restrict__ baseG, int* __restrict__ cursG) {
    const int* cnt; int* base; int* curs; int n;
    if (blockIdx.x == 0)      { cnt = cntF; base = baseF; curs = cursF; n = NF; }
    else if (blockIdx.x == 1) { cnt = cntC; base = baseC; curs = cursC; n = NC; }
    else                      { cnt = cntG; base = baseG; curs = cursG; n = NCELL; }
    const int IT = n >> 10;
    __shared__ int part[1024];
    const int t = threadIdx.x;
    int loc[16];
    int s = 0;
#pragma unroll
    for (int i = 0; i < 16; ++i) {
        int v = (i < IT) ? cnt[t * IT + i] : 0;
        loc[i] = v; s += v;
    }
    part[t] = s;
    __syncthreads();
    for (int off = 1; off < 1024; off <<= 1) {
        int v = part[t];
        int u = (t >= off) ? part[t - off] : 0;
        __syncthreads();
        part[t] = v + u;
        __syncthreads();
    }
    int ex = (t == 0) ? 0 : part[t - 1];
#pragma unroll
    for (int i = 0; i < 16; ++i) {
        if (i < IT) {
            base[t * IT + i] = ex;
            curs[t * IT + i] = ex;
            ex += loc[i];
        }
    }
    if (t == 1023) base[n] = ex;
}

// ---------------------------------------------------------------------------
// Merged scatter
// ---------------------------------------------------------------------------
__global__ __launch_bounds__(256) void scatter3_kernel(
    const int* __restrict__ ei_f, const int* __restrict__ ei_c,
    const float* __restrict__ pos_c,
    int* __restrict__ cursF, int* __restrict__ srtF,
    int* __restrict__ cursC, int* __restrict__ srtC,
    int* __restrict__ cursG, float2* __restrict__ sposG, int* __restrict__ sidxG) {
    int i = blockIdx.x * 256 + threadIdx.x;
    if (i < EF) {
        int pos = atomicAdd(&cursF[ei_f[EF + i]], 1);
        srtF[pos] = ei_f[i];
        return;
    }
    i -= EF;
    if (i < EC) {
        int pos = atomicAdd(&cursC[ei_c[EC + i]], 1);
        srtC[pos] = ei_c[i];
        return;
    }
    i -= EC;
    if (i < NC) {
        float2 p = ((const float2*)pos_c)[i];
        int pos = atomicAdd(&cursG[cell_of(p)], 1);
        sposG[pos] = p;
        sidxG[pos] = i;
    }
}

// ---------------------------------------------------------------------------
// kNN via grid: one thread per fine point, expanding Chebyshev rings.
// Top-3 as packed u64 (f32 bits of d)<<32 | idx  -> lexicographic (d, idx).
// Stop before ring r if d3 < ((r-1)*h)^2 (unvisited cells are >= (r-1)*h away).
// ---------------------------------------------------------------------------
__global__ __launch_bounds__(64) void knn_grid_kernel(
    const float* __restrict__ pos_f, const float2* __restrict__ sposG,
    const int* __restrict__ sidxG, const int* __restrict__ baseG,
    int* __restrict__ knn_idx, float* __restrict__ knn_w) {
    const int t = blockIdx.x * 64 + threadIdx.x;
    const float2 p = ((const float2*)pos_f)[t];
    int cx = (int)(p.x * (float)G); cx = cx > G - 1 ? G - 1 : cx;
    int cy = (int)(p.y * (float)G); cy = cy > G - 1 ? G - 1 : cy;

    u64 b0 = ~0ull, b1 = ~0ull, b2 = ~0ull;
    const float h = 1.0f / (float)G;

    auto scan_range = [&](int c0, int c1) {
        const int s0 = baseG[c0], s1 = baseG[c1 + 1];
        for (int i = s0; i < s1; ++i) {
            const float2 q = sposG[i];
            const float dx = p.x - q.x;
            const float dy = p.y - q.y;
            const float d = dx * dx + dy * dy;
            const u64 v = ((u64)__float_as_uint(d) << 32) | (unsigned)sidxG[i];
            if (v < b2) {
                if (v < b1) {
                    b2 = b1;
                    if (v < b0) { b1 = b0; b0 = v; } else b1 = v;
                } else b2 = v;
            }
        }
    };

    for (int r = 0; r < G; ++r) {
        if (r >= 1) {
            const float bd = __uint_as_float((unsigned)(b2 >> 32));
            const float lim = (float)(r - 1) * h;
            if (bd < lim * lim) break;
        }
        if (r == 0) {
            scan_range(cy * G + cx, cy * G + cx);
        } else {
            const int x0 = cx - r < 0 ? 0 : cx - r;
            const int x1 = cx + r > G - 1 ? G - 1 : cx + r;
            const int yT = cy - r, yB = cy + r;
            if (yT >= 0) scan_range(yT * G + x0, yT * G + x1);
            if (yB <= G - 1) scan_range(yB * G + x0, yB * G + x1);
            const int yy0 = yT + 1 < 0 ? 0 : yT + 1;
            const int yy1 = yB - 1 > G - 1 ? G - 1 : yB - 1;
            if (cx - r >= 0)
                for (int y = yy0; y <= yy1; ++y) scan_range(y * G + cx - r, y * G + cx - r);
            if (cx + r <= G - 1)
                for (int y = yy0; y <= yy1; ++y) scan_range(y * G + cx + r, y * G + cx + r);
        }
    }

    const float d0 = __uint_as_float((unsigned)(b0 >> 32));
    const float d1 = __uint_as_float((unsigned)(b1 >> 32));
    const float d2 = __uint_as_float((unsigned)(b2 >> 32));
    const float w0 = 1.0f / fmaxf(d0, 1e-16f);
    const float w1 = 1.0f / fmaxf(d1, 1e-16f);
    const float w2 = 1.0f / fmaxf(d2, 1e-16f);
    const float s = 1.0f / (w0 + w1 + w2);
    knn_idx[t * 3 + 0] = (int)(b0 & 0xffffffffu);
    knn_idx[t * 3 + 1] = (int)(b1 & 0xffffffffu);
    knn_idx[t * 3 + 2] = (int)(b2 & 0xffffffffu);
    knn_w[t * 3 + 0] = w0 * s;
    knn_w[t * 3 + 1] = w1 * s;
    knn_w[t * 3 + 2] = w2 * s;
}

// ---------------------------------------------------------------------------
// Interp: fp32 gather -> bf16 out. one thread per (t, 4 channels)
// ---------------------------------------------------------------------------
template <int C>
__global__ __launch_bounds__(256) void interp_kernel(
    const float* __restrict__ x, const int* __restrict__ knn_idx,
    const float* __restrict__ knn_w, ushort_t* __restrict__ out) {
    int tid = blockIdx.x * blockDim.x + threadIdx.x;
    int t = tid / (C / 4);
    int c4 = tid % (C / 4);
    int i0 = knn_idx[t * 3 + 0], i1 = knn_idx[t * 3 + 1], i2 = knn_idx[t * 3 + 2];
    float w0 = knn_w[t * 3 + 0], w1 = knn_w[t * 3 + 1], w2 = knn_w[t * 3 + 2];
    float4 a = ((const float4*)(x + (size_t)i0 * C))[c4];
    float4 b = ((const float4*)(x + (size_t)i1 * C))[c4];
    float4 c = ((const float4*)(x + (size_t)i2 * C))[c4];
    ushort4 r;
    r.x = f2bf(w0 * a.x + w1 * b.x + w2 * c.x);
    r.y = f2bf(w0 * a.y + w1 * b.y + w2 * c.y);
    r.z = f2bf(w0 * a.z + w1 * b.z + w2 * c.z);
    r.w = f2bf(w0 * a.w + w1 * b.w + w2 * c.w);
    *(ushort4*)(out + (size_t)t * C + c4 * 4) = r;
}

// ---------------------------------------------------------------------------
// MFMA GEMM  C[M][N] = act(concat(A1(K1)|A2(K2)) @ W + bias)  [+res+stats]
// Wave: 16 rows x 64 cols. Block: 4 waves = 64 rows. Grid: (M/64, N/64).
// ---------------------------------------------------------------------------
template <int K1, int K2, int N, bool ACT, bool RES>
__global__ __launch_bounds__(256) void mfma_mlp(
    const ushort_t* __restrict__ A1, const ushort_t* __restrict__ A2,
    const ushort_t* __restrict__ Wf, const float* __restrict__ bias,
    float* __restrict__ C, float* __restrict__ stats) {
    constexpr int K = K1 + K2;
    constexpr int KC = K / 32;
    constexpr int NTW = 4;               // 4 n-tiles = 64 cols per wave

    __shared__ float s_sum[64], s_sq[64];

    const int tid = threadIdx.x;
    const int wid = tid >> 6;
    const int lane = tid & 63;
    const int row_base = blockIdx.x * 64 + wid * 16;
    const int row_a = row_base + (lane & 15);
    const int klane = ((lane >> 4) << 3);

    if constexpr (RES) {
        if (tid < 64) { s_sum[tid] = 0.0f; s_sq[tid] = 0.0f; }
        __syncthreads();
    }

    short8v a[KC];
#pragma unroll
    for (int f = 0; f < KC; ++f) {
        const int k0 = f * 32 + klane;
        const ushort_t* p;
        if constexpr (K2 == 0) {
            p = A1 + (size_t)row_a * K1 + k0;
        } else {
            p = (k0 < K1) ? (A1 + (size_t)row_a * K1 + k0)
                          : (A2 + (size_t)row_a * K2 + (k0 - K1));
        }
        a[f] = *(const short8v*)p;
    }

    const int nt0 = blockIdx.y * NTW;
#pragma unroll
    for (int nt = 0; nt < NTW; ++nt) {
        const int ntg = nt0 + nt;
        f32x4 acc = {0.0f, 0.0f, 0.0f, 0.0f};
#pragma unroll
        for (int f = 0; f < KC; ++f) {
            const short8v b =
                *(const short8v*)(Wf + (size_t)(ntg * KC + f) * 512 + lane * 8);
            acc = __builtin_amdgcn_mfma_f32_16x16x32_bf16(a[f], b, acc, 0, 0, 0);
        }
        const int col = ntg * 16 + (lane & 15);
        float bb = 0.0f;
        if constexpr (ACT) bb = bias[col];
        float lsum = 0.0f, lsq = 0.0f;
#pragma unroll
        for (int r = 0; r < 4; ++r) {
            const int rowd = row_base + ((lane >> 4) << 2) + r;
            float v = acc[r] + bb;
            if constexpr (ACT) v = selu_f(v);
            if constexpr (RES) {
                v += C[(size_t)rowd * N + col];
                lsum += v; lsq += v * v;
            }
            C[(size_t)rowd * N + col] = v;
        }
        if constexpr (RES) {
            const int lcol = nt * 16 + (lane & 15);
            atomicAdd(&s_sum[lcol], lsum);
            atomicAdd(&s_sq[lcol], lsq);
        }
    }
    if constexpr (RES) {
        __syncthreads();
        if (tid < 64) {
            atomicAdd(&stats[blockIdx.y * 64 + tid], s_sum[tid]);
            atomicAdd(&stats[128 + blockIdx.y * 64 + tid], s_sq[tid]);
        }
    }
}

// ---------------------------------------------------------------------------
// Aggregation, one wave per dst node; PQ fp32 in, bf16 out.
// ---------------------------------------------------------------------------
template <int COUT>
__global__ __launch_bounds__(256) void agg_kernel(
    const float* __restrict__ PQ, const int* __restrict__ base,
    const int* __restrict__ sorted_src, const float* __restrict__ be,
    ushort_t* __restrict__ agg, int NN) {
    const int gid = blockIdx.x * blockDim.x + threadIdx.x;
    const int n = gid >> 6;
    const int lane = gid & 63;
    if (n >= NN) return;
    const int b0 = base[n], b1 = base[n + 1];

    if constexpr (COUT == 128) {
        float2 qv = *(const float2*)(PQ + (size_t)n * 256 + 128 + lane * 2);
        float2 bv = *(const float2*)(be + lane * 2);
        const float qx = qv.x + bv.x, qy = qv.y + bv.y;
        float ax = 0.0f, ay = 0.0f;
        for (int e = b0; e < b1; ++e) {
            const int src = sorted_src[e];
            float2 pp = *(const float2*)(PQ + (size_t)src * 256 + lane * 2);
            ax += selu_f(pp.x + qx);
            ay += selu_f(pp.y + qy);
        }
        ushort2 r; r.x = f2bf(ax); r.y = f2bf(ay);
        *(ushort2*)(agg + (size_t)n * 128 + lane * 2) = r;
    } else {
        const float q = PQ[(size_t)n * (2 * COUT) + COUT + lane] + be[lane];
        float a = 0.0f;
        for (int e = b0; e < b1; ++e) {
            const int src = sorted_src[e];
            a += selu_f(PQ[(size_t)src * (2 * COUT) + lane] + q);
        }
        agg[(size_t)n * COUT + lane] = f2bf(a);
    }
}

// ---------------------------------------------------------------------------
// BN normalize + SELU, in place on d_out.
// ---------------------------------------------------------------------------
__global__ __launch_bounds__(256) void bn_kernel(
    float* __restrict__ out, const float* __restrict__ stats,
    const float* __restrict__ gamma, const float* __restrict__ beta, int Nn) {
    const int i = blockIdx.x * blockDim.x + threadIdx.x;
    const int c = i & 127;
    const float invn = 1.0f / (float)Nn;
    float mu = stats[c] * invn;
    float var = stats[128 + c] * invn - mu * mu;
    float r = rsqrtf(var + 1e-5f);
    float v = (out[i] - mu) * r * gamma[c] + beta[c];
    out[i] = selu_f(v);
}

// ---------------------------------------------------------------------------
extern "C" void kernel_launch(void* const* d_in, const int* in_sizes, int n_in,
                              void* d_out, int out_size, void* d_ws, size_t ws_size,
                              hipStream_t stream) {
    const float* x     = (const float*)d_in[0];
    const float* pos_c = (const float*)d_in[1];
    const float* pos_f = (const float*)d_in[2];
    const int*   ei_c  = (const int*)d_in[3];
    const int*   ei_f  = (const int*)d_in[4];
    const float* We1 = (const float*)d_in[5];
    const float* be1 = (const float*)d_in[6];
    const float* Wn1 = (const float*)d_in[7];
    const float* bn1 = (const float*)d_in[8];
    const float* We2 = (const float*)d_in[9];
    const float* be2 = (const float*)d_in[10];
    const float* Wn2 = (const float*)d_in[11];
    const float* bn2 = (const float*)d_in[12];
    const float* WeS = (const float*)d_in[13];
    const float* beS = (const float*)d_in[14];
    const float* WnS = (const float*)d_in[15];
    const float* bnS = (const float*)d_in[16];
    const float* gamma = (const float*)d_in[17];
    const float* beta  = (const float*)d_in[18];

    char* w = (char*)d_ws;
    size_t o = 0;
    auto alloc = [&](size_t bytes) { void* p = w + o; o += (bytes + 255) & ~(size_t)255; return p; };
    int*      knn_idx = (int*)alloc((size_t)NF * 3 * sizeof(int));
    float*    knn_w   = (float*)alloc((size_t)NF * 3 * sizeof(float));
    ushort_t* x_upb   = (ushort_t*)alloc((size_t)NF * CIN * 2);
    float*    PQ      = (float*)alloc((size_t)NF * 2 * CO * sizeof(float));
    ushort_t* aggFb   = (ushort_t*)alloc((size_t)NF * CO * 2);
    float*    h1      = (float*)alloc((size_t)NC * CH * sizeof(float));
    ushort_t* agg1b   = (ushort_t*)alloc((size_t)NC * CH * 2);
    ushort_t* h_upb   = (ushort_t*)alloc((size_t)NF * CH * 2);
    ushort_t* xb      = (ushort_t*)alloc((size_t)NC * CIN * 2);
    ushort_t* WfS_pq  = (ushort_t*)alloc(128 * 256 * 2);
    ushort_t* Wf1_pq  = (ushort_t*)alloc(128 * 128 * 2);
    ushort_t* Wf2_pq  = (ushort_t*)alloc(64 * 256 * 2);
    ushort_t* WfS_n   = (ushort_t*)alloc(256 * 128 * 2);
    ushort_t* Wf1_n   = (ushort_t*)alloc(192 * 64 * 2);
    ushort_t* Wf2_n   = (ushort_t*)alloc(192 * 128 * 2);
    int*   cntF  = (int*)alloc((size_t)NF * sizeof(int));
    int*   baseF = (int*)alloc((size_t)(NF + 1) * sizeof(int));
    int*   cursF = (int*)alloc((size_t)NF * sizeof(int));
    int*   srtF  = (int*)alloc((size_t)EF * sizeof(int));
    int*   cntC  = (int*)alloc((size_t)NC * sizeof(int));
    int*   baseC = (int*)alloc((size_t)(NC + 1) * sizeof(int));
    int*   cursC = (int*)alloc((size_t)NC * sizeof(int));
    int*   srtC  = (int*)alloc((size_t)EC * sizeof(int));
    int*   cntG  = (int*)alloc((size_t)NCELL * sizeof(int));
    int*   baseG = (int*)alloc((size_t)(NCELL + 1) * sizeof(int));
    int*   cursG = (int*)alloc((size_t)NCELL * sizeof(int));
    float2* sposG = (float2*)alloc((size_t)NC * sizeof(float2));
    int*    sidxG = (int*)alloc((size_t)NC * sizeof(int));
    float* stats = (float*)alloc(256 * sizeof(float));
    float* outp = (float*)d_out;   // x_skip, then pre-BN+stats, then final

    // 1. conversions + zeroing
    {
        constexpr int TOTAL = NC * CIN + 128 * 256 + 128 * 128 + 64 * 256
                            + 256 * 128 + 192 * 64 + 192 * 128
                            + NF + NC + NCELL + 256;
        convert_kernel<<<(TOTAL + 255) / 256, 256, 0, stream>>>(
            x, xb, WeS, WfS_pq, We1, Wf1_pq, We2, Wf2_pq,
            WnS, WfS_n, Wn1, Wf1_n, Wn2, Wf2_n,
            cntF, cntC, cntG, stats);
    }

    // 2-4. merged counting sorts (fine edges, coarse edges, coarse points)
    constexpr int SORT_ITEMS = EF + EC + NC;
    hist3_kernel<<<(SORT_ITEMS + 255) / 256, 256, 0, stream>>>(
        ei_f, ei_c, pos_c, cntF, cntC, cntG);
    scan3_kernel<<<3, 1024, 0, stream>>>(
        cntF, baseF, cursF, cntC, baseC, cursC, cntG, baseG, cursG);
    scatter3_kernel<<<(SORT_ITEMS + 255) / 256, 256, 0, stream>>>(
        ei_f, ei_c, pos_c, cursF, srtF, cursC, srtC, cursG, sposG, sidxG);

    // 5. kNN via grid
    knn_grid_kernel<<<NF / 64, 64, 0, stream>>>(
        pos_f, sposG, sidxG, baseG, knn_idx, knn_w);

    // 6. upsample x -> bf16
    interp_kernel<128><<<NF * (128 / 4) / 256, 256, 0, stream>>>(x, knn_idx, knn_w, x_upb);

    // --- skip branch (fine graph, Cin->Cout) ---
    mfma_mlp<128, 0, 256, false, false><<<dim3(NF / 64, 4), 256, 0, stream>>>(
        x_upb, nullptr, WfS_pq, nullptr, PQ, nullptr);
    agg_kernel<128><<<NF / 4, 256, 0, stream>>>(PQ, baseF, srtF, beS, aggFb, NF);
    mfma_mlp<128, 128, 128, true, false><<<dim3(NF / 64, 2), 256, 0, stream>>>(
        x_upb, aggFb, WfS_n, bnS, outp, nullptr);        // outp = x_skip

    // --- coarse MPL (Cin->Ch) ---
    mfma_mlp<128, 0, 128, false, false><<<dim3(NC / 64, 2), 256, 0, stream>>>(
        xb, nullptr, Wf1_pq, nullptr, PQ, nullptr);
    agg_kernel<64><<<NC / 4, 256, 0, stream>>>(PQ, baseC, srtC, be1, agg1b, NC);
    mfma_mlp<128, 64, 64, true, false><<<dim3(NC / 64, 1), 256, 0, stream>>>(
        xb, agg1b, Wf1_n, bn1, h1, nullptr);

    // upsample h1 -> bf16
    interp_kernel<64><<<NF * (64 / 4) / 256, 256, 0, stream>>>(h1, knn_idx, knn_w, h_upb);

    // --- fine MPL (Ch->Cout), residual + stats fused ---
    mfma_mlp<64, 0, 256, false, false><<<dim3(NF / 64, 4), 256, 0, stream>>>(
        h_upb, nullptr, Wf2_pq, nullptr, PQ, nullptr);
    agg_kernel<128><<<NF / 4, 256, 0, stream>>>(PQ, baseF, srtF, be2, aggFb, NF);
    mfma_mlp<64, 128, 128, true, true><<<dim3(NF / 64, 2), 256, 0, stream>>>(
        h_upb, aggFb, Wf2_n, bn2, outp, stats);

    // BN + SELU
    bn_kernel<<<NF * CO / 256, 256, 0, stream>>>(outp, stats, gamma, beta, NF);
}

// Round 6
// 246.655 us; speedup vs baseline: 9.4295x; 1.0455x over previous
//
#include <hip/hip_runtime.h>

// ---------------------------------------------------------------------------
// Res_up block, round 6: "GEMM before interp" — knn_interpolate is linear, so
// interp(x)@W == interp(x@W). All fine-graph GEMM work whose input is an
// interpolation is done on the 4096 coarse nodes, then interpolated:
//   RA  = x  @ [P_S|Q_S (256) | U_S (128) | P_1|Q_1 (128)]   (4096x512x128)
//   RE  = h1 @ [P_2|Q_2 (256) | U_2 (128)]                   (4096x384x64)
// interp produces fine P/Q (bf16, for agg) and U (fp32, epilogue add).
// Remaining fine GEMMs: nodeS/nodeH at K=128. GEMM flops 4.8 -> 1.9 GF.
// 13 dispatches. knn fused into the RA GEMM dispatch.
// Sizes fixed: Nc=4096, Nf=16384, Ec=65536, Ef=262144, Cin=128, Ch=64, Co=128.
// ---------------------------------------------------------------------------

#define SELU_SCALE 1.0507009873554805f
#define SELU_ALPHA 1.6732632423543772f

static constexpr int NC = 4096, NF = 16384, EC = 65536, EF = 262144;
static constexpr int G = 32, NCELL = G * G;

typedef __attribute__((ext_vector_type(8))) short short8v;
typedef __attribute__((ext_vector_type(4))) float f32x4;
typedef unsigned short ushort_t;
typedef unsigned long long u64;

__device__ __forceinline__ float selu_f(float x) {
    return x > 0.0f ? SELU_SCALE * x
                    : SELU_SCALE * SELU_ALPHA * (__expf(x) - 1.0f);
}
__device__ __forceinline__ ushort_t f2bf(float f) {
    unsigned u = __float_as_uint(f);
    u += 0x7FFFu + ((u >> 16) & 1u);
    return (ushort_t)(u >> 16);
}
__device__ __forceinline__ float bf2f(ushort_t u) {
    return __uint_as_float(((unsigned)u) << 16);
}
__device__ __forceinline__ int cell_of(float2 p) {
    int cx = (int)(p.x * (float)G); cx = cx > G - 1 ? G - 1 : cx;
    int cy = (int)(p.y * (float)G); cy = cy > G - 1 ? G - 1 : cy;
    return cy * G + cx;
}

// ---------------------------------------------------------------------------
// Fragment-major weight writer: Wf[(ntile*KC+kc)*512 + lane*8 + e] = W[k][col]
//   k = kc*32 + (lane>>4)*8 + e, col = ntile*16 + (lane&15)
// ---------------------------------------------------------------------------
template <int K, typename F>
__device__ __forceinline__ void wfrag(F getw, ushort_t* __restrict__ dst, int idx) {
    constexpr int KC = K / 32;
    const int f = idx >> 9;
    const int r = idx & 511;
    const int lane = r >> 3;
    const int e = r & 7;
    const int ntile = f / KC;
    const int kc = f - ntile * KC;
    const int k = kc * 32 + ((lane >> 4) << 3) + e;
    const int col = ntile * 16 + (lane & 15);
    dst[idx] = f2bf(getw(k, col));
}

// ---------------------------------------------------------------------------
// prep: x->bf16, 5 weight-frag buffers, zero cnt/stats.
// ---------------------------------------------------------------------------
__global__ __launch_bounds__(256) void prep_kernel(
    const float* __restrict__ x, ushort_t* __restrict__ xb,
    const float* __restrict__ WeS, const float* __restrict__ WnS,
    const float* __restrict__ We1, const float* __restrict__ We2,
    const float* __restrict__ Wn2, const float* __restrict__ Wn1,
    ushort_t* __restrict__ WfA, ushort_t* __restrict__ WfE,
    ushort_t* __restrict__ WfSn, ushort_t* __restrict__ Wf1n,
    ushort_t* __restrict__ Wf2n,
    int* __restrict__ cntF, int* __restrict__ cntC, int* __restrict__ cntG,
    float* __restrict__ stats) {
    int i = blockIdx.x * 256 + threadIdx.x;
    if (i < NC * 128) { xb[i] = f2bf(x[i]); return; }
    i -= NC * 128;
    if (i < 65536) {   // RA weights: K=128, N=512
        wfrag<128>([&](int k, int j) {
            return j < 128 ? WeS[k * 128 + j]
                 : j < 256 ? WeS[(128 + k) * 128 + (j - 128)]
                 : j < 384 ? WnS[k * 128 + (j - 256)]
                 : j < 448 ? We1[k * 64 + (j - 384)]
                           : We1[(128 + k) * 64 + (j - 448)];
        }, WfA, i);
        return;
    }
    i -= 65536;
    if (i < 24576) {   // RE weights: K=64, N=384
        wfrag<64>([&](int k, int j) {
            return j < 128 ? We2[k * 128 + j]
                 : j < 256 ? We2[(64 + k) * 128 + (j - 128)]
                           : Wn2[k * 128 + (j - 256)];
        }, WfE, i);
        return;
    }
    i -= 24576;
    if (i < 16384) {   // nodeS: WnS bottom half, K=128, N=128
        wfrag<128>([&](int k, int j) { return WnS[(128 + k) * 128 + j]; }, WfSn, i);
        return;
    }
    i -= 16384;
    if (i < 12288) {   // node1: full Wn1, K=192, N=64
        wfrag<192>([&](int k, int j) { return Wn1[k * 64 + j]; }, Wf1n, i);
        return;
    }
    i -= 12288;
    if (i < 16384) {   // nodeH: Wn2 bottom, K=128, N=128
        wfrag<128>([&](int k, int j) { return Wn2[(64 + k) * 128 + j]; }, Wf2n, i);
        return;
    }
    i -= 16384;
    if (i < NF) { cntF[i] = 0; return; }
    i -= NF;
    if (i < NC) { cntC[i] = 0; return; }
    i -= NC;
    if (i < NCELL) { cntG[i] = 0; return; }
    i -= NCELL;
    if (i < 256) { stats[i] = 0.0f; return; }
}

// ---------------------------------------------------------------------------
// merged histogram / scan / scatter for {fine edges, coarse edges, grid cells}
// ---------------------------------------------------------------------------
__global__ __launch_bounds__(256) void hist3_kernel(
    const int* __restrict__ ei_f, const int* __restrict__ ei_c,
    const float* __restrict__ pos_c,
    int* __restrict__ cntF, int* __restrict__ cntC, int* __restrict__ cntG) {
    int i = blockIdx.x * 256 + threadIdx.x;
    if (i < EF) { atomicAdd(&cntF[ei_f[EF + i]], 1); return; }
    i -= EF;
    if (i < EC) { atomicAdd(&cntC[ei_c[EC + i]], 1); return; }
    i -= EC;
    if (i < NC) {
        float2 p = ((const float2*)pos_c)[i];
        atomicAdd(&cntG[cell_of(p)], 1);
    }
}

__global__ __launch_bounds__(1024) void scan3_kernel(
    int* __restrict__ cntF, int* __restrict__ baseF, int* __restrict__ cursF,
    int* __restrict__ cntC, int* __restrict__ baseC, int* __restrict__ cursC,
    int* __restrict__ cntG, int* __restrict__ baseG, int* __restrict__ cursG) {
    const int* cnt; int* base; int* curs; int n;
    if (blockIdx.x == 0)      { cnt = cntF; base = baseF; curs = cursF; n = NF; }
    else if (blockIdx.x == 1) { cnt = cntC; base = baseC; curs = cursC; n = NC; }
    else                      { cnt = cntG; base = baseG; curs = cursG; n = NCELL; }
    const int IT = n >> 10;
    __shared__ int part[1024];
    const int t = threadIdx.x;
    int loc[16];
    int s = 0;
#pragma unroll
    for (int i = 0; i < 16; ++i) {
        int v = (i < IT) ? cnt[t * IT + i] : 0;
        loc[i] = v; s += v;
    }
    part[t] = s;
    __syncthreads();
    for (int off = 1; off < 1024; off <<= 1) {
        int v = part[t];
        int u = (t >= off) ? part[t - off] : 0;
        __syncthreads();
        part[t] = v + u;
        __syncthreads();
    }
    int ex = (t == 0) ? 0 : part[t - 1];
#pragma unroll
    for (int i = 0; i < 16; ++i) {
        if (i < IT) {
            base[t * IT + i] = ex;
            curs[t * IT + i] = ex;
            ex += loc[i];
        }
    }
    if (t == 1023) base[n] = ex;
}

__global__ __launch_bounds__(256) void scatter3_kernel(
    const int* __restrict__ ei_f, const int* __restrict__ ei_c,
    const float* __restrict__ pos_c,
    int* __restrict__ cursF, int* __restrict__ srtF,
    int* __restrict__ cursC, int* __restrict__ srtC,
    int* __restrict__ cursG, float2* __restrict__ sposG, int* __restrict__ sidxG) {
    int i = blockIdx.x * 256 + threadIdx.x;
    if (i < EF) {
        int pos = atomicAdd(&cursF[ei_f[EF + i]], 1);
        srtF[pos] = ei_f[i];
        return;
    }
    i -= EF;
    if (i < EC) {
        int pos = atomicAdd(&cursC[ei_c[EC + i]], 1);
        srtC[pos] = ei_c[i];
        return;
    }
    i -= EC;
    if (i < NC) {
        float2 p = ((const float2*)pos_c)[i];
        int pos = atomicAdd(&cursG[cell_of(p)], 1);
        sposG[pos] = p;
        sidxG[pos] = i;
    }
}

// ---------------------------------------------------------------------------
// Fused dispatch: blocks 0..255 = RA GEMM (4096x512x128 bf16 MFMA);
// blocks 256..319 = grid-kNN (one thread per fine point, expanding rings).
// ---------------------------------------------------------------------------
__global__ __launch_bounds__(256) void gemmA_knn_kernel(
    const ushort_t* __restrict__ xb, const ushort_t* __restrict__ WfA,
    float* __restrict__ RA,
    const float* __restrict__ pos_f, const float2* __restrict__ sposG,
    const int* __restrict__ sidxG, const int* __restrict__ baseG,
    int* __restrict__ knn_idx, float* __restrict__ knn_w) {
    const int bid = blockIdx.x;
    const int tid = threadIdx.x;
    if (bid < 256) {
        const int wid = tid >> 6, lane = tid & 63;
        const int bx = bid >> 2, by = bid & 3;
        const int row_base = bx * 64 + wid * 16;
        const int row_a = row_base + (lane & 15);
        const int klane = (lane >> 4) << 3;
        short8v a[4];
#pragma unroll
        for (int f = 0; f < 4; ++f)
            a[f] = *(const short8v*)(xb + (size_t)row_a * 128 + f * 32 + klane);
#pragma unroll
        for (int nt = 0; nt < 8; ++nt) {
            const int ntg = by * 8 + nt;
            f32x4 acc = {0.0f, 0.0f, 0.0f, 0.0f};
#pragma unroll
            for (int f = 0; f < 4; ++f) {
                const short8v b =
                    *(const short8v*)(WfA + (size_t)(ntg * 4 + f) * 512 + lane * 8);
                acc = __builtin_amdgcn_mfma_f32_16x16x32_bf16(a[f], b, acc, 0, 0, 0);
            }
            const int col = ntg * 16 + (lane & 15);
            const int r0 = row_base + ((lane >> 4) << 2);
#pragma unroll
            for (int r = 0; r < 4; ++r)
                RA[(size_t)(r0 + r) * 512 + col] = acc[r];
        }
    } else {
        const int t = (bid - 256) * 256 + tid;
        const float2 p = ((const float2*)pos_f)[t];
        int cx = (int)(p.x * (float)G); cx = cx > G - 1 ? G - 1 : cx;
        int cy = (int)(p.y * (float)G); cy = cy > G - 1 ? G - 1 : cy;

        u64 b0 = ~0ull, b1 = ~0ull, b2 = ~0ull;
        const float h = 1.0f / (float)G;

        auto scan_range = [&](int c0, int c1) {
            const int s0 = baseG[c0], s1 = baseG[c1 + 1];
            for (int i = s0; i < s1; ++i) {
                const float2 q = sposG[i];
                const float dx = p.x - q.x;
                const float dy = p.y - q.y;
                const float d = dx * dx + dy * dy;
                const u64 v = ((u64)__float_as_uint(d) << 32) | (unsigned)sidxG[i];
                if (v < b2) {
                    if (v < b1) {
                        b2 = b1;
                        if (v < b0) { b1 = b0; b0 = v; } else b1 = v;
                    } else b2 = v;
                }
            }
        };

        for (int r = 0; r < G; ++r) {
            if (r >= 1) {
                const float bd = __uint_as_float((unsigned)(b2 >> 32));
                const float lim = (float)(r - 1) * h;
                if (bd < lim * lim) break;
            }
            if (r == 0) {
                scan_range(cy * G + cx, cy * G + cx);
            } else {
                const int x0 = cx - r < 0 ? 0 : cx - r;
                const int x1 = cx + r > G - 1 ? G - 1 : cx + r;
                const int yT = cy - r, yB = cy + r;
                if (yT >= 0) scan_range(yT * G + x0, yT * G + x1);
                if (yB <= G - 1) scan_range(yB * G + x0, yB * G + x1);
                const int yy0 = yT + 1 < 0 ? 0 : yT + 1;
                const int yy1 = yB - 1 > G - 1 ? G - 1 : yB - 1;
                if (cx - r >= 0)
                    for (int y = yy0; y <= yy1; ++y) scan_range(y * G + cx - r, y * G + cx - r);
                if (cx + r <= G - 1)
                    for (int y = yy0; y <= yy1; ++y) scan_range(y * G + cx + r, y * G + cx + r);
            }
        }

        const float d0 = __uint_as_float((unsigned)(b0 >> 32));
        const float d1 = __uint_as_float((unsigned)(b1 >> 32));
        const float d2 = __uint_as_float((unsigned)(b2 >> 32));
        const float w0 = 1.0f / fmaxf(d0, 1e-16f);
        const float w1 = 1.0f / fmaxf(d1, 1e-16f);
        const float w2 = 1.0f / fmaxf(d2, 1e-16f);
        const float s = 1.0f / (w0 + w1 + w2);
        knn_idx[t * 3 + 0] = (int)(b0 & 0xffffffffu);
        knn_idx[t * 3 + 1] = (int)(b1 & 0xffffffffu);
        knn_idx[t * 3 + 2] = (int)(b2 & 0xffffffffu);
        knn_w[t * 3 + 0] = w0 * s;
        knn_w[t * 3 + 1] = w1 * s;
        knn_w[t * 3 + 2] = w2 * s;
    }
}

// ---------------------------------------------------------------------------
// interp of coarse result rows: cols 0..255 -> PQf (bf16), 256..383 -> Uf (f32)
// thread per (t, 4-ch group); 96 groups per fine node.
// ---------------------------------------------------------------------------
template <int STRIDE>
__global__ __launch_bounds__(256) void interp_kernel(
    const float* __restrict__ R, const int* __restrict__ knn_idx,
    const float* __restrict__ knn_w, ushort_t* __restrict__ PQf,
    float* __restrict__ Uf) {
    const int tid = blockIdx.x * 256 + threadIdx.x;
    const int t = tid / 96;
    const int g = tid - t * 96;
    const int i0 = knn_idx[t * 3 + 0], i1 = knn_idx[t * 3 + 1], i2 = knn_idx[t * 3 + 2];
    const float w0 = knn_w[t * 3 + 0], w1 = knn_w[t * 3 + 1], w2 = knn_w[t * 3 + 2];
    const float4 a = *(const float4*)(R + (size_t)i0 * STRIDE + g * 4);
    const float4 b = *(const float4*)(R + (size_t)i1 * STRIDE + g * 4);
    const float4 c = *(const float4*)(R + (size_t)i2 * STRIDE + g * 4);
    float4 v;
    v.x = w0 * a.x + w1 * b.x + w2 * c.x;
    v.y = w0 * a.y + w1 * b.y + w2 * c.y;
    v.z = w0 * a.z + w1 * b.z + w2 * c.z;
    v.w = w0 * a.w + w1 * b.w + w2 * c.w;
    if (g < 64) {
        ushort4 o;
        o.x = f2bf(v.x); o.y = f2bf(v.y); o.z = f2bf(v.z); o.w = f2bf(v.w);
        *(ushort4*)(PQf + (size_t)t * 256 + g * 4) = o;
    } else {
        *(float4*)(Uf + (size_t)t * 128 + (g - 64) * 4) = v;
    }
}

// ---------------------------------------------------------------------------
// agg: fine part (bf16 PQf, 128 ch, 2 ch/lane) and optional coarse part
// (fp32 RA cols 384..511, 64 ch). One wave per dst node.
// ---------------------------------------------------------------------------
template <bool DUAL>
__global__ __launch_bounds__(256) void agg_kernel(
    const ushort_t* __restrict__ PQf, const int* __restrict__ baseF,
    const int* __restrict__ srtF, const float* __restrict__ beF,
    ushort_t* __restrict__ aggF,
    const float* __restrict__ RA, const int* __restrict__ baseC,
    const int* __restrict__ srtC, const float* __restrict__ beC,
    ushort_t* __restrict__ aggC) {
    const int bid = blockIdx.x;
    const int wid = threadIdx.x >> 6, lane = threadIdx.x & 63;
    if (!DUAL || bid < NF / 4) {
        const int n = bid * 4 + wid;
        const int b0 = baseF[n], b1 = baseF[n + 1];
        const ushort2 qv = *(const ushort2*)(PQf + (size_t)n * 256 + 128 + lane * 2);
        const float2 bv = *(const float2*)(beF + lane * 2);
        const float qx = bf2f(qv.x) + bv.x, qy = bf2f(qv.y) + bv.y;
        float ax = 0.0f, ay = 0.0f;
        for (int e = b0; e < b1; ++e) {
            const int src = srtF[e];
            const ushort2 pv = *(const ushort2*)(PQf + (size_t)src * 256 + lane * 2);
            ax += selu_f(bf2f(pv.x) + qx);
            ay += selu_f(bf2f(pv.y) + qy);
        }
        ushort2 r; r.x = f2bf(ax); r.y = f2bf(ay);
        *(ushort2*)(aggF + (size_t)n * 128 + lane * 2) = r;
    } else {
        const int n = (bid - NF / 4) * 4 + wid;
        const int b0 = baseC[n], b1 = baseC[n + 1];
        const float q = RA[(size_t)n * 512 + 448 + lane] + beC[lane];
        float s = 0.0f;
        for (int e = b0; e < b1; ++e) {
            const int src = srtC[e];
            s += selu_f(RA[(size_t)src * 512 + 384 + lane] + q);
        }
        aggC[(size_t)n * 64 + lane] = f2bf(s);
    }
}

// ---------------------------------------------------------------------------
// nodeS (blocks 0..255): x_skip = selu(aggF@WnS_bot + UfS + bnS) -> outp f32
// node1 (blocks 256..319): h1 = selu(concat(xb,agg1b)@Wn1 + bn1) -> h1b bf16
// ---------------------------------------------------------------------------
__global__ __launch_bounds__(256) void nodeSD_kernel(
    const ushort_t* __restrict__ aggF, const ushort_t* __restrict__ WfSn,
    const float* __restrict__ bnS, const float* __restrict__ UfS,
    float* __restrict__ outp,
    const ushort_t* __restrict__ xb, const ushort_t* __restrict__ agg1b,
    const ushort_t* __restrict__ Wf1n, const float* __restrict__ bn1,
    ushort_t* __restrict__ h1b) {
    const int tid = threadIdx.x;
    const int wid = tid >> 6, lane = tid & 63;
    const int klane = (lane >> 4) << 3;
    if (blockIdx.x < 256) {
        const int row_base = blockIdx.x * 64 + wid * 16;
        const int row_a = row_base + (lane & 15);
        short8v a[4];
#pragma unroll
        for (int f = 0; f < 4; ++f)
            a[f] = *(const short8v*)(aggF + (size_t)row_a * 128 + f * 32 + klane);
#pragma unroll
        for (int nt = 0; nt < 8; ++nt) {
            f32x4 acc = {0.0f, 0.0f, 0.0f, 0.0f};
#pragma unroll
            for (int f = 0; f < 4; ++f) {
                const short8v b =
                    *(const short8v*)(WfSn + (size_t)(nt * 4 + f) * 512 + lane * 8);
                acc = __builtin_amdgcn_mfma_f32_16x16x32_bf16(a[f], b, acc, 0, 0, 0);
            }
            const int col = nt * 16 + (lane & 15);
            const int r0 = row_base + ((lane >> 4) << 2);
#pragma unroll
            for (int r = 0; r < 4; ++r) {
                const size_t o = (size_t)(r0 + r) * 128 + col;
                outp[o] = selu_f(acc[r] + bnS[col] + UfS[o]);
            }
        }
    } else {
        const int row_base = (blockIdx.x - 256) * 64 + wid * 16;
        const int row_a = row_base + (lane & 15);
        short8v a[6];
#pragma unroll
        for (int f = 0; f < 4; ++f)
            a[f] = *(const short8v*)(xb + (size_t)row_a * 128 + f * 32 + klane);
#pragma unroll
        for (int f = 0; f < 2; ++f)
            a[4 + f] = *(const short8v*)(agg1b + (size_t)row_a * 64 + f * 32 + klane);
#pragma unroll
        for (int nt = 0; nt < 4; ++nt) {
            f32x4 acc = {0.0f, 0.0f, 0.0f, 0.0f};
#pragma unroll
            for (int f = 0; f < 6; ++f) {
                const short8v b =
                    *(const short8v*)(Wf1n + (size_t)(nt * 6 + f) * 512 + lane * 8);
                acc = __builtin_amdgcn_mfma_f32_16x16x32_bf16(a[f], b, acc, 0, 0, 0);
            }
            const int col = nt * 16 + (lane & 15);
            const int r0 = row_base + ((lane >> 4) << 2);
#pragma unroll
            for (int r = 0; r < 4; ++r)
                h1b[(size_t)(r0 + r) * 64 + col] = f2bf(selu_f(acc[r] + bn1[col]));
        }
    }
}

// ---------------------------------------------------------------------------
// RE GEMM: h1b(4096x64) @ WfE -> RE (4096x384 f32). 256 blocks.
// ---------------------------------------------------------------------------
__global__ __launch_bounds__(256) void gemmE_kernel(
    const ushort_t* __restrict__ h1b, const ushort_t* __restrict__ WfE,
    float* __restrict__ RE) {
    const int tid = threadIdx.x;
    const int wid = tid >> 6, lane = tid & 63;
    const int bx = blockIdx.x >> 2, by = blockIdx.x & 3;
    const int row_base = bx * 64 + wid * 16;
    const int row_a = row_base + (lane & 15);
    const int klane = (lane >> 4) << 3;
    short8v a[2];
#pragma unroll
    for (int f = 0; f < 2; ++f)
        a[f] = *(const short8v*)(h1b + (size_t)row_a * 64 + f * 32 + klane);
#pragma unroll
    for (int nt = 0; nt < 6; ++nt) {
        const int ntg = by * 6 + nt;
        f32x4 acc = {0.0f, 0.0f, 0.0f, 0.0f};
#pragma unroll
        for (int f = 0; f < 2; ++f) {
            const short8v b =
                *(const short8v*)(WfE + (size_t)(ntg * 2 + f) * 512 + lane * 8);
            acc = __builtin_amdgcn_mfma_f32_16x16x32_bf16(a[f], b, acc, 0, 0, 0);
        }
        const int col = ntg * 16 + (lane & 15);
        const int r0 = row_base + ((lane >> 4) << 2);
#pragma unroll
        for (int r = 0; r < 4; ++r)
            RE[(size_t)(r0 + r) * 384 + col] = acc[r];
    }
}

// ---------------------------------------------------------------------------
// nodeH: v = selu(aggF@Wn2_bot + Uf2 + bn2) + x_skip; write outp; BN stats.
// ---------------------------------------------------------------------------
__global__ __launch_bounds__(256) void nodeH_kernel(
    const ushort_t* __restrict__ aggF, const ushort_t* __restrict__ Wf2n,
    const float* __restrict__ bn2, const float* __restrict__ Uf2,
    float* __restrict__ outp, float* __restrict__ stats) {
    __shared__ float s_sum[128], s_sq[128];
    const int tid = threadIdx.x;
    const int wid = tid >> 6, lane = tid & 63;
    const int klane = (lane >> 4) << 3;
    if (tid < 128) { s_sum[tid] = 0.0f; s_sq[tid] = 0.0f; }
    __syncthreads();
    const int row_base = blockIdx.x * 64 + wid * 16;
    const int row_a = row_base + (lane & 15);
    short8v a[4];
#pragma unroll
    for (int f = 0; f < 4; ++f)
        a[f] = *(const short8v*)(aggF + (size_t)row_a * 128 + f * 32 + klane);
#pragma unroll
    for (int nt = 0; nt < 8; ++nt) {
        f32x4 acc = {0.0f, 0.0f, 0.0f, 0.0f};
#pragma unroll
        for (int f = 0; f < 4; ++f) {
            const short8v b =
                *(const short8v*)(Wf2n + (size_t)(nt * 4 + f) * 512 + lane * 8);
            acc = __builtin_amdgcn_mfma_f32_16x16x32_bf16(a[f], b, acc, 0, 0, 0);
        }
        const int col = nt * 16 + (lane & 15);
        const int r0 = row_base + ((lane >> 4) << 2);
        float lsum = 0.0f, lsq = 0.0f;
#pragma unroll
        for (int r = 0; r < 4; ++r) {
            const size_t o = (size_t)(r0 + r) * 128 + col;
            float v = selu_f(acc[r] + bn2[col] + Uf2[o]) + outp[o];
            outp[o] = v;
            lsum += v; lsq += v * v;
        }
        atomicAdd(&s_sum[nt * 16 + (lane & 15)], lsum);
        atomicAdd(&s_sq[nt * 16 + (lane & 15)], lsq);
    }
    __syncthreads();
    if (tid < 128) {
        atomicAdd(&stats[tid], s_sum[tid]);
        atomicAdd(&stats[128 + tid], s_sq[tid]);
    }
}

// ---------------------------------------------------------------------------
// BN normalize + SELU, in place on d_out.
// ---------------------------------------------------------------------------
__global__ __launch_bounds__(256) void bn_kernel(
    float* __restrict__ out, const float* __restrict__ stats,
    const float* __restrict__ gamma, const float* __restrict__ beta, int Nn) {
    const int i = blockIdx.x * blockDim.x + threadIdx.x;
    const int c = i & 127;
    const float invn = 1.0f / (float)Nn;
    float mu = stats[c] * invn;
    float var = stats[128 + c] * invn - mu * mu;
    float r = rsqrtf(var + 1e-5f);
    float v = (out[i] - mu) * r * gamma[c] + beta[c];
    out[i] = selu_f(v);
}

// ---------------------------------------------------------------------------
extern "C" void kernel_launch(void* const* d_in, const int* in_sizes, int n_in,
                              void* d_out, int out_size, void* d_ws, size_t ws_size,
                              hipStream_t stream) {
    const float* x     = (const float*)d_in[0];
    const float* pos_c = (const float*)d_in[1];
    const float* pos_f = (const float*)d_in[2];
    const int*   ei_c  = (const int*)d_in[3];
    const int*   ei_f  = (const int*)d_in[4];
    const float* We1 = (const float*)d_in[5];
    const float* be1 = (const float*)d_in[6];
    const float* Wn1 = (const float*)d_in[7];
    const float* bn1 = (const float*)d_in[8];
    const float* We2 = (const float*)d_in[9];
    const float* be2 = (const float*)d_in[10];
    const float* Wn2 = (const float*)d_in[11];
    const float* bn2 = (const float*)d_in[12];
    const float* WeS = (const float*)d_in[13];
    const float* beS = (const float*)d_in[14];
    const float* WnS = (const float*)d_in[15];
    const float* bnS = (const float*)d_in[16];
    const float* gamma = (const float*)d_in[17];
    const float* beta  = (const float*)d_in[18];

    char* w = (char*)d_ws;
    size_t o = 0;
    auto alloc = [&](size_t bytes) { void* p = w + o; o += (bytes + 255) & ~(size_t)255; return p; };
    int*      knn_idx = (int*)alloc((size_t)NF * 3 * sizeof(int));
    float*    knn_w   = (float*)alloc((size_t)NF * 3 * sizeof(float));
    float*    RA      = (float*)alloc((size_t)NC * 512 * sizeof(float));  // also RE
    ushort_t* PQf     = (ushort_t*)alloc((size_t)NF * 256 * 2);           // reused
    float*    Uf      = (float*)alloc((size_t)NF * 128 * sizeof(float));  // reused
    ushort_t* aggF    = (ushort_t*)alloc((size_t)NF * 128 * 2);           // reused
    ushort_t* agg1b   = (ushort_t*)alloc((size_t)NC * 64 * 2);
    ushort_t* h1b     = (ushort_t*)alloc((size_t)NC * 64 * 2);
    ushort_t* xb      = (ushort_t*)alloc((size_t)NC * 128 * 2);
    ushort_t* WfA     = (ushort_t*)alloc(65536 * 2);
    ushort_t* WfE     = (ushort_t*)alloc(24576 * 2);
    ushort_t* WfSn    = (ushort_t*)alloc(16384 * 2);
    ushort_t* Wf1n    = (ushort_t*)alloc(12288 * 2);
    ushort_t* Wf2n    = (ushort_t*)alloc(16384 * 2);
    int*   cntF  = (int*)alloc((size_t)NF * sizeof(int));
    int*   baseF = (int*)alloc((size_t)(NF + 1) * sizeof(int));
    int*   cursF = (int*)alloc((size_t)NF * sizeof(int));
    int*   srtF  = (int*)alloc((size_t)EF * sizeof(int));
    int*   cntC  = (int*)alloc((size_t)NC * sizeof(int));
    int*   baseC = (int*)alloc((size_t)(NC + 1) * sizeof(int));
    int*   cursC = (int*)alloc((size_t)NC * sizeof(int));
    int*   srtC  = (int*)alloc((size_t)EC * sizeof(int));
    int*   cntG  = (int*)alloc((size_t)NCELL * sizeof(int));
    int*   baseG = (int*)alloc((size_t)(NCELL + 1) * sizeof(int));
    int*   cursG = (int*)alloc((size_t)NCELL * sizeof(int));
    float2* sposG = (float2*)alloc((size_t)NC * sizeof(float2));
    int*    sidxG = (int*)alloc((size_t)NC * sizeof(int));
    float* stats = (float*)alloc(256 * sizeof(float));
    float* outp = (float*)d_out;

    // 1. prep (converts + weight frags + zeroing)
    constexpr int PREP_TOTAL = NC * 128 + 65536 + 24576 + 16384 + 12288 + 16384
                             + NF + NC + NCELL + 256;
    prep_kernel<<<(PREP_TOTAL + 255) / 256, 256, 0, stream>>>(
        x, xb, WeS, WnS, We1, We2, Wn2, Wn1,
        WfA, WfE, WfSn, Wf1n, Wf2n, cntF, cntC, cntG, stats);

    // 2-4. merged counting sorts
    constexpr int SORT_ITEMS = EF + EC + NC;
    hist3_kernel<<<(SORT_ITEMS + 255) / 256, 256, 0, stream>>>(
        ei_f, ei_c, pos_c, cntF, cntC, cntG);
    scan3_kernel<<<3, 1024, 0, stream>>>(
        cntF, baseF, cursF, cntC, baseC, cursC, cntG, baseG, cursG);
    scatter3_kernel<<<(SORT_ITEMS + 255) / 256, 256, 0, stream>>>(
        ei_f, ei_c, pos_c, cursF, srtF, cursC, srtC, cursG, sposG, sidxG);

    // 5. RA GEMM + kNN (fused)
    gemmA_knn_kernel<<<320, 256, 0, stream>>>(
        xb, WfA, RA, pos_f, sposG, sidxG, baseG, knn_idx, knn_w);

    // 6. interp RA -> PQf(S) + Uf(S)
    interp_kernel<512><<<NF * 96 / 256, 256, 0, stream>>>(RA, knn_idx, knn_w, PQf, Uf);

    // 7. agg: fine skip + coarse mpl1 (fused)
    agg_kernel<true><<<NF / 4 + NC / 4, 256, 0, stream>>>(
        PQf, baseF, srtF, beS, aggF, RA, baseC, srtC, be1, agg1b);

    // 8. nodeS (x_skip -> d_out) + node1 (h1b) (fused)
    nodeSD_kernel<<<320, 256, 0, stream>>>(
        aggF, WfSn, bnS, Uf, outp, xb, agg1b, Wf1n, bn1, h1b);

    // 9. RE GEMM (mpl2 coarse part)
    gemmE_kernel<<<256, 256, 0, stream>>>(h1b, WfE, RA);

    // 10. interp RE -> PQf(2) + Uf(2)
    interp_kernel<384><<<NF * 96 / 256, 256, 0, stream>>>(RA, knn_idx, knn_w, PQf, Uf);

    // 11. agg2 (fine)
    agg_kernel<false><<<NF / 4, 256, 0, stream>>>(
        PQf, baseF, srtF, be2, aggF, nullptr, nullptr, nullptr, nullptr, nullptr);

    // 12. nodeH: final MLP + residual + BN stats
    nodeH_kernel<<<256, 256, 0, stream>>>(aggF, Wf2n, bn2, Uf, outp, stats);

    // 13. BN + SELU
    bn_kernel<<<NF * 128 / 256, 256, 0, stream>>>(outp, stats, gamma, beta, NF);
}

// Round 7
// 238.252 us; speedup vs baseline: 9.7620x; 1.0353x over previous
//
#include <hip/hip_runtime.h>

// ---------------------------------------------------------------------------
// Res_up block, round 7: round 6 + kNN re-parallelized (4 lanes/point, packed
// 16B grid records, shfl-merged top-3, cooperative rare-ring fallback) and
// Uf stored as bf16.
// Sizes fixed: Nc=4096, Nf=16384, Ec=65536, Ef=262144, Cin=128, Ch=64, Co=128.
// ---------------------------------------------------------------------------

#define SELU_SCALE 1.0507009873554805f
#define SELU_ALPHA 1.6732632423543772f

static constexpr int NC = 4096, NF = 16384, EC = 65536, EF = 262144;
static constexpr int G = 32, NCELL = G * G;

typedef __attribute__((ext_vector_type(8))) short short8v;
typedef __attribute__((ext_vector_type(4))) float f32x4;
typedef unsigned short ushort_t;
typedef unsigned long long u64;

__device__ __forceinline__ float selu_f(float x) {
    return x > 0.0f ? SELU_SCALE * x
                    : SELU_SCALE * SELU_ALPHA * (__expf(x) - 1.0f);
}
__device__ __forceinline__ ushort_t f2bf(float f) {
    unsigned u = __float_as_uint(f);
    u += 0x7FFFu + ((u >> 16) & 1u);
    return (ushort_t)(u >> 16);
}
__device__ __forceinline__ float bf2f(ushort_t u) {
    return __uint_as_float(((unsigned)u) << 16);
}
__device__ __forceinline__ int cell_of(float2 p) {
    int cx = (int)(p.x * (float)G); cx = cx > G - 1 ? G - 1 : cx;
    int cy = (int)(p.y * (float)G); cy = cy > G - 1 ? G - 1 : cy;
    return cy * G + cx;
}
// insert v into sorted triple (a0<=a1<=a2); strict < keeps stable tie order
__device__ __forceinline__ void ins3(u64& a0, u64& a1, u64& a2, u64 v) {
    if (v < a2) {
        if (v < a1) {
            a2 = a1;
            if (v < a0) { a1 = a0; a0 = v; } else a1 = v;
        } else a2 = v;
    }
}

// ---------------------------------------------------------------------------
// Fragment-major weight writer: Wf[(ntile*KC+kc)*512 + lane*8 + e] = W[k][col]
// ---------------------------------------------------------------------------
template <int K, typename F>
__device__ __forceinline__ void wfrag(F getw, ushort_t* __restrict__ dst, int idx) {
    constexpr int KC = K / 32;
    const int f = idx >> 9;
    const int r = idx & 511;
    const int lane = r >> 3;
    const int e = r & 7;
    const int ntile = f / KC;
    const int kc = f - ntile * KC;
    const int k = kc * 32 + ((lane >> 4) << 3) + e;
    const int col = ntile * 16 + (lane & 15);
    dst[idx] = f2bf(getw(k, col));
}

// ---------------------------------------------------------------------------
// prep: x->bf16, 5 weight-frag buffers, zero cnt/stats.
// ---------------------------------------------------------------------------
__global__ __launch_bounds__(256) void prep_kernel(
    const float* __restrict__ x, ushort_t* __restrict__ xb,
    const float* __restrict__ WeS, const float* __restrict__ WnS,
    const float* __restrict__ We1, const float* __restrict__ We2,
    const float* __restrict__ Wn2, const float* __restrict__ Wn1,
    ushort_t* __restrict__ WfA, ushort_t* __restrict__ WfE,
    ushort_t* __restrict__ WfSn, ushort_t* __restrict__ Wf1n,
    ushort_t* __restrict__ Wf2n,
    int* __restrict__ cntF, int* __restrict__ cntC, int* __restrict__ cntG,
    float* __restrict__ stats) {
    int i = blockIdx.x * 256 + threadIdx.x;
    if (i < NC * 128) { xb[i] = f2bf(x[i]); return; }
    i -= NC * 128;
    if (i < 65536) {   // RA weights: K=128, N=512
        wfrag<128>([&](int k, int j) {
            return j < 128 ? WeS[k * 128 + j]
                 : j < 256 ? WeS[(128 + k) * 128 + (j - 128)]
                 : j < 384 ? WnS[k * 128 + (j - 256)]
                 : j < 448 ? We1[k * 64 + (j - 384)]
                           : We1[(128 + k) * 64 + (j - 448)];
        }, WfA, i);
        return;
    }
    i -= 65536;
    if (i < 24576) {   // RE weights: K=64, N=384
        wfrag<64>([&](int k, int j) {
            return j < 128 ? We2[k * 128 + j]
                 : j < 256 ? We2[(64 + k) * 128 + (j - 128)]
                           : Wn2[k * 128 + (j - 256)];
        }, WfE, i);
        return;
    }
    i -= 24576;
    if (i < 16384) {   // nodeS: WnS bottom half, K=128, N=128
        wfrag<128>([&](int k, int j) { return WnS[(128 + k) * 128 + j]; }, WfSn, i);
        return;
    }
    i -= 16384;
    if (i < 12288) {   // node1: full Wn1, K=192, N=64
        wfrag<192>([&](int k, int j) { return Wn1[k * 64 + j]; }, Wf1n, i);
        return;
    }
    i -= 12288;
    if (i < 16384) {   // nodeH: Wn2 bottom, K=128, N=128
        wfrag<128>([&](int k, int j) { return Wn2[(64 + k) * 128 + j]; }, Wf2n, i);
        return;
    }
    i -= 16384;
    if (i < NF) { cntF[i] = 0; return; }
    i -= NF;
    if (i < NC) { cntC[i] = 0; return; }
    i -= NC;
    if (i < NCELL) { cntG[i] = 0; return; }
    i -= NCELL;
    if (i < 256) { stats[i] = 0.0f; return; }
}

// ---------------------------------------------------------------------------
// merged histogram / scan / scatter for {fine edges, coarse edges, grid cells}
// ---------------------------------------------------------------------------
__global__ __launch_bounds__(256) void hist3_kernel(
    const int* __restrict__ ei_f, const int* __restrict__ ei_c,
    const float* __restrict__ pos_c,
    int* __restrict__ cntF, int* __restrict__ cntC, int* __restrict__ cntG) {
    int i = blockIdx.x * 256 + threadIdx.x;
    if (i < EF) { atomicAdd(&cntF[ei_f[EF + i]], 1); return; }
    i -= EF;
    if (i < EC) { atomicAdd(&cntC[ei_c[EC + i]], 1); return; }
    i -= EC;
    if (i < NC) {
        float2 p = ((const float2*)pos_c)[i];
        atomicAdd(&cntG[cell_of(p)], 1);
    }
}

__global__ __launch_bounds__(1024) void scan3_kernel(
    int* __restrict__ cntF, int* __restrict__ baseF, int* __restrict__ cursF,
    int* __restrict__ cntC, int* __restrict__ baseC, int* __restrict__ cursC,
    int* __restrict__ cntG, int* __restrict__ baseG, int* __restrict__ cursG) {
    const int* cnt; int* base; int* curs; int n;
    if (blockIdx.x == 0)      { cnt = cntF; base = baseF; curs = cursF; n = NF; }
    else if (blockIdx.x == 1) { cnt = cntC; base = baseC; curs = cursC; n = NC; }
    else                      { cnt = cntG; base = baseG; curs = cursG; n = NCELL; }
    const int IT = n >> 10;
    __shared__ int part[1024];
    const int t = threadIdx.x;
    int loc[16];
    int s = 0;
#pragma unroll
    for (int i = 0; i < 16; ++i) {
        int v = (i < IT) ? cnt[t * IT + i] : 0;
        loc[i] = v; s += v;
    }
    part[t] = s;
    __syncthreads();
    for (int off = 1; off < 1024; off <<= 1) {
        int v = part[t];
        int u = (t >= off) ? part[t - off] : 0;
        __syncthreads();
        part[t] = v + u;
        __syncthreads();
    }
    int ex = (t == 0) ? 0 : part[t - 1];
#pragma unroll
    for (int i = 0; i < 16; ++i) {
        if (i < IT) {
            base[t * IT + i] = ex;
            curs[t * IT + i] = ex;
            ex += loc[i];
        }
    }
    if (t == 1023) base[n] = ex;
}

__global__ __launch_bounds__(256) void scatter3_kernel(
    const int* __restrict__ ei_f, const int* __restrict__ ei_c,
    const float* __restrict__ pos_c,
    int* __restrict__ cursF, int* __restrict__ srtF,
    int* __restrict__ cursC, int* __restrict__ srtC,
    int* __restrict__ cursG, float4* __restrict__ grecs) {
    int i = blockIdx.x * 256 + threadIdx.x;
    if (i < EF) {
        int pos = atomicAdd(&cursF[ei_f[EF + i]], 1);
        srtF[pos] = ei_f[i];
        return;
    }
    i -= EF;
    if (i < EC) {
        int pos = atomicAdd(&cursC[ei_c[EC + i]], 1);
        srtC[pos] = ei_c[i];
        return;
    }
    i -= EC;
    if (i < NC) {
        float2 p = ((const float2*)pos_c)[i];
        int pos = atomicAdd(&cursG[cell_of(p)], 1);
        float4 rec;
        rec.x = p.x; rec.y = p.y; rec.z = __int_as_float(i); rec.w = 0.0f;
        grecs[pos] = rec;
    }
}

// ---------------------------------------------------------------------------
// Fused: blocks 0..255 = RA GEMM (4096x512x128 bf16 MFMA);
// blocks 256..511 = grid-kNN, 4 lanes per fine point.
// ---------------------------------------------------------------------------
__global__ __launch_bounds__(256) void gemmA_knn_kernel(
    const ushort_t* __restrict__ xb, const ushort_t* __restrict__ WfA,
    float* __restrict__ RA,
    const float* __restrict__ pos_f, const float4* __restrict__ grecs,
    const int* __restrict__ baseG,
    int* __restrict__ knn_idx, float* __restrict__ knn_w) {
    const int bid = blockIdx.x;
    const int tid = threadIdx.x;
    if (bid < 256) {
        const int wid = tid >> 6, lane = tid & 63;
        const int bx = bid >> 2, by = bid & 3;
        const int row_base = bx * 64 + wid * 16;
        const int row_a = row_base + (lane & 15);
        const int klane = (lane >> 4) << 3;
        short8v a[4];
#pragma unroll
        for (int f = 0; f < 4; ++f)
            a[f] = *(const short8v*)(xb + (size_t)row_a * 128 + f * 32 + klane);
#pragma unroll
        for (int nt = 0; nt < 8; ++nt) {
            const int ntg = by * 8 + nt;
            f32x4 acc = {0.0f, 0.0f, 0.0f, 0.0f};
#pragma unroll
            for (int f = 0; f < 4; ++f) {
                const short8v b =
                    *(const short8v*)(WfA + (size_t)(ntg * 4 + f) * 512 + lane * 8);
                acc = __builtin_amdgcn_mfma_f32_16x16x32_bf16(a[f], b, acc, 0, 0, 0);
            }
            const int col = ntg * 16 + (lane & 15);
            const int r0 = row_base + ((lane >> 4) << 2);
#pragma unroll
            for (int r = 0; r < 4; ++r)
                RA[(size_t)(r0 + r) * 512 + col] = acc[r];
        }
    } else {
        const int g4 = (bid - 256) * 256 + tid;    // 65536 = 4 * NF
        const int t = g4 >> 2;
        const int sub = g4 & 3;
        const float2 p = ((const float2*)pos_f)[t];
        int cx = (int)(p.x * (float)G); cx = cx > G - 1 ? G - 1 : cx;
        int cy = (int)(p.y * (float)G); cy = cy > G - 1 ? G - 1 : cy;
        const float h = 1.0f / (float)G;

        u64 b0 = ~0ull, b1 = ~0ull, b2 = ~0ull;

        // --- ring <= 1 (3x3 cells, clipped), candidates strided over 4 lanes
        {
            const int xx0 = cx - 1 < 0 ? 0 : cx - 1;
            const int xx1 = cx + 1 > G - 1 ? G - 1 : cx + 1;
            const int yy0 = cy - 1 < 0 ? 0 : cy - 1;
            const int yy1 = cy + 1 > G - 1 ? G - 1 : cy + 1;
            int rs[3], rl[3];
            int nr = 0;
            for (int yy = yy0; yy <= yy1; ++yy) {
                const int s = baseG[yy * G + xx0];
                const int e = baseG[yy * G + xx1 + 1];
                rs[nr] = s; rl[nr] = e - s; ++nr;
            }
            const int l0 = rl[0];
            const int l01 = l0 + (nr > 1 ? rl[1] : 0);
            const int m = l01 + (nr > 2 ? rl[2] : 0);
            for (int j = sub; j < m; j += 4) {
                int i;
                if (j < l0) i = rs[0] + j;
                else if (j < l01) i = rs[1] + (j - l0);
                else i = rs[2] + (j - l01);
                const float4 q = grecs[i];
                const float dx = p.x - q.x;
                const float dy = p.y - q.y;
                const float d = dx * dx + dy * dy;
                ins3(b0, b1, b2, ((u64)__float_as_uint(d) << 32) |
                                 (u64)__float_as_uint(q.z));
            }
            // tree-merge disjoint per-lane triples across the 4-lane group
#pragma unroll
            for (int mk = 1; mk <= 2; mk <<= 1) {
                const u64 e0 = __shfl_xor(b0, mk);
                const u64 e1 = __shfl_xor(b1, mk);
                const u64 e2 = __shfl_xor(b2, mk);
                ins3(b0, b1, b2, e0);
                ins3(b0, b1, b2, e1);
                ins3(b0, b1, b2, e2);
            }
        }

        // --- rare wider rings (cooperative; fresh triple per ring)
        for (int r = 2; r < G; ++r) {
            const float bd = __uint_as_float((unsigned)(b2 >> 32));
            const float lim = (float)(r - 1) * h;
            if (bd < lim * lim) break;     // NaN-safe: continues while unfilled
            u64 c0 = ~0ull, c1 = ~0ull, c2 = ~0ull;
            auto scan_cells = [&](int cell0, int cell1, int step) {
                for (int c = cell0; c <= cell1; c += step) {
                    const int s0 = baseG[c], s1 = baseG[c + 1];
                    for (int i = s0; i < s1; ++i) {
                        const float4 q = grecs[i];
                        const float dx = p.x - q.x;
                        const float dy = p.y - q.y;
                        const float d = dx * dx + dy * dy;
                        ins3(c0, c1, c2, ((u64)__float_as_uint(d) << 32) |
                                         (u64)__float_as_uint(q.z));
                    }
                }
            };
            const int x0 = cx - r < 0 ? 0 : cx - r;
            const int x1 = cx + r > G - 1 ? G - 1 : cx + r;
            const int yi0 = cy - r + 1 < 0 ? 0 : cy - r + 1;
            const int yi1 = cy + r - 1 > G - 1 ? G - 1 : cy + r - 1;
            if (sub == 0) { if (cy - r >= 0)     scan_cells((cy - r) * G + x0, (cy - r) * G + x1, 1); }
            else if (sub == 1) { if (cy + r <= G - 1) scan_cells((cy + r) * G + x0, (cy + r) * G + x1, 1); }
            else if (sub == 2) { if (cx - r >= 0 && yi0 <= yi1) scan_cells(yi0 * G + cx - r, yi1 * G + cx - r, G); }
            else               { if (cx + r <= G - 1 && yi0 <= yi1) scan_cells(yi0 * G + cx + r, yi1 * G + cx + r, G); }
#pragma unroll
            for (int mk = 1; mk <= 2; mk <<= 1) {
                const u64 e0 = __shfl_xor(c0, mk);
                const u64 e1 = __shfl_xor(c1, mk);
                const u64 e2 = __shfl_xor(c2, mk);
                ins3(c0, c1, c2, e0);
                ins3(c0, c1, c2, e1);
                ins3(c0, c1, c2, e2);
            }
            // insert ring candidates into shared triple (distinct idx -> safe)
            ins3(b0, b1, b2, c0);
            ins3(b0, b1, b2, c1);
            ins3(b0, b1, b2, c2);
        }

        if (sub == 0) {
            const float d0 = __uint_as_float((unsigned)(b0 >> 32));
            const float d1 = __uint_as_float((unsigned)(b1 >> 32));
            const float d2 = __uint_as_float((unsigned)(b2 >> 32));
            const float w0 = 1.0f / fmaxf(d0, 1e-16f);
            const float w1 = 1.0f / fmaxf(d1, 1e-16f);
            const float w2 = 1.0f / fmaxf(d2, 1e-16f);
            const float s = 1.0f / (w0 + w1 + w2);
            knn_idx[t * 3 + 0] = __float_as_int(__uint_as_float((unsigned)(b0 & 0xffffffffu)));
            knn_idx[t * 3 + 1] = __float_as_int(__uint_as_float((unsigned)(b1 & 0xffffffffu)));
            knn_idx[t * 3 + 2] = __float_as_int(__uint_as_float((unsigned)(b2 & 0xffffffffu)));
            knn_w[t * 3 + 0] = w0 * s;
            knn_w[t * 3 + 1] = w1 * s;
            knn_w[t * 3 + 2] = w2 * s;
        }
    }
}

// ---------------------------------------------------------------------------
// interp of coarse result rows: cols 0..255 -> PQf (bf16), 256..383 -> Uf (bf16)
// thread per (t, 4-ch group); 96 groups per fine node.
// ---------------------------------------------------------------------------
template <int STRIDE>
__global__ __launch_bounds__(256) void interp_kernel(
    const float* __restrict__ R, const int* __restrict__ knn_idx,
    const float* __restrict__ knn_w, ushort_t* __restrict__ PQf,
    ushort_t* __restrict__ Uf) {
    const int tid = blockIdx.x * 256 + threadIdx.x;
    const int t = tid / 96;
    const int g = tid - t * 96;
    const int i0 = knn_idx[t * 3 + 0], i1 = knn_idx[t * 3 + 1], i2 = knn_idx[t * 3 + 2];
    const float w0 = knn_w[t * 3 + 0], w1 = knn_w[t * 3 + 1], w2 = knn_w[t * 3 + 2];
    const float4 a = *(const float4*)(R + (size_t)i0 * STRIDE + g * 4);
    const float4 b = *(const float4*)(R + (size_t)i1 * STRIDE + g * 4);
    const float4 c = *(const float4*)(R + (size_t)i2 * STRIDE + g * 4);
    ushort4 o;
    o.x = f2bf(w0 * a.x + w1 * b.x + w2 * c.x);
    o.y = f2bf(w0 * a.y + w1 * b.y + w2 * c.y);
    o.z = f2bf(w0 * a.z + w1 * b.z + w2 * c.z);
    o.w = f2bf(w0 * a.w + w1 * b.w + w2 * c.w);
    if (g < 64) *(ushort4*)(PQf + (size_t)t * 256 + g * 4) = o;
    else        *(ushort4*)(Uf + (size_t)t * 128 + (g - 64) * 4) = o;
}

// ---------------------------------------------------------------------------
// agg: fine part (bf16 PQf, 128 ch, 2 ch/lane) and optional coarse part
// (fp32 RA cols 384..511, 64 ch). One wave per dst node.
// ---------------------------------------------------------------------------
template <bool DUAL>
__global__ __launch_bounds__(256) void agg_kernel(
    const ushort_t* __restrict__ PQf, const int* __restrict__ baseF,
    const int* __restrict__ srtF, const float* __restrict__ beF,
    ushort_t* __restrict__ aggF,
    const float* __restrict__ RA, const int* __restrict__ baseC,
    const int* __restrict__ srtC, const float* __restrict__ beC,
    ushort_t* __restrict__ aggC) {
    const int bid = blockIdx.x;
    const int wid = threadIdx.x >> 6, lane = threadIdx.x & 63;
    if (!DUAL || bid < NF / 4) {
        const int n = bid * 4 + wid;
        const int b0 = baseF[n], b1 = baseF[n + 1];
        const ushort2 qv = *(const ushort2*)(PQf + (size_t)n * 256 + 128 + lane * 2);
        const float2 bv = *(const float2*)(beF + lane * 2);
        const float qx = bf2f(qv.x) + bv.x, qy = bf2f(qv.y) + bv.y;
        float ax = 0.0f, ay = 0.0f;
        for (int e = b0; e < b1; ++e) {
            const int src = srtF[e];
            const ushort2 pv = *(const ushort2*)(PQf + (size_t)src * 256 + lane * 2);
            ax += selu_f(bf2f(pv.x) + qx);
            ay += selu_f(bf2f(pv.y) + qy);
        }
        ushort2 r; r.x = f2bf(ax); r.y = f2bf(ay);
        *(ushort2*)(aggF + (size_t)n * 128 + lane * 2) = r;
    } else {
        const int n = (bid - NF / 4) * 4 + wid;
        const int b0 = baseC[n], b1 = baseC[n + 1];
        const float q = RA[(size_t)n * 512 + 448 + lane] + beC[lane];
        float s = 0.0f;
        for (int e = b0; e < b1; ++e) {
            const int src = srtC[e];
            s += selu_f(RA[(size_t)src * 512 + 384 + lane] + q);
        }
        aggC[(size_t)n * 64 + lane] = f2bf(s);
    }
}

// ---------------------------------------------------------------------------
// nodeS (blocks 0..255): x_skip = selu(aggF@WnS_bot + UfS + bnS) -> outp f32
// node1 (blocks 256..319): h1 = selu(concat(xb,agg1b)@Wn1 + bn1) -> h1b bf16
// ---------------------------------------------------------------------------
__global__ __launch_bounds__(256) void nodeSD_kernel(
    const ushort_t* __restrict__ aggF, const ushort_t* __restrict__ WfSn,
    const float* __restrict__ bnS, const ushort_t* __restrict__ UfS,
    float* __restrict__ outp,
    const ushort_t* __restrict__ xb, const ushort_t* __restrict__ agg1b,
    const ushort_t* __restrict__ Wf1n, const float* __restrict__ bn1,
    ushort_t* __restrict__ h1b) {
    const int tid = threadIdx.x;
    const int wid = tid >> 6, lane = tid & 63;
    const int klane = (lane >> 4) << 3;
    if (blockIdx.x < 256) {
        const int row_base = blockIdx.x * 64 + wid * 16;
        const int row_a = row_base + (lane & 15);
        short8v a[4];
#pragma unroll
        for (int f = 0; f < 4; ++f)
            a[f] = *(const short8v*)(aggF + (size_t)row_a * 128 + f * 32 + klane);
#pragma unroll
        for (int nt = 0; nt < 8; ++nt) {
            f32x4 acc = {0.0f, 0.0f, 0.0f, 0.0f};
#pragma unroll
            for (int f = 0; f < 4; ++f) {
                const short8v b =
                    *(const short8v*)(WfSn + (size_t)(nt * 4 + f) * 512 + lane * 8);
                acc = __builtin_amdgcn_mfma_f32_16x16x32_bf16(a[f], b, acc, 0, 0, 0);
            }
            const int col = nt * 16 + (lane & 15);
            const int r0 = row_base + ((lane >> 4) << 2);
#pragma unroll
            for (int r = 0; r < 4; ++r) {
                const size_t o = (size_t)(r0 + r) * 128 + col;
                outp[o] = selu_f(acc[r] + bnS[col] + bf2f(UfS[o]));
            }
        }
    } else {
        const int row_base = (blockIdx.x - 256) * 64 + wid * 16;
        const int row_a = row_base + (lane & 15);
        short8v a[6];
#pragma unroll
        for (int f = 0; f < 4; ++f)
            a[f] = *(const short8v*)(xb + (size_t)row_a * 128 + f * 32 + klane);
#pragma unroll
        for (int f = 0; f < 2; ++f)
            a[4 + f] = *(const short8v*)(agg1b + (size_t)row_a * 64 + f * 32 + klane);
#pragma unroll
        for (int nt = 0; nt < 4; ++nt) {
            f32x4 acc = {0.0f, 0.0f, 0.0f, 0.0f};
#pragma unroll
            for (int f = 0; f < 6; ++f) {
                const short8v b =
                    *(const short8v*)(Wf1n + (size_t)(nt * 6 + f) * 512 + lane * 8);
                acc = __builtin_amdgcn_mfma_f32_16x16x32_bf16(a[f], b, acc, 0, 0, 0);
            }
            const int col = nt * 16 + (lane & 15);
            const int r0 = row_base + ((lane >> 4) << 2);
#pragma unroll
            for (int r = 0; r < 4; ++r)
                h1b[(size_t)(r0 + r) * 64 + col] = f2bf(selu_f(acc[r] + bn1[col]));
        }
    }
}

// ---------------------------------------------------------------------------
// RE GEMM: h1b(4096x64) @ WfE -> RE (4096x384 f32). 256 blocks.
// ---------------------------------------------------------------------------
__global__ __launch_bounds__(256) void gemmE_kernel(
    const ushort_t* __restrict__ h1b, const ushort_t* __restrict__ WfE,
    float* __restrict__ RE) {
    const int tid = threadIdx.x;
    const int wid = tid >> 6, lane = tid & 63;
    const int bx = blockIdx.x >> 2, by = blockIdx.x & 3;
    const int row_base = bx * 64 + wid * 16;
    const int row_a = row_base + (lane & 15);
    const int klane = (lane >> 4) << 3;
    short8v a[2];
#pragma unroll
    for (int f = 0; f < 2; ++f)
        a[f] = *(const short8v*)(h1b + (size_t)row_a * 64 + f * 32 + klane);
#pragma unroll
    for (int nt = 0; nt < 6; ++nt) {
        const int ntg = by * 6 + nt;
        f32x4 acc = {0.0f, 0.0f, 0.0f, 0.0f};
#pragma unroll
        for (int f = 0; f < 2; ++f) {
            const short8v b =
                *(const short8v*)(WfE + (size_t)(ntg * 2 + f) * 512 + lane * 8);
            acc = __builtin_amdgcn_mfma_f32_16x16x32_bf16(a[f], b, acc, 0, 0, 0);
        }
        const int col = ntg * 16 + (lane & 15);
        const int r0 = row_base + ((lane >> 4) << 2);
#pragma unroll
        for (int r = 0; r < 4; ++r)
            RE[(size_t)(r0 + r) * 384 + col] = acc[r];
    }
}

// ---------------------------------------------------------------------------
// nodeH: v = selu(aggF@Wn2_bot + Uf2 + bn2) + x_skip; write outp; BN stats.
// ---------------------------------------------------------------------------
__global__ __launch_bounds__(256) void nodeH_kernel(
    const ushort_t* __restrict__ aggF, const ushort_t* __restrict__ Wf2n,
    const float* __restrict__ bn2, const ushort_t* __restrict__ Uf2,
    float* __restrict__ outp, float* __restrict__ stats) {
    __shared__ float s_sum[128], s_sq[128];
    const int tid = threadIdx.x;
    const int wid = tid >> 6, lane = tid & 63;
    const int klane = (lane >> 4) << 3;
    if (tid < 128) { s_sum[tid] = 0.0f; s_sq[tid] = 0.0f; }
    __syncthreads();
    const int row_base = blockIdx.x * 64 + wid * 16;
    const int row_a = row_base + (lane & 15);
    short8v a[4];
#pragma unroll
    for (int f = 0; f < 4; ++f)
        a[f] = *(const short8v*)(aggF + (size_t)row_a * 128 + f * 32 + klane);
#pragma unroll
    for (int nt = 0; nt < 8; ++nt) {
        f32x4 acc = {0.0f, 0.0f, 0.0f, 0.0f};
#pragma unroll
        for (int f = 0; f < 4; ++f) {
            const short8v b =
                *(const short8v*)(Wf2n + (size_t)(nt * 4 + f) * 512 + lane * 8);
            acc = __builtin_amdgcn_mfma_f32_16x16x32_bf16(a[f], b, acc, 0, 0, 0);
        }
        const int col = nt * 16 + (lane & 15);
        const int r0 = row_base + ((lane >> 4) << 2);
        float lsum = 0.0f, lsq = 0.0f;
#pragma unroll
        for (int r = 0; r < 4; ++r) {
            const size_t o = (size_t)(r0 + r) * 128 + col;
            float v = selu_f(acc[r] + bn2[col] + bf2f(Uf2[o])) + outp[o];
            outp[o] = v;
            lsum += v; lsq += v * v;
        }
        atomicAdd(&s_sum[nt * 16 + (lane & 15)], lsum);
        atomicAdd(&s_sq[nt * 16 + (lane & 15)], lsq);
    }
    __syncthreads();
    if (tid < 128) {
        atomicAdd(&stats[tid], s_sum[tid]);
        atomicAdd(&stats[128 + tid], s_sq[tid]);
    }
}

// ---------------------------------------------------------------------------
// BN normalize + SELU, in place on d_out.
// ---------------------------------------------------------------------------
__global__ __launch_bounds__(256) void bn_kernel(
    float* __restrict__ out, const float* __restrict__ stats,
    const float* __restrict__ gamma, const float* __restrict__ beta, int Nn) {
    const int i = blockIdx.x * blockDim.x + threadIdx.x;
    const int c = i & 127;
    const float invn = 1.0f / (float)Nn;
    float mu = stats[c] * invn;
    float var = stats[128 + c] * invn - mu * mu;
    float r = rsqrtf(var + 1e-5f);
    float v = (out[i] - mu) * r * gamma[c] + beta[c];
    out[i] = selu_f(v);
}

// ---------------------------------------------------------------------------
extern "C" void kernel_launch(void* const* d_in, const int* in_sizes, int n_in,
                              void* d_out, int out_size, void* d_ws, size_t ws_size,
                              hipStream_t stream) {
    const float* x     = (const float*)d_in[0];
    const float* pos_c = (const float*)d_in[1];
    const float* pos_f = (const float*)d_in[2];
    const int*   ei_c  = (const int*)d_in[3];
    const int*   ei_f  = (const int*)d_in[4];
    const float* We1 = (const float*)d_in[5];
    const float* be1 = (const float*)d_in[6];
    const float* Wn1 = (const float*)d_in[7];
    const float* bn1 = (const float*)d_in[8];
    const float* We2 = (const float*)d_in[9];
    const float* be2 = (const float*)d_in[10];
    const float* Wn2 = (const float*)d_in[11];
    const float* bn2 = (const float*)d_in[12];
    const float* WeS = (const float*)d_in[13];
    const float* beS = (const float*)d_in[14];
    const float* WnS = (const float*)d_in[15];
    const float* bnS = (const float*)d_in[16];
    const float* gamma = (const float*)d_in[17];
    const float* beta  = (const float*)d_in[18];

    char* w = (char*)d_ws;
    size_t o = 0;
    auto alloc = [&](size_t bytes) { void* p = w + o; o += (bytes + 255) & ~(size_t)255; return p; };
    int*      knn_idx = (int*)alloc((size_t)NF * 3 * sizeof(int));
    float*    knn_w   = (float*)alloc((size_t)NF * 3 * sizeof(float));
    float*    RA      = (float*)alloc((size_t)NC * 512 * sizeof(float));  // also RE
    ushort_t* PQf     = (ushort_t*)alloc((size_t)NF * 256 * 2);           // reused
    ushort_t* Uf      = (ushort_t*)alloc((size_t)NF * 128 * 2);           // reused
    ushort_t* aggF    = (ushort_t*)alloc((size_t)NF * 128 * 2);           // reused
    ushort_t* agg1b   = (ushort_t*)alloc((size_t)NC * 64 * 2);
    ushort_t* h1b     = (ushort_t*)alloc((size_t)NC * 64 * 2);
    ushort_t* xb      = (ushort_t*)alloc((size_t)NC * 128 * 2);
    ushort_t* WfA     = (ushort_t*)alloc(65536 * 2);
    ushort_t* WfE     = (ushort_t*)alloc(24576 * 2);
    ushort_t* WfSn    = (ushort_t*)alloc(16384 * 2);
    ushort_t* Wf1n    = (ushort_t*)alloc(12288 * 2);
    ushort_t* Wf2n    = (ushort_t*)alloc(16384 * 2);
    int*   cntF  = (int*)alloc((size_t)NF * sizeof(int));
    int*   baseF = (int*)alloc((size_t)(NF + 1) * sizeof(int));
    int*   cursF = (int*)alloc((size_t)NF * sizeof(int));
    int*   srtF  = (int*)alloc((size_t)EF * sizeof(int));
    int*   cntC  = (int*)alloc((size_t)NC * sizeof(int));
    int*   baseC = (int*)alloc((size_t)(NC + 1) * sizeof(int));
    int*   cursC = (int*)alloc((size_t)NC * sizeof(int));
    int*   srtC  = (int*)alloc((size_t)EC * sizeof(int));
    int*   cntG  = (int*)alloc((size_t)NCELL * sizeof(int));
    int*   baseG = (int*)alloc((size_t)(NCELL + 1) * sizeof(int));
    int*   cursG = (int*)alloc((size_t)NCELL * sizeof(int));
    float4* grecs = (float4*)alloc((size_t)NC * sizeof(float4));
    float* stats = (float*)alloc(256 * sizeof(float));
    float* outp = (float*)d_out;

    // 1. prep (converts + weight frags + zeroing)
    constexpr int PREP_TOTAL = NC * 128 + 65536 + 24576 + 16384 + 12288 + 16384
                             + NF + NC + NCELL + 256;
    prep_kernel<<<(PREP_TOTAL + 255) / 256, 256, 0, stream>>>(
        x, xb, WeS, WnS, We1, We2, Wn2, Wn1,
        WfA, WfE, WfSn, Wf1n, Wf2n, cntF, cntC, cntG, stats);

    // 2-4. merged counting sorts
    constexpr int SORT_ITEMS = EF + EC + NC;
    hist3_kernel<<<(SORT_ITEMS + 255) / 256, 256, 0, stream>>>(
        ei_f, ei_c, pos_c, cntF, cntC, cntG);
    scan3_kernel<<<3, 1024, 0, stream>>>(
        cntF, baseF, cursF, cntC, baseC, cursC, cntG, baseG, cursG);
    scatter3_kernel<<<(SORT_ITEMS + 255) / 256, 256, 0, stream>>>(
        ei_f, ei_c, pos_c, cursF, srtF, cursC, srtC, cursG, grecs);

    // 5. RA GEMM + kNN (fused; knn = 4 lanes/point)
    gemmA_knn_kernel<<<512, 256, 0, stream>>>(
        xb, WfA, RA, pos_f, grecs, baseG, knn_idx, knn_w);

    // 6. interp RA -> PQf(S) + Uf(S)
    interp_kernel<512><<<NF * 96 / 256, 256, 0, stream>>>(RA, knn_idx, knn_w, PQf, Uf);

    // 7. agg: fine skip + coarse mpl1 (fused)
    agg_kernel<true><<<NF / 4 + NC / 4, 256, 0, stream>>>(
        PQf, baseF, srtF, beS, aggF, RA, baseC, srtC, be1, agg1b);

    // 8. nodeS (x_skip -> d_out) + node1 (h1b) (fused)
    nodeSD_kernel<<<320, 256, 0, stream>>>(
        aggF, WfSn, bnS, Uf, outp, xb, agg1b, Wf1n, bn1, h1b);

    // 9. RE GEMM (mpl2 coarse part)
    gemmE_kernel<<<256, 256, 0, stream>>>(h1b, WfE, RA);

    // 10. interp RE -> PQf(2) + Uf(2)
    interp_kernel<384><<<NF * 96 / 256, 256, 0, stream>>>(RA, knn_idx, knn_w, PQf, Uf);

    // 11. agg2 (fine)
    agg_kernel<false><<<NF / 4, 256, 0, stream>>>(
        PQf, baseF, srtF, be2, aggF, nullptr, nullptr, nullptr, nullptr, nullptr);

    // 12. nodeH: final MLP + residual + BN stats
    nodeH_kernel<<<256, 256, 0, stream>>>(aggF, Wf2n, bn2, Uf, outp, stats);

    // 13. BN + SELU
    bn_kernel<<<NF * 128 / 256, 256, 0, stream>>>(outp, stats, gamma, beta, NF);
}

// Round 8
// 227.676 us; speedup vs baseline: 10.2155x; 1.0465x over previous
//
#include <hip/hip_runtime.h>

// ---------------------------------------------------------------------------
// Res_up block, round 8: round 7 +
//  - RA/RE coarse GEMM results stored bf16 (halves interp/agg gather traffic)
//  - gemmE fused into nodeSD (h1 tile stays in LDS; RE computed in-block)
//  - kNN at 8 lanes/point; interp at 8 channels/thread (16B gathers)
// 12 dispatches.
// Sizes fixed: Nc=4096, Nf=16384, Ec=65536, Ef=262144, Cin=128, Ch=64, Co=128.
// ---------------------------------------------------------------------------

#define SELU_SCALE 1.0507009873554805f
#define SELU_ALPHA 1.6732632423543772f

static constexpr int NC = 4096, NF = 16384, EC = 65536, EF = 262144;
static constexpr int G = 32, NCELL = G * G;

typedef __attribute__((ext_vector_type(8))) short short8v;
typedef __attribute__((ext_vector_type(4))) float f32x4;
typedef unsigned short ushort_t;
typedef unsigned long long u64;

__device__ __forceinline__ float selu_f(float x) {
    return x > 0.0f ? SELU_SCALE * x
                    : SELU_SCALE * SELU_ALPHA * (__expf(x) - 1.0f);
}
__device__ __forceinline__ ushort_t f2bf(float f) {
    unsigned u = __float_as_uint(f);
    u += 0x7FFFu + ((u >> 16) & 1u);
    return (ushort_t)(u >> 16);
}
__device__ __forceinline__ float bf2f(ushort_t u) {
    return __uint_as_float(((unsigned)u) << 16);
}
__device__ __forceinline__ int cell_of(float2 p) {
    int cx = (int)(p.x * (float)G); cx = cx > G - 1 ? G - 1 : cx;
    int cy = (int)(p.y * (float)G); cy = cy > G - 1 ? G - 1 : cy;
    return cy * G + cx;
}
// insert v into sorted triple (a0<=a1<=a2); strict < keeps stable tie order
__device__ __forceinline__ void ins3(u64& a0, u64& a1, u64& a2, u64 v) {
    if (v < a2) {
        if (v < a1) {
            a2 = a1;
            if (v < a0) { a1 = a0; a0 = v; } else a1 = v;
        } else a2 = v;
    }
}

// ---------------------------------------------------------------------------
// Fragment-major weight writer: Wf[(ntile*KC+kc)*512 + lane*8 + e] = W[k][col]
// ---------------------------------------------------------------------------
template <int K, typename F>
__device__ __forceinline__ void wfrag(F getw, ushort_t* __restrict__ dst, int idx) {
    constexpr int KC = K / 32;
    const int f = idx >> 9;
    const int r = idx & 511;
    const int lane = r >> 3;
    const int e = r & 7;
    const int ntile = f / KC;
    const int kc = f - ntile * KC;
    const int k = kc * 32 + ((lane >> 4) << 3) + e;
    const int col = ntile * 16 + (lane & 15);
    dst[idx] = f2bf(getw(k, col));
}

// ---------------------------------------------------------------------------
// prep: x->bf16, 5 weight-frag buffers, zero cnt/stats.
// ---------------------------------------------------------------------------
__global__ __launch_bounds__(256) void prep_kernel(
    const float* __restrict__ x, ushort_t* __restrict__ xb,
    const float* __restrict__ WeS, const float* __restrict__ WnS,
    const float* __restrict__ We1, const float* __restrict__ We2,
    const float* __restrict__ Wn2, const float* __restrict__ Wn1,
    ushort_t* __restrict__ WfA, ushort_t* __restrict__ WfE,
    ushort_t* __restrict__ WfSn, ushort_t* __restrict__ Wf1n,
    ushort_t* __restrict__ Wf2n,
    int* __restrict__ cntF, int* __restrict__ cntC, int* __restrict__ cntG,
    float* __restrict__ stats) {
    int i = blockIdx.x * 256 + threadIdx.x;
    if (i < NC * 128) { xb[i] = f2bf(x[i]); return; }
    i -= NC * 128;
    if (i < 65536) {   // RA weights: K=128, N=512
        wfrag<128>([&](int k, int j) {
            return j < 128 ? WeS[k * 128 + j]
                 : j < 256 ? WeS[(128 + k) * 128 + (j - 128)]
                 : j < 384 ? WnS[k * 128 + (j - 256)]
                 : j < 448 ? We1[k * 64 + (j - 384)]
                           : We1[(128 + k) * 64 + (j - 448)];
        }, WfA, i);
        return;
    }
    i -= 65536;
    if (i < 24576) {   // RE weights: K=64, N=384
        wfrag<64>([&](int k, int j) {
            return j < 128 ? We2[k * 128 + j]
                 : j < 256 ? We2[(64 + k) * 128 + (j - 128)]
                           : Wn2[k * 128 + (j - 256)];
        }, WfE, i);
        return;
    }
    i -= 24576;
    if (i < 16384) {   // nodeS: WnS bottom half, K=128, N=128
        wfrag<128>([&](int k, int j) { return WnS[(128 + k) * 128 + j]; }, WfSn, i);
        return;
    }
    i -= 16384;
    if (i < 12288) {   // node1: full Wn1, K=192, N=64
        wfrag<192>([&](int k, int j) { return Wn1[k * 64 + j]; }, Wf1n, i);
        return;
    }
    i -= 12288;
    if (i < 16384) {   // nodeH: Wn2 bottom, K=128, N=128
        wfrag<128>([&](int k, int j) { return Wn2[(64 + k) * 128 + j]; }, Wf2n, i);
        return;
    }
    i -= 16384;
    if (i < NF) { cntF[i] = 0; return; }
    i -= NF;
    if (i < NC) { cntC[i] = 0; return; }
    i -= NC;
    if (i < NCELL) { cntG[i] = 0; return; }
    i -= NCELL;
    if (i < 256) { stats[i] = 0.0f; return; }
}

// ---------------------------------------------------------------------------
// merged histogram / scan / scatter for {fine edges, coarse edges, grid cells}
// ---------------------------------------------------------------------------
__global__ __launch_bounds__(256) void hist3_kernel(
    const int* __restrict__ ei_f, const int* __restrict__ ei_c,
    const float* __restrict__ pos_c,
    int* __restrict__ cntF, int* __restrict__ cntC, int* __restrict__ cntG) {
    int i = blockIdx.x * 256 + threadIdx.x;
    if (i < EF) { atomicAdd(&cntF[ei_f[EF + i]], 1); return; }
    i -= EF;
    if (i < EC) { atomicAdd(&cntC[ei_c[EC + i]], 1); return; }
    i -= EC;
    if (i < NC) {
        float2 p = ((const float2*)pos_c)[i];
        atomicAdd(&cntG[cell_of(p)], 1);
    }
}

__global__ __launch_bounds__(1024) void scan3_kernel(
    int* __restrict__ cntF, int* __restrict__ baseF, int* __restrict__ cursF,
    int* __restrict__ cntC, int* __restrict__ baseC, int* __restrict__ cursC,
    int* __restrict__ cntG, int* __restrict__ baseG, int* __restrict__ cursG) {
    const int* cnt; int* base; int* curs; int n;
    if (blockIdx.x == 0)      { cnt = cntF; base = baseF; curs = cursF; n = NF; }
    else if (blockIdx.x == 1) { cnt = cntC; base = baseC; curs = cursC; n = NC; }
    else                      { cnt = cntG; base = baseG; curs = cursG; n = NCELL; }
    const int IT = n >> 10;
    __shared__ int part[1024];
    const int t = threadIdx.x;
    int loc[16];
    int s = 0;
#pragma unroll
    for (int i = 0; i < 16; ++i) {
        int v = (i < IT) ? cnt[t * IT + i] : 0;
        loc[i] = v; s += v;
    }
    part[t] = s;
    __syncthreads();
    for (int off = 1; off < 1024; off <<= 1) {
        int v = part[t];
        int u = (t >= off) ? part[t - off] : 0;
        __syncthreads();
        part[t] = v + u;
        __syncthreads();
    }
    int ex = (t == 0) ? 0 : part[t - 1];
#pragma unroll
    for (int i = 0; i < 16; ++i) {
        if (i < IT) {
            base[t * IT + i] = ex;
            curs[t * IT + i] = ex;
            ex += loc[i];
        }
    }
    if (t == 1023) base[n] = ex;
}

__global__ __launch_bounds__(256) void scatter3_kernel(
    const int* __restrict__ ei_f, const int* __restrict__ ei_c,
    const float* __restrict__ pos_c,
    int* __restrict__ cursF, int* __restrict__ srtF,
    int* __restrict__ cursC, int* __restrict__ srtC,
    int* __restrict__ cursG, float4* __restrict__ grecs) {
    int i = blockIdx.x * 256 + threadIdx.x;
    if (i < EF) {
        int pos = atomicAdd(&cursF[ei_f[EF + i]], 1);
        srtF[pos] = ei_f[i];
        return;
    }
    i -= EF;
    if (i < EC) {
        int pos = atomicAdd(&cursC[ei_c[EC + i]], 1);
        srtC[pos] = ei_c[i];
        return;
    }
    i -= EC;
    if (i < NC) {
        float2 p = ((const float2*)pos_c)[i];
        int pos = atomicAdd(&cursG[cell_of(p)], 1);
        float4 rec;
        rec.x = p.x; rec.y = p.y; rec.z = __int_as_float(i); rec.w = 0.0f;
        grecs[pos] = rec;
    }
}

// ---------------------------------------------------------------------------
// Fused: blocks 0..255 = RA GEMM (4096x512x128, bf16 out);
// blocks 256..767 = grid-kNN, 8 lanes per fine point.
// ---------------------------------------------------------------------------
__global__ __launch_bounds__(256) void gemmA_knn_kernel(
    const ushort_t* __restrict__ xb, const ushort_t* __restrict__ WfA,
    ushort_t* __restrict__ RA,
    const float* __restrict__ pos_f, const float4* __restrict__ grecs,
    const int* __restrict__ baseG,
    int* __restrict__ knn_idx, float* __restrict__ knn_w) {
    const int bid = blockIdx.x;
    const int tid = threadIdx.x;
    if (bid < 256) {
        const int wid = tid >> 6, lane = tid & 63;
        const int bx = bid >> 2, by = bid & 3;
        const int row_base = bx * 64 + wid * 16;
        const int row_a = row_base + (lane & 15);
        const int klane = (lane >> 4) << 3;
        short8v a[4];
#pragma unroll
        for (int f = 0; f < 4; ++f)
            a[f] = *(const short8v*)(xb + (size_t)row_a * 128 + f * 32 + klane);
#pragma unroll
        for (int nt = 0; nt < 8; ++nt) {
            const int ntg = by * 8 + nt;
            f32x4 acc = {0.0f, 0.0f, 0.0f, 0.0f};
#pragma unroll
            for (int f = 0; f < 4; ++f) {
                const short8v b =
                    *(const short8v*)(WfA + (size_t)(ntg * 4 + f) * 512 + lane * 8);
                acc = __builtin_amdgcn_mfma_f32_16x16x32_bf16(a[f], b, acc, 0, 0, 0);
            }
            const int col = ntg * 16 + (lane & 15);
            const int r0 = row_base + ((lane >> 4) << 2);
#pragma unroll
            for (int r = 0; r < 4; ++r)
                RA[(size_t)(r0 + r) * 512 + col] = f2bf(acc[r]);
        }
    } else {
        const int g8 = (bid - 256) * 256 + tid;    // 131072 = 8 * NF
        const int t = g8 >> 3;
        const int sub = g8 & 7;
        const float2 p = ((const float2*)pos_f)[t];
        int cx = (int)(p.x * (float)G); cx = cx > G - 1 ? G - 1 : cx;
        int cy = (int)(p.y * (float)G); cy = cy > G - 1 ? G - 1 : cy;
        const float h = 1.0f / (float)G;

        u64 b0 = ~0ull, b1 = ~0ull, b2 = ~0ull;

        // --- ring <= 1 (3x3 cells, clipped), candidates strided over 8 lanes
        {
            const int xx0 = cx - 1 < 0 ? 0 : cx - 1;
            const int xx1 = cx + 1 > G - 1 ? G - 1 : cx + 1;
            const int yy0 = cy - 1 < 0 ? 0 : cy - 1;
            const int yy1 = cy + 1 > G - 1 ? G - 1 : cy + 1;
            int rs[3], rl[3];
            int nr = 0;
            for (int yy = yy0; yy <= yy1; ++yy) {
                const int s = baseG[yy * G + xx0];
                const int e = baseG[yy * G + xx1 + 1];
                rs[nr] = s; rl[nr] = e - s; ++nr;
            }
            const int l0 = rl[0];
            const int l01 = l0 + (nr > 1 ? rl[1] : 0);
            const int m = l01 + (nr > 2 ? rl[2] : 0);
            for (int j = sub; j < m; j += 8) {
                int i;
                if (j < l0) i = rs[0] + j;
                else if (j < l01) i = rs[1] + (j - l0);
                else i = rs[2] + (j - l01);
                const float4 q = grecs[i];
                const float dx = p.x - q.x;
                const float dy = p.y - q.y;
                const float d = dx * dx + dy * dy;
                ins3(b0, b1, b2, ((u64)__float_as_uint(d) << 32) |
                                 (u64)__float_as_uint(q.z));
            }
            // tree-merge disjoint per-lane triples across the 8-lane group
#pragma unroll
            for (int mk = 1; mk <= 4; mk <<= 1) {
                const u64 e0 = __shfl_xor(b0, mk);
                const u64 e1 = __shfl_xor(b1, mk);
                const u64 e2 = __shfl_xor(b2, mk);
                ins3(b0, b1, b2, e0);
                ins3(b0, b1, b2, e1);
                ins3(b0, b1, b2, e2);
            }
        }

        // --- rare wider rings (cooperative; fresh triple per ring)
        for (int r = 2; r < G; ++r) {
            const float bd = __uint_as_float((unsigned)(b2 >> 32));
            const float lim = (float)(r - 1) * h;
            if (bd < lim * lim) break;     // NaN-safe: continues while unfilled
            u64 c0 = ~0ull, c1 = ~0ull, c2 = ~0ull;
            auto scan_cells = [&](int cell0, int cell1, int step) {
                for (int c = cell0; c <= cell1; c += step) {
                    const int s0 = baseG[c], s1 = baseG[c + 1];
                    for (int i = s0; i < s1; ++i) {
                        const float4 q = grecs[i];
                        const float dx = p.x - q.x;
                        const float dy = p.y - q.y;
                        const float d = dx * dx + dy * dy;
                        ins3(c0, c1, c2, ((u64)__float_as_uint(d) << 32) |
                                         (u64)__float_as_uint(q.z));
                    }
                }
            };
            const int side = sub & 3, phase = sub >> 2;
            const int x0 = cx - r < 0 ? 0 : cx - r;
            const int x1 = cx + r > G - 1 ? G - 1 : cx + r;
            const int yi0 = cy - r + 1 < 0 ? 0 : cy - r + 1;
            const int yi1 = cy + r - 1 > G - 1 ? G - 1 : cy + r - 1;
            if (side == 0) {
                if (cy - r >= 0) scan_cells((cy - r) * G + x0 + phase, (cy - r) * G + x1, 2);
            } else if (side == 1) {
                if (cy + r <= G - 1) scan_cells((cy + r) * G + x0 + phase, (cy + r) * G + x1, 2);
            } else if (side == 2) {
                if (cx - r >= 0 && yi0 + phase <= yi1)
                    scan_cells((yi0 + phase) * G + cx - r, yi1 * G + cx - r, 2 * G);
            } else {
                if (cx + r <= G - 1 && yi0 + phase <= yi1)
                    scan_cells((yi0 + phase) * G + cx + r, yi1 * G + cx + r, 2 * G);
            }
#pragma unroll
            for (int mk = 1; mk <= 4; mk <<= 1) {
                const u64 e0 = __shfl_xor(c0, mk);
                const u64 e1 = __shfl_xor(c1, mk);
                const u64 e2 = __shfl_xor(c2, mk);
                ins3(c0, c1, c2, e0);
                ins3(c0, c1, c2, e1);
                ins3(c0, c1, c2, e2);
            }
            ins3(b0, b1, b2, c0);
            ins3(b0, b1, b2, c1);
            ins3(b0, b1, b2, c2);
        }

        if (sub == 0) {
            const float d0 = __uint_as_float((unsigned)(b0 >> 32));
            const float d1 = __uint_as_float((unsigned)(b1 >> 32));
            const float d2 = __uint_as_float((unsigned)(b2 >> 32));
            const float w0 = 1.0f / fmaxf(d0, 1e-16f);
            const float w1 = 1.0f / fmaxf(d1, 1e-16f);
            const float w2 = 1.0f / fmaxf(d2, 1e-16f);
            const float s = 1.0f / (w0 + w1 + w2);
            knn_idx[t * 3 + 0] = (int)(b0 & 0xffffffffu);
            knn_idx[t * 3 + 1] = (int)(b1 & 0xffffffffu);
            knn_idx[t * 3 + 2] = (int)(b2 & 0xffffffffu);
            knn_w[t * 3 + 0] = w0 * s;
            knn_w[t * 3 + 1] = w1 * s;
            knn_w[t * 3 + 2] = w2 * s;
        }
    }
}

// ---------------------------------------------------------------------------
// interp of bf16 coarse rows: cols 0..255 -> PQf, 256..383 -> Uf (both bf16).
// thread per (t, 8-ch group); 48 groups per fine node; 16B gathers.
// ---------------------------------------------------------------------------
template <int STRIDE>
__global__ __launch_bounds__(256) void interp_kernel(
    const ushort_t* __restrict__ R, const int* __restrict__ knn_idx,
    const float* __restrict__ knn_w, ushort_t* __restrict__ PQf,
    ushort_t* __restrict__ Uf) {
    const int tid = blockIdx.x * 256 + threadIdx.x;
    const int t = tid / 48;
    const int g = tid - t * 48;
    const int i0 = knn_idx[t * 3 + 0], i1 = knn_idx[t * 3 + 1], i2 = knn_idx[t * 3 + 2];
    const float w0 = knn_w[t * 3 + 0], w1 = knn_w[t * 3 + 1], w2 = knn_w[t * 3 + 2];
    const short8v a = *(const short8v*)(R + (size_t)i0 * STRIDE + g * 8);
    const short8v b = *(const short8v*)(R + (size_t)i1 * STRIDE + g * 8);
    const short8v c = *(const short8v*)(R + (size_t)i2 * STRIDE + g * 8);
    short8v o;
#pragma unroll
    for (int e = 0; e < 8; ++e) {
        const float v = w0 * bf2f((ushort_t)a[e]) + w1 * bf2f((ushort_t)b[e])
                      + w2 * bf2f((ushort_t)c[e]);
        o[e] = (short)f2bf(v);
    }
    if (g < 32) *(short8v*)(PQf + (size_t)t * 256 + g * 8) = o;
    else        *(short8v*)(Uf + (size_t)t * 128 + (g - 32) * 8) = o;
}

// ---------------------------------------------------------------------------
// agg: fine part (bf16 PQf, 128 ch, 2 ch/lane) and optional coarse part
// (bf16 RA cols 384..511, 64 ch). One wave per dst node.
// ---------------------------------------------------------------------------
template <bool DUAL>
__global__ __launch_bounds__(256) void agg_kernel(
    const ushort_t* __restrict__ PQf, const int* __restrict__ baseF,
    const int* __restrict__ srtF, const float* __restrict__ beF,
    ushort_t* __restrict__ aggF,
    const ushort_t* __restrict__ RA, const int* __restrict__ baseC,
    const int* __restrict__ srtC, const float* __restrict__ beC,
    ushort_t* __restrict__ aggC) {
    const int bid = blockIdx.x;
    const int wid = threadIdx.x >> 6, lane = threadIdx.x & 63;
    if (!DUAL || bid < NF / 4) {
        const int n = bid * 4 + wid;
        const int b0 = baseF[n], b1 = baseF[n + 1];
        const ushort2 qv = *(const ushort2*)(PQf + (size_t)n * 256 + 128 + lane * 2);
        const float2 bv = *(const float2*)(beF + lane * 2);
        const float qx = bf2f(qv.x) + bv.x, qy = bf2f(qv.y) + bv.y;
        float ax = 0.0f, ay = 0.0f;
        for (int e = b0; e < b1; ++e) {
            const int src = srtF[e];
            const ushort2 pv = *(const ushort2*)(PQf + (size_t)src * 256 + lane * 2);
            ax += selu_f(bf2f(pv.x) + qx);
            ay += selu_f(bf2f(pv.y) + qy);
        }
        ushort2 r; r.x = f2bf(ax); r.y = f2bf(ay);
        *(ushort2*)(aggF + (size_t)n * 128 + lane * 2) = r;
    } else {
        const int n = (bid - NF / 4) * 4 + wid;
        const int b0 = baseC[n], b1 = baseC[n + 1];
        const float q = bf2f(RA[(size_t)n * 512 + 448 + lane]) + beC[lane];
        float s = 0.0f;
        for (int e = b0; e < b1; ++e) {
            const int src = srtC[e];
            s += selu_f(bf2f(RA[(size_t)src * 512 + 384 + lane]) + q);
        }
        aggC[(size_t)n * 64 + lane] = f2bf(s);
    }
}

// ---------------------------------------------------------------------------
// nodeSD: blocks 0..255: x_skip = selu(aggF@WnS_bot + UfS + bnS) -> outp f32
//         blocks 256..319: h1 = selu(concat(xb,agg1b)@Wn1 + bn1) kept in LDS,
//                          then RE = h1 @ WfE (fused gemmE) -> RE bf16
// ---------------------------------------------------------------------------
__global__ __launch_bounds__(256) void nodeSD_kernel(
    const ushort_t* __restrict__ aggF, const ushort_t* __restrict__ WfSn,
    const float* __restrict__ bnS, const ushort_t* __restrict__ UfS,
    float* __restrict__ outp,
    const ushort_t* __restrict__ xb, const ushort_t* __restrict__ agg1b,
    const ushort_t* __restrict__ Wf1n, const float* __restrict__ bn1,
    const ushort_t* __restrict__ WfE, ushort_t* __restrict__ RE) {
    __shared__ ushort_t h1s[64][72];     // padded: 144B row stride
    const int tid = threadIdx.x;
    const int wid = tid >> 6, lane = tid & 63;
    const int klane = (lane >> 4) << 3;
    if (blockIdx.x < 256) {
        const int row_base = blockIdx.x * 64 + wid * 16;
        const int row_a = row_base + (lane & 15);
        short8v a[4];
#pragma unroll
        for (int f = 0; f < 4; ++f)
            a[f] = *(const short8v*)(aggF + (size_t)row_a * 128 + f * 32 + klane);
#pragma unroll
        for (int nt = 0; nt < 8; ++nt) {
            f32x4 acc = {0.0f, 0.0f, 0.0f, 0.0f};
#pragma unroll
            for (int f = 0; f < 4; ++f) {
                const short8v b =
                    *(const short8v*)(WfSn + (size_t)(nt * 4 + f) * 512 + lane * 8);
                acc = __builtin_amdgcn_mfma_f32_16x16x32_bf16(a[f], b, acc, 0, 0, 0);
            }
            const int col = nt * 16 + (lane & 15);
            const int r0 = row_base + ((lane >> 4) << 2);
#pragma unroll
            for (int r = 0; r < 4; ++r) {
                const size_t o = (size_t)(r0 + r) * 128 + col;
                outp[o] = selu_f(acc[r] + bnS[col] + bf2f(UfS[o]));
            }
        }
    } else {
        const int row_base = (blockIdx.x - 256) * 64 + wid * 16;
        const int row_a = row_base + (lane & 15);
        short8v a[6];
#pragma unroll
        for (int f = 0; f < 4; ++f)
            a[f] = *(const short8v*)(xb + (size_t)row_a * 128 + f * 32 + klane);
#pragma unroll
        for (int f = 0; f < 2; ++f)
            a[4 + f] = *(const short8v*)(agg1b + (size_t)row_a * 64 + f * 32 + klane);
#pragma unroll
        for (int nt = 0; nt < 4; ++nt) {
            f32x4 acc = {0.0f, 0.0f, 0.0f, 0.0f};
#pragma unroll
            for (int f = 0; f < 6; ++f) {
                const short8v b =
                    *(const short8v*)(Wf1n + (size_t)(nt * 6 + f) * 512 + lane * 8);
                acc = __builtin_amdgcn_mfma_f32_16x16x32_bf16(a[f], b, acc, 0, 0, 0);
            }
            const int col = nt * 16 + (lane & 15);
            const int lr0 = wid * 16 + ((lane >> 4) << 2);
#pragma unroll
            for (int r = 0; r < 4; ++r)
                h1s[lr0 + r][col] = f2bf(selu_f(acc[r] + bn1[col]));
        }
        __syncthreads();
        // fused gemmE: RE(rows row_base..row_base+15 per wave) = h1 @ WfE
        short8v ha[2];
#pragma unroll
        for (int f = 0; f < 2; ++f)
            ha[f] = *(const short8v*)&h1s[wid * 16 + (lane & 15)][f * 32 + klane];
#pragma unroll
        for (int nt = 0; nt < 24; ++nt) {
            f32x4 acc = {0.0f, 0.0f, 0.0f, 0.0f};
#pragma unroll
            for (int f = 0; f < 2; ++f) {
                const short8v b =
                    *(const short8v*)(WfE + (size_t)(nt * 2 + f) * 512 + lane * 8);
                acc = __builtin_amdgcn_mfma_f32_16x16x32_bf16(ha[f], b, acc, 0, 0, 0);
            }
            const int col = nt * 16 + (lane & 15);
            const int r0 = row_base + ((lane >> 4) << 2);
#pragma unroll
            for (int r = 0; r < 4; ++r)
                RE[(size_t)(r0 + r) * 384 + col] = f2bf(acc[r]);
        }
    }
}

// ---------------------------------------------------------------------------
// nodeH: v = selu(aggF@Wn2_bot + Uf2 + bn2) + x_skip; write outp; BN stats.
// ---------------------------------------------------------------------------
__global__ __launch_bounds__(256) void nodeH_kernel(
    const ushort_t* __restrict__ aggF, const ushort_t* __restrict__ Wf2n,
    const float* __restrict__ bn2, const ushort_t* __restrict__ Uf2,
    float* __restrict__ outp, float* __restrict__ stats) {
    __shared__ float s_sum[128], s_sq[128];
    const int tid = threadIdx.x;
    const int wid = tid >> 6, lane = tid & 63;
    const int klane = (lane >> 4) << 3;
    if (tid < 128) { s_sum[tid] = 0.0f; s_sq[tid] = 0.0f; }
    __syncthreads();
    const int row_base = blockIdx.x * 64 + wid * 16;
    const int row_a = row_base + (lane & 15);
    short8v a[4];
#pragma unroll
    for (int f = 0; f < 4; ++f)
        a[f] = *(const short8v*)(aggF + (size_t)row_a * 128 + f * 32 + klane);
#pragma unroll
    for (int nt = 0; nt < 8; ++nt) {
        f32x4 acc = {0.0f, 0.0f, 0.0f, 0.0f};
#pragma unroll
        for (int f = 0; f < 4; ++f) {
            const short8v b =
                *(const short8v*)(Wf2n + (size_t)(nt * 4 + f) * 512 + lane * 8);
            acc = __builtin_amdgcn_mfma_f32_16x16x32_bf16(a[f], b, acc, 0, 0, 0);
        }
        const int col = nt * 16 + (lane & 15);
        const int r0 = row_base + ((lane >> 4) << 2);
        float lsum = 0.0f, lsq = 0.0f;
#pragma unroll
        for (int r = 0; r < 4; ++r) {
            const size_t o = (size_t)(r0 + r) * 128 + col;
            float v = selu_f(acc[r] + bn2[col] + bf2f(Uf2[o])) + outp[o];
            outp[o] = v;
            lsum += v; lsq += v * v;
        }
        atomicAdd(&s_sum[nt * 16 + (lane & 15)], lsum);
        atomicAdd(&s_sq[nt * 16 + (lane & 15)], lsq);
    }
    __syncthreads();
    if (tid < 128) {
        atomicAdd(&stats[tid], s_sum[tid]);
        atomicAdd(&stats[128 + tid], s_sq[tid]);
    }
}

// ---------------------------------------------------------------------------
// BN normalize + SELU, in place on d_out.
// ---------------------------------------------------------------------------
__global__ __launch_bounds__(256) void bn_kernel(
    float* __restrict__ out, const float* __restrict__ stats,
    const float* __restrict__ gamma, const float* __restrict__ beta, int Nn) {
    const int i = blockIdx.x * blockDim.x + threadIdx.x;
    const int c = i & 127;
    const float invn = 1.0f / (float)Nn;
    float mu = stats[c] * invn;
    float var = stats[128 + c] * invn - mu * mu;
    float r = rsqrtf(var + 1e-5f);
    float v = (out[i] - mu) * r * gamma[c] + beta[c];
    out[i] = selu_f(v);
}

// ---------------------------------------------------------------------------
extern "C" void kernel_launch(void* const* d_in, const int* in_sizes, int n_in,
                              void* d_out, int out_size, void* d_ws, size_t ws_size,
                              hipStream_t stream) {
    const float* x     = (const float*)d_in[0];
    const float* pos_c = (const float*)d_in[1];
    const float* pos_f = (const float*)d_in[2];
    const int*   ei_c  = (const int*)d_in[3];
    const int*   ei_f  = (const int*)d_in[4];
    const float* We1 = (const float*)d_in[5];
    const float* be1 = (const float*)d_in[6];
    const float* Wn1 = (const float*)d_in[7];
    const float* bn1 = (const float*)d_in[8];
    const float* We2 = (const float*)d_in[9];
    const float* be2 = (const float*)d_in[10];
    const float* Wn2 = (const float*)d_in[11];
    const float* bn2 = (const float*)d_in[12];
    const float* WeS = (const float*)d_in[13];
    const float* beS = (const float*)d_in[14];
    const float* WnS = (const float*)d_in[15];
    const float* bnS = (const float*)d_in[16];
    const float* gamma = (const float*)d_in[17];
    const float* beta  = (const float*)d_in[18];

    char* w = (char*)d_ws;
    size_t o = 0;
    auto alloc = [&](size_t bytes) { void* p = w + o; o += (bytes + 255) & ~(size_t)255; return p; };
    int*      knn_idx = (int*)alloc((size_t)NF * 3 * sizeof(int));
    float*    knn_w   = (float*)alloc((size_t)NF * 3 * sizeof(float));
    ushort_t* RA      = (ushort_t*)alloc((size_t)NC * 512 * 2);   // also RE (aliased)
    ushort_t* PQf     = (ushort_t*)alloc((size_t)NF * 256 * 2);   // reused
    ushort_t* Uf      = (ushort_t*)alloc((size_t)NF * 128 * 2);   // reused
    ushort_t* aggF    = (ushort_t*)alloc((size_t)NF * 128 * 2);   // reused
    ushort_t* agg1b   = (ushort_t*)alloc((size_t)NC * 64 * 2);
    ushort_t* xb      = (ushort_t*)alloc((size_t)NC * 128 * 2);
    ushort_t* WfA     = (ushort_t*)alloc(65536 * 2);
    ushort_t* WfE     = (ushort_t*)alloc(24576 * 2);
    ushort_t* WfSn    = (ushort_t*)alloc(16384 * 2);
    ushort_t* Wf1n    = (ushort_t*)alloc(12288 * 2);
    ushort_t* Wf2n    = (ushort_t*)alloc(16384 * 2);
    int*   cntF  = (int*)alloc((size_t)NF * sizeof(int));
    int*   baseF = (int*)alloc((size_t)(NF + 1) * sizeof(int));
    int*   cursF = (int*)alloc((size_t)NF * sizeof(int));
    int*   srtF  = (int*)alloc((size_t)EF * sizeof(int));
    int*   cntC  = (int*)alloc((size_t)NC * sizeof(int));
    int*   baseC = (int*)alloc((size_t)(NC + 1) * sizeof(int));
    int*   cursC = (int*)alloc((size_t)NC * sizeof(int));
    int*   srtC  = (int*)alloc((size_t)EC * sizeof(int));
    int*   cntG  = (int*)alloc((size_t)NCELL * sizeof(int));
    int*   baseG = (int*)alloc((size_t)(NCELL + 1) * sizeof(int));
    int*   cursG = (int*)alloc((size_t)NCELL * sizeof(int));
    float4* grecs = (float4*)alloc((size_t)NC * sizeof(float4));
    float* stats = (float*)alloc(256 * sizeof(float));
    ushort_t* RE = RA;               // RA dead once nodeSD starts
    float* outp = (float*)d_out;

    // 1. prep (converts + weight frags + zeroing)
    constexpr int PREP_TOTAL = NC * 128 + 65536 + 24576 + 16384 + 12288 + 16384
                             + NF + NC + NCELL + 256;
    prep_kernel<<<(PREP_TOTAL + 255) / 256, 256, 0, stream>>>(
        x, xb, WeS, WnS, We1, We2, Wn2, Wn1,
        WfA, WfE, WfSn, Wf1n, Wf2n, cntF, cntC, cntG, stats);

    // 2-4. merged counting sorts
    constexpr int SORT_ITEMS = EF + EC + NC;
    hist3_kernel<<<(SORT_ITEMS + 255) / 256, 256, 0, stream>>>(
        ei_f, ei_c, pos_c, cntF, cntC, cntG);
    scan3_kernel<<<3, 1024, 0, stream>>>(
        cntF, baseF, cursF, cntC, baseC, cursC, cntG, baseG, cursG);
    scatter3_kernel<<<(SORT_ITEMS + 255) / 256, 256, 0, stream>>>(
        ei_f, ei_c, pos_c, cursF, srtF, cursC, srtC, cursG, grecs);

    // 5. RA GEMM (bf16 out) + kNN (8 lanes/point)
    gemmA_knn_kernel<<<768, 256, 0, stream>>>(
        xb, WfA, RA, pos_f, grecs, baseG, knn_idx, knn_w);

    // 6. interp RA -> PQf(S) + Uf(S)
    interp_kernel<512><<<NF * 48 / 256, 256, 0, stream>>>(RA, knn_idx, knn_w, PQf, Uf);

    // 7. agg: fine skip + coarse mpl1 (fused)
    agg_kernel<true><<<NF / 4 + NC / 4, 256, 0, stream>>>(
        PQf, baseF, srtF, beS, aggF, RA, baseC, srtC, be1, agg1b);

    // 8. nodeS (x_skip -> d_out) + node1 + fused gemmE (RE)
    nodeSD_kernel<<<320, 256, 0, stream>>>(
        aggF, WfSn, bnS, Uf, outp, xb, agg1b, Wf1n, bn1, WfE, RE);

    // 9. interp RE -> PQf(2) + Uf(2)
    interp_kernel<384><<<NF * 48 / 256, 256, 0, stream>>>(RE, knn_idx, knn_w, PQf, Uf);

    // 10. agg2 (fine)
    agg_kernel<false><<<NF / 4, 256, 0, stream>>>(
        PQf, baseF, srtF, be2, aggF, nullptr, nullptr, nullptr, nullptr, nullptr);

    // 11. nodeH: final MLP + residual + BN stats
    nodeH_kernel<<<256, 256, 0, stream>>>(aggF, Wf2n, bn2, Uf, outp, stats);

    // 12. BN + SELU
    bn_kernel<<<NF * 128 / 256, 256, 0, stream>>>(outp, stats, gamma, beta, NF);
}